// Round 1
// 2641.794 us; speedup vs baseline: 1.3089x; 1.3089x over previous
//
#include <hip/hip_runtime.h>
#include <hip/hip_bf16.h>
#include <stdint.h>

// ===========================================================================
// VQ-VAE forward, MI355X. Round 6: encoder moved to bf16 matrix cores via
// 3-limb split-bf16 (Ozaki-style, 6 products) + f64 chunk folding.
// R5 baseline = 3458us, 84% of it in the f32-VALU gemmf (50 TF, MfmaUtil=0).
//
// Numerics: limbs hi/mid/lo cover 24 mantissa bits (residual 2^-27); kept
// products {hh,hm,mh,hl,lh,mm}; dropped terms ~2^-26 rel. f32 MFMA acc is
// folded to f64 every 2 K-steps (64 K) -> accum err ~1.2e-7*|out|.
// Propagated z err ~3e-8 abs -> argmin score err ~1e-9, same class as R5's
// f32-fma/f64-fold design => index flips stay at the reference-f32 floor.
// Decoder: unchanged bf16 MFMA (proven).
// Layout: inputs f32; out f32: rec[16384*1024] | qst[16384*256] | loss[1]
// | idx[16384].
// ===========================================================================

#define BDIM  16384
#define DIN   1024
#define DH1   2048
#define DH2   1024
#define DCODE 256
#define KCODE 1024

typedef __hip_bfloat16 bf16;
typedef __attribute__((ext_vector_type(8))) short short8;
typedef __attribute__((ext_vector_type(4))) float f32x4;

// ---------------------------------------------------------------------------
// 3-limb bf16 split: f = h + m + l up to 2^-27 relative.
// (f - bf16(f)) is exact in f32 (Sterbenz), so limbs are exact residuals.
// ---------------------------------------------------------------------------
__device__ __forceinline__ void split3(float f, ushort* h, ushort* m, ushort* l)
{
    bf16 bh = __float2bfloat16(f);
    float r1 = f - __bfloat162float(bh);
    bf16 bm = __float2bfloat16(r1);
    float r2 = r1 - __bfloat162float(bm);
    bf16 bl = __float2bfloat16(r2);
    *h = *(ushort*)&bh; *m = *(ushort*)&bm; *l = *(ushort*)&bl;
}

// ---------------------------------------------------------------------------
// split-bf16 MFMA GEMM: C = act(A @ Bt^T + bias) computed as the 6-term
// limb expansion on the matrix cores.
// A planes: [M][K] bf16, plane stride PA. Bt planes: [N][K] bf16, stride PB.
// 128x128 tile, BK=32, 512 thr / 8 waves, wave tile 32x64 = 2x4 MFMA
// 16x16x32. f32 acc folded into f64 shadow every 2 K-steps.
// OUTK: 0 = write 3 bf16 limb planes (stride PC), 2 = f64 out.
// ---------------------------------------------------------------------------
template<int RELU, int OUTK>
__global__ __launch_bounds__(512, 2)
void gemms(const ushort* __restrict__ Apl, const ushort* __restrict__ Bpl,
           const float* __restrict__ bias, void* __restrict__ C,
           int M, int N, int K, size_t PA, size_t PB, size_t PC)
{
    __shared__ __align__(16) short As[3][128][40];   // pad 40: 80B rows, 16B-aligned,
    __shared__ __align__(16) short Bs[3][128][40];   // 2-way-max bank pattern (free)
    const int tid  = threadIdx.x;
    const int lane = tid & 63;
    const int wave = tid >> 6;                 // 0..7
    const int wm = (wave >> 1) << 5;           // 4 m-waves * 32
    const int wn = (wave & 1) << 6;            // 2 n-waves * 64
    const int fr = lane & 15, fq = lane >> 4;
    const int row0 = blockIdx.y << 7, col0 = blockIdx.x << 7;

    const int sr = tid >> 2, sc = (tid & 3) << 3;   // stage: 128 rows x 32 k

    const ushort* Ag = Apl + (size_t)(row0 + sr) * K + sc;
    const ushort* Bg = Bpl + (size_t)(col0 + sr) * K + sc;

    f32x4  acc[2][4];
    double dacc[2][4][4];
    #pragma unroll
    for (int i = 0; i < 2; ++i)
        #pragma unroll
        for (int j = 0; j < 4; ++j) {
            acc[i][j] = (f32x4)0.0f;
            #pragma unroll
            for (int r = 0; r < 4; ++r) dacc[i][j][r] = 0.0;
        }

    // software-pipelined staging: preload step 0
    short8 sa[3], sb[3];
    #pragma unroll
    for (int p = 0; p < 3; ++p) {
        sa[p] = *(const short8*)(Ag + (size_t)p * PA);
        sb[p] = *(const short8*)(Bg + (size_t)p * PB);
    }

    const int nsteps = K >> 5;
    for (int s = 0; s < nsteps; ++s) {
        __syncthreads();
        #pragma unroll
        for (int p = 0; p < 3; ++p) {
            *(short8*)&As[p][sr][sc] = sa[p];
            *(short8*)&Bs[p][sr][sc] = sb[p];
        }
        __syncthreads();
        if (s + 1 < nsteps) {            // issue next-tile loads before compute
            const int kb = (s + 1) << 5;
            #pragma unroll
            for (int p = 0; p < 3; ++p) {
                sa[p] = *(const short8*)(Ag + (size_t)p * PA + kb);
                sb[p] = *(const short8*)(Bg + (size_t)p * PB + kb);
            }
        }

        // hold all B limb fragments (12 reads), stream A per i (6 reads)
        short8 bh[4], bm[4], bl[4];
        #pragma unroll
        for (int j = 0; j < 4; ++j) {
            const int bn = wn + (j << 4) + fr;
            bh[j] = *(const short8*)&Bs[0][bn][fq << 3];
            bm[j] = *(const short8*)&Bs[1][bn][fq << 3];
            bl[j] = *(const short8*)&Bs[2][bn][fq << 3];
        }
        #pragma unroll
        for (int i = 0; i < 2; ++i) {
            const int an = wm + (i << 4) + fr;
            short8 ah = *(const short8*)&As[0][an][fq << 3];
            short8 am = *(const short8*)&As[1][an][fq << 3];
            short8 al = *(const short8*)&As[2][an][fq << 3];
            #pragma unroll
            for (int j = 0; j < 4; ++j) {
                acc[i][j] = __builtin_amdgcn_mfma_f32_16x16x32_bf16(ah, bh[j], acc[i][j], 0, 0, 0);
                acc[i][j] = __builtin_amdgcn_mfma_f32_16x16x32_bf16(ah, bm[j], acc[i][j], 0, 0, 0);
                acc[i][j] = __builtin_amdgcn_mfma_f32_16x16x32_bf16(am, bh[j], acc[i][j], 0, 0, 0);
                acc[i][j] = __builtin_amdgcn_mfma_f32_16x16x32_bf16(ah, bl[j], acc[i][j], 0, 0, 0);
                acc[i][j] = __builtin_amdgcn_mfma_f32_16x16x32_bf16(al, bh[j], acc[i][j], 0, 0, 0);
                acc[i][j] = __builtin_amdgcn_mfma_f32_16x16x32_bf16(am, bm[j], acc[i][j], 0, 0, 0);
            }
        }

        if (s & 1) {   // fold f32 acc into f64 shadow every 2 K-steps (64 K)
            #pragma unroll
            for (int i = 0; i < 2; ++i)
                #pragma unroll
                for (int j = 0; j < 4; ++j) {
                    #pragma unroll
                    for (int r = 0; r < 4; ++r) dacc[i][j][r] += (double)acc[i][j][r];
                    acc[i][j] = (f32x4)0.0f;
                }
        }
    }
    // final fold (no-op when nsteps even; guard for odd)
    #pragma unroll
    for (int i = 0; i < 2; ++i)
        #pragma unroll
        for (int j = 0; j < 4; ++j)
            #pragma unroll
            for (int r = 0; r < 4; ++r) dacc[i][j][r] += (double)acc[i][j][r];

    // epilogue: D[m = fq*4 + r][n = fr] per 16x16 fragment (gemmb-verified map)
    #pragma unroll
    for (int j = 0; j < 4; ++j) {
        const int n = col0 + wn + (j << 4) + fr;
        const double bv = (double)bias[n];
        #pragma unroll
        for (int i = 0; i < 2; ++i) {
            const int mb = row0 + wm + (i << 4) + (fq << 2);
            #pragma unroll
            for (int r = 0; r < 4; ++r) {
                double v = dacc[i][j][r] + bv;
                if (RELU) v = v > 0.0 ? v : 0.0;
                const size_t o = (size_t)(mb + r) * N + n;
                if (OUTK == 2) {
                    ((double*)C)[o] = v;
                } else {
                    ushort h, m, l;
                    split3((float)v, &h, &m, &l);
                    ushort* Cp = (ushort*)C;
                    Cp[o] = h; Cp[PC + o] = m; Cp[2 * PC + o] = l;
                }
            }
        }
    }
}

// ---------------------------------------------------------------------------
// bf16 MFMA GEMM (decoder, unchanged from R5): C = act(A @ Bt^T + bias).
// ---------------------------------------------------------------------------
template<int RELU, int OUTBF>
__global__ __launch_bounds__(256)
void gemmb(const ushort* __restrict__ A, const ushort* __restrict__ Bt,
           const float* __restrict__ bias, void* __restrict__ C,
           int M, int N, int K)
{
    __shared__ __align__(16) short As[128][40];
    __shared__ __align__(16) short Bs[128][40];
    const int tid  = threadIdx.x;
    const int lane = tid & 63;
    const int wave = tid >> 6;
    const int wm = (wave >> 1) << 6, wn = (wave & 1) << 6;
    const int fr = lane & 15;
    const int fq = lane >> 4;
    const int row0 = blockIdx.y << 7, col0 = blockIdx.x << 7;

    const int sr = tid >> 1, sh = (tid & 1) << 4;

    const ushort* Ag = A  + (size_t)(row0 + sr) * K + sh;
    const ushort* Bg = Bt + (size_t)(col0 + sr) * K + sh;

    f32x4 acc[4][4];
    #pragma unroll
    for (int i = 0; i < 4; ++i)
        #pragma unroll
        for (int j = 0; j < 4; ++j) acc[i][j] = (f32x4)0.0f;

    for (int kb = 0; kb < K; kb += 32) {
        short8 a0 = *(const short8*)(Ag + kb);
        short8 a1 = *(const short8*)(Ag + kb + 8);
        short8 b0 = *(const short8*)(Bg + kb);
        short8 b1 = *(const short8*)(Bg + kb + 8);
        __syncthreads();
        *(short8*)&As[sr][sh]     = a0;
        *(short8*)&As[sr][sh + 8] = a1;
        *(short8*)&Bs[sr][sh]     = b0;
        *(short8*)&Bs[sr][sh + 8] = b1;
        __syncthreads();

        short8 af[4], bf[4];
        #pragma unroll
        for (int i = 0; i < 4; ++i)
            af[i] = *(const short8*)&As[wm + (i << 4) + fr][fq << 3];
        #pragma unroll
        for (int j = 0; j < 4; ++j)
            bf[j] = *(const short8*)&Bs[wn + (j << 4) + fr][fq << 3];
        #pragma unroll
        for (int i = 0; i < 4; ++i)
            #pragma unroll
            for (int j = 0; j < 4; ++j)
                acc[i][j] = __builtin_amdgcn_mfma_f32_16x16x32_bf16(
                                af[i], bf[j], acc[i][j], 0, 0, 0);
    }

    #pragma unroll
    for (int j = 0; j < 4; ++j) {
        const int n = col0 + wn + (j << 4) + fr;
        const float bv = bias[n];
        #pragma unroll
        for (int i = 0; i < 4; ++i) {
            const int mb = row0 + wm + (i << 4) + (fq << 2);
            #pragma unroll
            for (int r = 0; r < 4; ++r) {
                float v = acc[i][j][r] + bv;
                if (RELU) v = fmaxf(v, 0.0f);
                size_t o = (size_t)(mb + r) * N + n;
                if (OUTBF) ((bf16*)C)[o]  = __float2bfloat16(v);
                else       ((float*)C)[o] = v;
            }
        }
    }
}

// ---------------------------------------------------------------------------
// decoder weight transpose + f32->bf16 (unchanged)
// ---------------------------------------------------------------------------
__global__ __launch_bounds__(256)
void wtrans(const float* __restrict__ W, ushort* __restrict__ Wt, int K, int N)
{
    __shared__ float tile[64][65];
    const int tid = threadIdx.x;
    const int kb = blockIdx.y << 6, nb = blockIdx.x << 6;
    const int r = tid >> 4, c4 = (tid & 15) << 2;
    #pragma unroll
    for (int s = 0; s < 4; ++s) {
        float4 v = *(const float4*)(W + (size_t)(kb + r + (s << 4)) * N + nb + c4);
        tile[r + (s << 4)][c4 + 0] = v.x; tile[r + (s << 4)][c4 + 1] = v.y;
        tile[r + (s << 4)][c4 + 2] = v.z; tile[r + (s << 4)][c4 + 3] = v.w;
    }
    __syncthreads();
    #pragma unroll
    for (int s = 0; s < 4; ++s) {
        const int n = r + (s << 4);
        ushort u[4];
        #pragma unroll
        for (int l = 0; l < 4; ++l) {
            bf16 h = __float2bfloat16(tile[c4 + l][n]);
            u[l] = *(ushort*)&h;
        }
        *(ushort4*)(Wt + (size_t)(nb + n) * K + kb + c4) = make_ushort4(u[0], u[1], u[2], u[3]);
    }
}

// ---------------------------------------------------------------------------
// encoder weight transpose + 3-limb split: planes [N][K], stride N*K
// ---------------------------------------------------------------------------
__global__ __launch_bounds__(256)
void wsplit(const float* __restrict__ W, ushort* __restrict__ Wt, int K, int N)
{
    __shared__ float tile[64][65];
    const int tid = threadIdx.x;
    const int kb = blockIdx.y << 6, nb = blockIdx.x << 6;
    const int r = tid >> 4, c4 = (tid & 15) << 2;
    const size_t NK = (size_t)N * K;
    #pragma unroll
    for (int s = 0; s < 4; ++s) {
        float4 v = *(const float4*)(W + (size_t)(kb + r + (s << 4)) * N + nb + c4);
        tile[r + (s << 4)][c4 + 0] = v.x; tile[r + (s << 4)][c4 + 1] = v.y;
        tile[r + (s << 4)][c4 + 2] = v.z; tile[r + (s << 4)][c4 + 3] = v.w;
    }
    __syncthreads();
    #pragma unroll
    for (int s = 0; s < 4; ++s) {
        const int n = r + (s << 4);
        ushort h[4], m[4], l[4];
        #pragma unroll
        for (int e = 0; e < 4; ++e) split3(tile[c4 + e][n], &h[e], &m[e], &l[e]);
        const size_t o = (size_t)(nb + n) * K + kb + c4;
        *(ushort4*)(Wt + o)          = make_ushort4(h[0], h[1], h[2], h[3]);
        *(ushort4*)(Wt + NK + o)     = make_ushort4(m[0], m[1], m[2], m[3]);
        *(ushort4*)(Wt + 2 * NK + o) = make_ushort4(l[0], l[1], l[2], l[3]);
    }
}

// ---------------------------------------------------------------------------
// x -> 3 bf16 limb planes (row-major, plane stride P elements)
// ---------------------------------------------------------------------------
__global__ __launch_bounds__(256)
void xsplit(const float* __restrict__ X, ushort* __restrict__ Xp, size_t P)
{
    const size_t i = ((size_t)blockIdx.x * 256 + threadIdx.x) << 2;
    float4 v = *(const float4*)(X + i);
    ushort h[4], m[4], l[4];
    split3(v.x, &h[0], &m[0], &l[0]);
    split3(v.y, &h[1], &m[1], &l[1]);
    split3(v.z, &h[2], &m[2], &l[2]);
    split3(v.w, &h[3], &m[3], &l[3]);
    *(ushort4*)(Xp + i)         = make_ushort4(h[0], h[1], h[2], h[3]);
    *(ushort4*)(Xp + P + i)     = make_ushort4(m[0], m[1], m[2], m[3]);
    *(ushort4*)(Xp + 2 * P + i) = make_ushort4(l[0], l[1], l[2], l[3]);
}

// ---------------------------------------------------------------------------
// codebook squared norms (f64) (unchanged)
// ---------------------------------------------------------------------------
__global__ __launch_bounds__(64)
void c2_k(const float* __restrict__ cb, double* __restrict__ c2)
{
    int code = blockIdx.x, l = threadIdx.x;
    float4 v = *(const float4*)(cb + (size_t)code * DCODE + (l << 2));
    double s = (double)v.x * v.x + (double)v.y * v.y
             + (double)v.z * v.z + (double)v.w * v.w;
    #pragma unroll
    for (int off = 32; off; off >>= 1) s += __shfl_down(s, off, 64);
    if (l == 0) c2[code] = s;
}

// ---------------------------------------------------------------------------
// distance + argmin (f64) (unchanged)
// ---------------------------------------------------------------------------
__global__ __launch_bounds__(256)
void dist_k(const double* __restrict__ z, const float* __restrict__ cb,
            const double* __restrict__ c2, int* __restrict__ idx_out)
{
    __shared__ double As[16][64];
    __shared__ float  Bs[16][64];
    __shared__ double rs[64][17];
    __shared__ int    ri[64][17];
    const int tid = threadIdx.x;
    const int tx = tid & 15, ty = tid >> 4;
    const int row0 = blockIdx.x << 6;
    const int am = tid >> 2, ak = (tid & 3) << 2;
    const int cn = tid >> 2, ck = (tid & 3) << 2;

    double bsc[4]; int bid[4];
    #pragma unroll
    for (int i = 0; i < 4; ++i) { bsc[i] = 1e300; bid[i] = 0; }

    for (int ct = 0; ct < KCODE / 64; ++ct) {
        const int col0 = ct << 6;
        double dacc[4][4];
        #pragma unroll
        for (int i = 0; i < 4; ++i)
            #pragma unroll
            for (int j = 0; j < 4; ++j) dacc[i][j] = 0.0;

        for (int kb = 0; kb < DCODE; kb += 16) {
            const double* zp = z + (size_t)(row0 + am) * DCODE + kb + ak;
            As[ak + 0][am] = zp[0]; As[ak + 1][am] = zp[1];
            As[ak + 2][am] = zp[2]; As[ak + 3][am] = zp[3];
            float4 w = *(const float4*)(cb + (size_t)(col0 + cn) * DCODE + kb + ck);
            Bs[ck + 0][cn] = w.x; Bs[ck + 1][cn] = w.y;
            Bs[ck + 2][cn] = w.z; Bs[ck + 3][cn] = w.w;
            __syncthreads();

            #pragma unroll
            for (int kk = 0; kk < 16; ++kk) {
                double av[4]; float bv[4];
                #pragma unroll
                for (int i = 0; i < 4; ++i) av[i] = As[kk][(ty << 2) + i];
                #pragma unroll
                for (int j = 0; j < 4; ++j) bv[j] = Bs[kk][(tx << 2) + j];
                #pragma unroll
                for (int i = 0; i < 4; ++i)
                    #pragma unroll
                    for (int j = 0; j < 4; ++j)
                        dacc[i][j] = fma(av[i], (double)bv[j], dacc[i][j]);
            }
            __syncthreads();
        }

        #pragma unroll
        for (int i = 0; i < 4; ++i) {
            #pragma unroll
            for (int j = 0; j < 4; ++j) {
                int c = col0 + (tx << 2) + j;
                double s = c2[c] - 2.0 * dacc[i][j];
                if (s < bsc[i]) { bsc[i] = s; bid[i] = c; }
            }
        }
    }

    #pragma unroll
    for (int i = 0; i < 4; ++i) {
        rs[(ty << 2) + i][tx] = bsc[i];
        ri[(ty << 2) + i][tx] = bid[i];
    }
    __syncthreads();
    if (tid < 64) {
        double m = rs[tid][0]; int mi = ri[tid][0];
        #pragma unroll
        for (int t = 1; t < 16; ++t) {
            double s = rs[tid][t]; int c = ri[tid][t];
            if (s < m || (s == m && c < mi)) { m = s; mi = c; }
        }
        idx_out[row0 + tid] = mi;
    }
}

// ---------------------------------------------------------------------------
// gather + straight-through + loss partials + idx (unchanged)
// ---------------------------------------------------------------------------
__global__ __launch_bounds__(256)
void gather_k(const int* __restrict__ idx_in, const float* __restrict__ cb,
              const double* __restrict__ z, ushort* __restrict__ qstb,
              float* __restrict__ out_qst, float* __restrict__ out_idx,
              float* __restrict__ accum)
{
    int row = blockIdx.x, d = threadIdx.x;
    int idx = idx_in[row];
    float  qv = cb[(size_t)idx * DCODE + d];
    double zv = z[(size_t)row * DCODE + d];
    double qs = zv + ((double)qv - zv);
    out_qst[(size_t)row * DCODE + d] = (float)qs;
    bf16 h = __float2bfloat16((float)qs);
    qstb[(size_t)row * DCODE + d] = *(ushort*)&h;
    double diff = (double)qv - zv;
    double s = diff * diff;
    #pragma unroll
    for (int off = 32; off; off >>= 1) s += __shfl_down(s, off, 64);
    __shared__ double sred[4];
    if ((d & 63) == 0) sred[d >> 6] = s;
    __syncthreads();
    if (d == 0) {
        atomicAdd(accum, (float)(sred[0] + sred[1] + sred[2] + sred[3]));
        out_idx[row] = (float)idx;
    }
}

__global__ void loss_k(const float* __restrict__ accum, float* __restrict__ out_loss)
{
    out_loss[0] = 1.25f * accum[0] / 4194304.0f;
}

// ===========================================================================
extern "C" void kernel_launch(void* const* d_in, const int* in_sizes, int n_in,
                              void* d_out, int out_size, void* d_ws, size_t ws_size,
                              hipStream_t stream)
{
    const float* x   = (const float*)d_in[0];
    const float* eW1 = (const float*)d_in[1];
    const float* eb1 = (const float*)d_in[2];
    const float* eW2 = (const float*)d_in[3];
    const float* eb2 = (const float*)d_in[4];
    const float* eW3 = (const float*)d_in[5];
    const float* eb3 = (const float*)d_in[6];
    const float* cbk = (const float*)d_in[7];
    const float* dW1 = (const float*)d_in[8];
    const float* db1 = (const float*)d_in[9];
    const float* dW2 = (const float*)d_in[10];
    const float* db2 = (const float*)d_in[11];
    const float* dW3 = (const float*)d_in[12];
    const float* db3 = (const float*)d_in[13];

    // fixed: decoder Wt1..3 bf16, encoder limb planes eP1..3, c2, accum
    const size_t FIX_W1 = (size_t)1024 * 256 * 2;
    const size_t FIX_W2 = (size_t)2048 * 1024 * 2;
    const size_t FIX_W3 = (size_t)1024 * 2048 * 2;
    const size_t EPS1 = (size_t)3 * 2048 * 1024 * 2;
    const size_t EPS2 = (size_t)3 * 1024 * 2048 * 2;
    const size_t EPS3 = (size_t)3 * 256 * 1024 * 2;
    const size_t FIXED = FIX_W1 + FIX_W2 + FIX_W3 + EPS1 + EPS2 + EPS3 + 8192 + 256;

    // per-row: xpl 6144 | h1pl 12288 | h2pl 6144 | zb 2048 | qstb 512 | idx 4
    int R = BDIM;
    while (R > 256 && (size_t)R * 27140 + FIXED > ws_size) R >>= 1;
    const int nch = BDIM / R;

    char* ws = (char*)d_ws;
    size_t off = 0;
    ushort* xpl  = (ushort*)(ws + off); off += (size_t)R * 6144;  // aliased by dh1b
    ushort* h1pl = (ushort*)(ws + off); off += (size_t)R * 12288; // aliased by dh2b
    ushort* h2pl = (ushort*)(ws + off); off += (size_t)R * 6144;
    double* zb   = (double*)(ws + off); off += (size_t)R * 2048;
    ushort* qstb = (ushort*)(ws + off); off += (size_t)R * 512;
    int*    idxb = (int*)(ws + off);    off += (size_t)R * 4;
    ushort* Wt1  = (ushort*)(ws + off); off += FIX_W1;
    ushort* Wt2  = (ushort*)(ws + off); off += FIX_W2;
    ushort* Wt3  = (ushort*)(ws + off); off += FIX_W3;
    ushort* eP1  = (ushort*)(ws + off); off += EPS1;
    ushort* eP2  = (ushort*)(ws + off); off += EPS2;
    ushort* eP3  = (ushort*)(ws + off); off += EPS3;
    double* c2   = (double*)(ws + off); off += 8192;
    float*  accum = (float*)(ws + off);
    ushort* dh1b = xpl;                  // R x 1024 bf16 (decoder h1)
    ushort* dh2b = h1pl;                 // R x 2048 bf16 (decoder h2)

    float* out      = (float*)d_out;
    float* out_rec  = out;
    float* out_qst  = out + (size_t)BDIM * DIN;
    float* out_loss = out_qst + (size_t)BDIM * DCODE;
    float* out_idx  = out_loss + 1;

    hipMemsetAsync(accum, 0, 16, stream);
    c2_k<<<KCODE, 64, 0, stream>>>(cbk, c2);
    wtrans<<<dim3(1024 / 64,  256 / 64), 256, 0, stream>>>(dW1, Wt1,  256, 1024);
    wtrans<<<dim3(2048 / 64, 1024 / 64), 256, 0, stream>>>(dW2, Wt2, 1024, 2048);
    wtrans<<<dim3(1024 / 64, 2048 / 64), 256, 0, stream>>>(dW3, Wt3, 2048, 1024);
    wsplit<<<dim3(2048 / 64, 1024 / 64), 256, 0, stream>>>(eW1, eP1, 1024, 2048);
    wsplit<<<dim3(1024 / 64, 2048 / 64), 256, 0, stream>>>(eW2, eP2, 2048, 1024);
    wsplit<<<dim3( 256 / 64, 1024 / 64), 256, 0, stream>>>(eW3, eP3, 1024,  256);

    for (int c = 0; c < nch; ++c) {
        const float* xc = x + (size_t)c * R * DIN;
        float* rec_c = out_rec + (size_t)c * R * DIN;
        float* qst_c = out_qst + (size_t)c * R * DCODE;
        float* idx_c = out_idx + (size_t)c * R;

        // encoder: split-bf16 MFMA (6-term limb expansion + f64 folds)
        xsplit<<<R, 256, 0, stream>>>(xc, xpl, (size_t)R * DIN);
        gemms<1, 0><<<dim3(DH1 / 128, R / 128), 512, 0, stream>>>(
            xpl, eP1, eb1, h1pl, R, DH1, DIN,
            (size_t)R * DIN, (size_t)DH1 * DIN, (size_t)R * DH1);
        gemms<1, 0><<<dim3(DH2 / 128, R / 128), 512, 0, stream>>>(
            h1pl, eP2, eb2, h2pl, R, DH2, DH1,
            (size_t)R * DH1, (size_t)DH2 * DH1, (size_t)R * DH2);
        gemms<0, 2><<<dim3(DCODE / 128, R / 128), 512, 0, stream>>>(
            h2pl, eP3, eb3, zb, R, DCODE, DH2,
            (size_t)R * DH2, (size_t)DCODE * DH2, 0);

        // vector quantization (f64)
        dist_k<<<R / 64, 256, 0, stream>>>(zb, cbk, c2, idxb);
        gather_k<<<R, 256, 0, stream>>>(idxb, cbk, zb, qstb, qst_c, idx_c, accum);

        // decoder (bf16 MFMA)
        gemmb<1, 1><<<dim3(DH2 / 128, R / 128), 256, 0, stream>>>(qstb, Wt1, db1, dh1b, R, DH2, DCODE);
        gemmb<1, 1><<<dim3(DH1 / 128, R / 128), 256, 0, stream>>>(dh1b, Wt2, db2, dh2b, R, DH1, DH2);
        gemmb<0, 0><<<dim3(DIN / 128, R / 128), 256, 0, stream>>>(dh2b, Wt3, db3, rec_c, R, DIN, DH1);
    }

    loss_k<<<1, 1, 0, stream>>>(accum, out_loss);
}

// Round 2
// 1785.225 us; speedup vs baseline: 1.9369x; 1.4798x over previous
//
#include <hip/hip_runtime.h>
#include <hip/hip_bf16.h>
#include <stdint.h>

// ===========================================================================
// VQ-VAE forward, MI355X. Round 7: VQ distance+argmin moved to matrix cores.
// R6 = 2642us; top cost was dist_k (f64 VALU GEMM, 2x500us, Occupancy 5.7%,
// 128 blocks on 256 CUs, MfmaUtil=0). Distances are score = c2 - 2*(z.c):
// compute z.c^T with the same 3-limb split-bf16 MFMA machinery as the
// encoder (6 products, f64 folds), fuse argmin into the epilogue, reduce
// partials in a tiny second kernel. Phases restructured: encoder chunks ->
// zsplit -> distm -> reduce8 -> gather (full B) -> decoder chunks.
//
// Numerics: limb-split dot error ~1e-9 on scores (random-sign accum over
// K=256, |z|~0.3, |c|~1e-3) -- same class as the accepted encoder z error
// (~3e-8 abs -> ~1e-9 score). Winner gap ~2e-7. Loss still uses f64 zb.
// Layout: inputs f32; out f32: rec[16384*1024] | qst[16384*256] | loss[1]
// | idx[16384].
// ===========================================================================

#define BDIM  16384
#define DIN   1024
#define DH1   2048
#define DH2   1024
#define DCODE 256
#define KCODE 1024

typedef __hip_bfloat16 bf16;
typedef __attribute__((ext_vector_type(8))) short short8;
typedef __attribute__((ext_vector_type(4))) float f32x4;

// ---------------------------------------------------------------------------
// 3-limb bf16 split: f = h + m + l up to ~2^-24 relative.
// ---------------------------------------------------------------------------
__device__ __forceinline__ void split3(float f, ushort* h, ushort* m, ushort* l)
{
    bf16 bh = __float2bfloat16(f);
    float r1 = f - __bfloat162float(bh);
    bf16 bm = __float2bfloat16(r1);
    float r2 = r1 - __bfloat162float(bm);
    bf16 bl = __float2bfloat16(r2);
    *h = *(ushort*)&bh; *m = *(ushort*)&bm; *l = *(ushort*)&bl;
}

// ---------------------------------------------------------------------------
// split-bf16 MFMA GEMM: C = act(A @ Bt^T + bias), 6-term limb expansion.
// A planes: [M][K] bf16 stride PA; Bt planes: [N][K] bf16 stride PB.
// 128x128 tile, BK=32, 512 thr / 8 waves, wave tile 32x64.
// OUTK: 0 = write 3 bf16 limb planes (stride PC), 2 = f64 out.
// ---------------------------------------------------------------------------
template<int RELU, int OUTK>
__global__ __launch_bounds__(512, 2)
void gemms(const ushort* __restrict__ Apl, const ushort* __restrict__ Bpl,
           const float* __restrict__ bias, void* __restrict__ C,
           int M, int N, int K, size_t PA, size_t PB, size_t PC)
{
    __shared__ __align__(16) short As[3][128][40];
    __shared__ __align__(16) short Bs[3][128][40];
    const int tid  = threadIdx.x;
    const int lane = tid & 63;
    const int wave = tid >> 6;
    const int wm = (wave >> 1) << 5;
    const int wn = (wave & 1) << 6;
    const int fr = lane & 15, fq = lane >> 4;
    const int row0 = blockIdx.y << 7, col0 = blockIdx.x << 7;

    const int sr = tid >> 2, sc = (tid & 3) << 3;

    const ushort* Ag = Apl + (size_t)(row0 + sr) * K + sc;
    const ushort* Bg = Bpl + (size_t)(col0 + sr) * K + sc;

    f32x4  acc[2][4];
    double dacc[2][4][4];
    #pragma unroll
    for (int i = 0; i < 2; ++i)
        #pragma unroll
        for (int j = 0; j < 4; ++j) {
            acc[i][j] = (f32x4)0.0f;
            #pragma unroll
            for (int r = 0; r < 4; ++r) dacc[i][j][r] = 0.0;
        }

    short8 sa[3], sb[3];
    #pragma unroll
    for (int p = 0; p < 3; ++p) {
        sa[p] = *(const short8*)(Ag + (size_t)p * PA);
        sb[p] = *(const short8*)(Bg + (size_t)p * PB);
    }

    const int nsteps = K >> 5;
    for (int s = 0; s < nsteps; ++s) {
        __syncthreads();
        #pragma unroll
        for (int p = 0; p < 3; ++p) {
            *(short8*)&As[p][sr][sc] = sa[p];
            *(short8*)&Bs[p][sr][sc] = sb[p];
        }
        __syncthreads();
        if (s + 1 < nsteps) {
            const int kb = (s + 1) << 5;
            #pragma unroll
            for (int p = 0; p < 3; ++p) {
                sa[p] = *(const short8*)(Ag + (size_t)p * PA + kb);
                sb[p] = *(const short8*)(Bg + (size_t)p * PB + kb);
            }
        }

        short8 bh[4], bm[4], bl[4];
        #pragma unroll
        for (int j = 0; j < 4; ++j) {
            const int bn = wn + (j << 4) + fr;
            bh[j] = *(const short8*)&Bs[0][bn][fq << 3];
            bm[j] = *(const short8*)&Bs[1][bn][fq << 3];
            bl[j] = *(const short8*)&Bs[2][bn][fq << 3];
        }
        #pragma unroll
        for (int i = 0; i < 2; ++i) {
            const int an = wm + (i << 4) + fr;
            short8 ah = *(const short8*)&As[0][an][fq << 3];
            short8 am = *(const short8*)&As[1][an][fq << 3];
            short8 al = *(const short8*)&As[2][an][fq << 3];
            #pragma unroll
            for (int j = 0; j < 4; ++j) {
                acc[i][j] = __builtin_amdgcn_mfma_f32_16x16x32_bf16(ah, bh[j], acc[i][j], 0, 0, 0);
                acc[i][j] = __builtin_amdgcn_mfma_f32_16x16x32_bf16(ah, bm[j], acc[i][j], 0, 0, 0);
                acc[i][j] = __builtin_amdgcn_mfma_f32_16x16x32_bf16(am, bh[j], acc[i][j], 0, 0, 0);
                acc[i][j] = __builtin_amdgcn_mfma_f32_16x16x32_bf16(ah, bl[j], acc[i][j], 0, 0, 0);
                acc[i][j] = __builtin_amdgcn_mfma_f32_16x16x32_bf16(al, bh[j], acc[i][j], 0, 0, 0);
                acc[i][j] = __builtin_amdgcn_mfma_f32_16x16x32_bf16(am, bm[j], acc[i][j], 0, 0, 0);
            }
        }

        if (s & 1) {
            #pragma unroll
            for (int i = 0; i < 2; ++i)
                #pragma unroll
                for (int j = 0; j < 4; ++j) {
                    #pragma unroll
                    for (int r = 0; r < 4; ++r) dacc[i][j][r] += (double)acc[i][j][r];
                    acc[i][j] = (f32x4)0.0f;
                }
        }
    }
    #pragma unroll
    for (int i = 0; i < 2; ++i)
        #pragma unroll
        for (int j = 0; j < 4; ++j)
            #pragma unroll
            for (int r = 0; r < 4; ++r) dacc[i][j][r] += (double)acc[i][j][r];

    #pragma unroll
    for (int j = 0; j < 4; ++j) {
        const int n = col0 + wn + (j << 4) + fr;
        const double bv = (double)bias[n];
        #pragma unroll
        for (int i = 0; i < 2; ++i) {
            const int mb = row0 + wm + (i << 4) + (fq << 2);
            #pragma unroll
            for (int r = 0; r < 4; ++r) {
                double v = dacc[i][j][r] + bv;
                if (RELU) v = v > 0.0 ? v : 0.0;
                const size_t o = (size_t)(mb + r) * N + n;
                if (OUTK == 2) {
                    ((double*)C)[o] = v;
                } else {
                    ushort h, m, l;
                    split3((float)v, &h, &m, &l);
                    ushort* Cp = (ushort*)C;
                    Cp[o] = h; Cp[PC + o] = m; Cp[2 * PC + o] = l;
                }
            }
        }
    }
}

// ---------------------------------------------------------------------------
// split-bf16 MFMA distance + fused argmin. Zpl: [3][BDIM][DCODE] bf16 limb
// planes of z; Cpl: [3][KCODE][DCODE] limb planes of codebook.
// score[b][n] = c2[n] - 2 * (z_b . c_n). Per block: 128 rows x 128 codes;
// epilogue reduces argmin over the code tile -> partials [row][KCODE/128].
// ---------------------------------------------------------------------------
__global__ __launch_bounds__(512, 2)
void distm(const ushort* __restrict__ Zpl, const ushort* __restrict__ Cpl,
           const double* __restrict__ c2, double* __restrict__ psc,
           int* __restrict__ pix)
{
    __shared__ __align__(16) short As[3][128][40];
    __shared__ __align__(16) short Bs[3][128][40];
    const int tid  = threadIdx.x;
    const int lane = tid & 63;
    const int wave = tid >> 6;
    const int wm = (wave >> 1) << 5;
    const int wn = (wave & 1) << 6;
    const int fr = lane & 15, fq = lane >> 4;
    const int row0 = blockIdx.y << 7, col0 = blockIdx.x << 7;
    const int sr = tid >> 2, sc = (tid & 3) << 3;
    const size_t PZ = (size_t)BDIM * DCODE;
    const size_t PC = (size_t)KCODE * DCODE;

    const ushort* Ag = Zpl + (size_t)(row0 + sr) * DCODE + sc;
    const ushort* Bg = Cpl + (size_t)(col0 + sr) * DCODE + sc;

    f32x4  acc[2][4];
    double dacc[2][4][4];
    #pragma unroll
    for (int i = 0; i < 2; ++i)
        #pragma unroll
        for (int j = 0; j < 4; ++j) {
            acc[i][j] = (f32x4)0.0f;
            #pragma unroll
            for (int r = 0; r < 4; ++r) dacc[i][j][r] = 0.0;
        }

    short8 sa[3], sb[3];
    #pragma unroll
    for (int p = 0; p < 3; ++p) {
        sa[p] = *(const short8*)(Ag + (size_t)p * PZ);
        sb[p] = *(const short8*)(Bg + (size_t)p * PC);
    }

    const int nsteps = DCODE >> 5;   // 8
    for (int s = 0; s < nsteps; ++s) {
        __syncthreads();
        #pragma unroll
        for (int p = 0; p < 3; ++p) {
            *(short8*)&As[p][sr][sc] = sa[p];
            *(short8*)&Bs[p][sr][sc] = sb[p];
        }
        __syncthreads();
        if (s + 1 < nsteps) {
            const int kb = (s + 1) << 5;
            #pragma unroll
            for (int p = 0; p < 3; ++p) {
                sa[p] = *(const short8*)(Ag + (size_t)p * PZ + kb);
                sb[p] = *(const short8*)(Bg + (size_t)p * PC + kb);
            }
        }

        short8 bh[4], bm[4], bl[4];
        #pragma unroll
        for (int j = 0; j < 4; ++j) {
            const int bn = wn + (j << 4) + fr;
            bh[j] = *(const short8*)&Bs[0][bn][fq << 3];
            bm[j] = *(const short8*)&Bs[1][bn][fq << 3];
            bl[j] = *(const short8*)&Bs[2][bn][fq << 3];
        }
        #pragma unroll
        for (int i = 0; i < 2; ++i) {
            const int an = wm + (i << 4) + fr;
            short8 ah = *(const short8*)&As[0][an][fq << 3];
            short8 am = *(const short8*)&As[1][an][fq << 3];
            short8 al = *(const short8*)&As[2][an][fq << 3];
            #pragma unroll
            for (int j = 0; j < 4; ++j) {
                acc[i][j] = __builtin_amdgcn_mfma_f32_16x16x32_bf16(ah, bh[j], acc[i][j], 0, 0, 0);
                acc[i][j] = __builtin_amdgcn_mfma_f32_16x16x32_bf16(ah, bm[j], acc[i][j], 0, 0, 0);
                acc[i][j] = __builtin_amdgcn_mfma_f32_16x16x32_bf16(am, bh[j], acc[i][j], 0, 0, 0);
                acc[i][j] = __builtin_amdgcn_mfma_f32_16x16x32_bf16(ah, bl[j], acc[i][j], 0, 0, 0);
                acc[i][j] = __builtin_amdgcn_mfma_f32_16x16x32_bf16(al, bh[j], acc[i][j], 0, 0, 0);
                acc[i][j] = __builtin_amdgcn_mfma_f32_16x16x32_bf16(am, bm[j], acc[i][j], 0, 0, 0);
            }
        }

        if (s & 1) {
            #pragma unroll
            for (int i = 0; i < 2; ++i)
                #pragma unroll
                for (int j = 0; j < 4; ++j) {
                    #pragma unroll
                    for (int r = 0; r < 4; ++r) dacc[i][j][r] += (double)acc[i][j][r];
                    acc[i][j] = (f32x4)0.0f;
                }
        }
    }
    #pragma unroll
    for (int i = 0; i < 2; ++i)
        #pragma unroll
        for (int j = 0; j < 4; ++j)
            #pragma unroll
            for (int r = 0; r < 4; ++r) dacc[i][j][r] += (double)acc[i][j][r];

    // --- fused argmin epilogue ---
    __syncthreads();                       // As dead; reuse as reduce buffer
    double* scb = (double*)&As[0][0][0];   // [128][2] scores
    int*    sib = (int*)(scb + 256);       // [128][2] indices

    #pragma unroll
    for (int i = 0; i < 2; ++i) {
        #pragma unroll
        for (int r = 0; r < 4; ++r) {
            double bs = 1e300; int bi = 0;
            #pragma unroll
            for (int j = 0; j < 4; ++j) {
                const int n = col0 + wn + (j << 4) + fr;
                const double s = c2[n] - 2.0 * dacc[i][j][r];
                if (s < bs) { bs = s; bi = n; }   // j ascending => lowest idx on tie
            }
            #pragma unroll
            for (int msk = 1; msk < 16; msk <<= 1) {
                double os = __shfl_xor(bs, msk, 64);
                int    oi = __shfl_xor(bi, msk, 64);
                if (os < bs || (os == bs && oi < bi)) { bs = os; bi = oi; }
            }
            if (fr == 0) {
                const int lr = wm + (i << 4) + (fq << 2) + r;
                scb[lr * 2 + (wave & 1)] = bs;
                sib[lr * 2 + (wave & 1)] = bi;
            }
        }
    }
    __syncthreads();
    if (tid < 128) {
        double s0 = scb[tid * 2], s1 = scb[tid * 2 + 1];
        int    i0 = sib[tid * 2], i1 = sib[tid * 2 + 1];
        const bool t1 = (s1 < s0) || (s1 == s0 && i1 < i0);
        const size_t o = (size_t)(row0 + tid) * (KCODE / 128) + blockIdx.x;
        psc[o] = t1 ? s1 : s0;
        pix[o] = t1 ? i1 : i0;
    }
}

// ---------------------------------------------------------------------------
// reduce partial argmins: [row][8] -> idx
// ---------------------------------------------------------------------------
__global__ __launch_bounds__(256)
void reduce8(const double* __restrict__ psc, const int* __restrict__ pix,
             int* __restrict__ idx_out)
{
    const int row = blockIdx.x * 256 + threadIdx.x;
    const double* ps = psc + (size_t)row * (KCODE / 128);
    const int*    pi = pix + (size_t)row * (KCODE / 128);
    double m = ps[0]; int mi = pi[0];
    #pragma unroll
    for (int t = 1; t < KCODE / 128; ++t) {
        double s = ps[t]; int c = pi[t];
        if (s < m || (s == m && c < mi)) { m = s; mi = c; }
    }
    idx_out[row] = mi;
}

// ---------------------------------------------------------------------------
// z (f64) -> 3 bf16 limb planes, plane stride P
// ---------------------------------------------------------------------------
__global__ __launch_bounds__(256)
void zsplit(const double* __restrict__ z, ushort* __restrict__ Zp, size_t P)
{
    const size_t i = ((size_t)blockIdx.x * 256 + threadIdx.x) << 1;
    double2 v = *(const double2*)(z + i);
    ushort h[2], m[2], l[2];
    split3((float)v.x, &h[0], &m[0], &l[0]);
    split3((float)v.y, &h[1], &m[1], &l[1]);
    *(ushort2*)(Zp + i)         = make_ushort2(h[0], h[1]);
    *(ushort2*)(Zp + P + i)     = make_ushort2(m[0], m[1]);
    *(ushort2*)(Zp + 2 * P + i) = make_ushort2(l[0], l[1]);
}

// ---------------------------------------------------------------------------
// bf16 MFMA GEMM (decoder, unchanged): C = act(A @ Bt^T + bias).
// ---------------------------------------------------------------------------
template<int RELU, int OUTBF>
__global__ __launch_bounds__(256)
void gemmb(const ushort* __restrict__ A, const ushort* __restrict__ Bt,
           const float* __restrict__ bias, void* __restrict__ C,
           int M, int N, int K)
{
    __shared__ __align__(16) short As[128][40];
    __shared__ __align__(16) short Bs[128][40];
    const int tid  = threadIdx.x;
    const int lane = tid & 63;
    const int wave = tid >> 6;
    const int wm = (wave >> 1) << 6, wn = (wave & 1) << 6;
    const int fr = lane & 15;
    const int fq = lane >> 4;
    const int row0 = blockIdx.y << 7, col0 = blockIdx.x << 7;

    const int sr = tid >> 1, sh = (tid & 1) << 4;

    const ushort* Ag = A  + (size_t)(row0 + sr) * K + sh;
    const ushort* Bg = Bt + (size_t)(col0 + sr) * K + sh;

    f32x4 acc[4][4];
    #pragma unroll
    for (int i = 0; i < 4; ++i)
        #pragma unroll
        for (int j = 0; j < 4; ++j) acc[i][j] = (f32x4)0.0f;

    for (int kb = 0; kb < K; kb += 32) {
        short8 a0 = *(const short8*)(Ag + kb);
        short8 a1 = *(const short8*)(Ag + kb + 8);
        short8 b0 = *(const short8*)(Bg + kb);
        short8 b1 = *(const short8*)(Bg + kb + 8);
        __syncthreads();
        *(short8*)&As[sr][sh]     = a0;
        *(short8*)&As[sr][sh + 8] = a1;
        *(short8*)&Bs[sr][sh]     = b0;
        *(short8*)&Bs[sr][sh + 8] = b1;
        __syncthreads();

        short8 af[4], bf[4];
        #pragma unroll
        for (int i = 0; i < 4; ++i)
            af[i] = *(const short8*)&As[wm + (i << 4) + fr][fq << 3];
        #pragma unroll
        for (int j = 0; j < 4; ++j)
            bf[j] = *(const short8*)&Bs[wn + (j << 4) + fr][fq << 3];
        #pragma unroll
        for (int i = 0; i < 4; ++i)
            #pragma unroll
            for (int j = 0; j < 4; ++j)
                acc[i][j] = __builtin_amdgcn_mfma_f32_16x16x32_bf16(
                                af[i], bf[j], acc[i][j], 0, 0, 0);
    }

    #pragma unroll
    for (int j = 0; j < 4; ++j) {
        const int n = col0 + wn + (j << 4) + fr;
        const float bv = bias[n];
        #pragma unroll
        for (int i = 0; i < 4; ++i) {
            const int mb = row0 + wm + (i << 4) + (fq << 2);
            #pragma unroll
            for (int r = 0; r < 4; ++r) {
                float v = acc[i][j][r] + bv;
                if (RELU) v = fmaxf(v, 0.0f);
                size_t o = (size_t)(mb + r) * N + n;
                if (OUTBF) ((bf16*)C)[o]  = __float2bfloat16(v);
                else       ((float*)C)[o] = v;
            }
        }
    }
}

// ---------------------------------------------------------------------------
// decoder weight transpose + f32->bf16 (unchanged)
// ---------------------------------------------------------------------------
__global__ __launch_bounds__(256)
void wtrans(const float* __restrict__ W, ushort* __restrict__ Wt, int K, int N)
{
    __shared__ float tile[64][65];
    const int tid = threadIdx.x;
    const int kb = blockIdx.y << 6, nb = blockIdx.x << 6;
    const int r = tid >> 4, c4 = (tid & 15) << 2;
    #pragma unroll
    for (int s = 0; s < 4; ++s) {
        float4 v = *(const float4*)(W + (size_t)(kb + r + (s << 4)) * N + nb + c4);
        tile[r + (s << 4)][c4 + 0] = v.x; tile[r + (s << 4)][c4 + 1] = v.y;
        tile[r + (s << 4)][c4 + 2] = v.z; tile[r + (s << 4)][c4 + 3] = v.w;
    }
    __syncthreads();
    #pragma unroll
    for (int s = 0; s < 4; ++s) {
        const int n = r + (s << 4);
        ushort u[4];
        #pragma unroll
        for (int l = 0; l < 4; ++l) {
            bf16 h = __float2bfloat16(tile[c4 + l][n]);
            u[l] = *(ushort*)&h;
        }
        *(ushort4*)(Wt + (size_t)(nb + n) * K + kb + c4) = make_ushort4(u[0], u[1], u[2], u[3]);
    }
}

// ---------------------------------------------------------------------------
// encoder weight transpose + 3-limb split: planes [N][K], stride N*K
// ---------------------------------------------------------------------------
__global__ __launch_bounds__(256)
void wsplit(const float* __restrict__ W, ushort* __restrict__ Wt, int K, int N)
{
    __shared__ float tile[64][65];
    const int tid = threadIdx.x;
    const int kb = blockIdx.y << 6, nb = blockIdx.x << 6;
    const int r = tid >> 4, c4 = (tid & 15) << 2;
    const size_t NK = (size_t)N * K;
    #pragma unroll
    for (int s = 0; s < 4; ++s) {
        float4 v = *(const float4*)(W + (size_t)(kb + r + (s << 4)) * N + nb + c4);
        tile[r + (s << 4)][c4 + 0] = v.x; tile[r + (s << 4)][c4 + 1] = v.y;
        tile[r + (s << 4)][c4 + 2] = v.z; tile[r + (s << 4)][c4 + 3] = v.w;
    }
    __syncthreads();
    #pragma unroll
    for (int s = 0; s < 4; ++s) {
        const int n = r + (s << 4);
        ushort h[4], m[4], l[4];
        #pragma unroll
        for (int e = 0; e < 4; ++e) split3(tile[c4 + e][n], &h[e], &m[e], &l[e]);
        const size_t o = (size_t)(nb + n) * K + kb + c4;
        *(ushort4*)(Wt + o)          = make_ushort4(h[0], h[1], h[2], h[3]);
        *(ushort4*)(Wt + NK + o)     = make_ushort4(m[0], m[1], m[2], m[3]);
        *(ushort4*)(Wt + 2 * NK + o) = make_ushort4(l[0], l[1], l[2], l[3]);
    }
}

// ---------------------------------------------------------------------------
// f32 row-major -> 3 bf16 limb planes, plane stride P (also used for cbk)
// ---------------------------------------------------------------------------
__global__ __launch_bounds__(256)
void xsplit(const float* __restrict__ X, ushort* __restrict__ Xp, size_t P)
{
    const size_t i = ((size_t)blockIdx.x * 256 + threadIdx.x) << 2;
    float4 v = *(const float4*)(X + i);
    ushort h[4], m[4], l[4];
    split3(v.x, &h[0], &m[0], &l[0]);
    split3(v.y, &h[1], &m[1], &l[1]);
    split3(v.z, &h[2], &m[2], &l[2]);
    split3(v.w, &h[3], &m[3], &l[3]);
    *(ushort4*)(Xp + i)         = make_ushort4(h[0], h[1], h[2], h[3]);
    *(ushort4*)(Xp + P + i)     = make_ushort4(m[0], m[1], m[2], m[3]);
    *(ushort4*)(Xp + 2 * P + i) = make_ushort4(l[0], l[1], l[2], l[3]);
}

// ---------------------------------------------------------------------------
// codebook squared norms (f64)
// ---------------------------------------------------------------------------
__global__ __launch_bounds__(64)
void c2_k(const float* __restrict__ cb, double* __restrict__ c2)
{
    int code = blockIdx.x, l = threadIdx.x;
    float4 v = *(const float4*)(cb + (size_t)code * DCODE + (l << 2));
    double s = (double)v.x * v.x + (double)v.y * v.y
             + (double)v.z * v.z + (double)v.w * v.w;
    #pragma unroll
    for (int off = 32; off; off >>= 1) s += __shfl_down(s, off, 64);
    if (l == 0) c2[code] = s;
}

// ---------------------------------------------------------------------------
// gather + straight-through + loss partials + idx (unchanged)
// ---------------------------------------------------------------------------
__global__ __launch_bounds__(256)
void gather_k(const int* __restrict__ idx_in, const float* __restrict__ cb,
              const double* __restrict__ z, ushort* __restrict__ qstb,
              float* __restrict__ out_qst, float* __restrict__ out_idx,
              float* __restrict__ accum)
{
    int row = blockIdx.x, d = threadIdx.x;
    int idx = idx_in[row];
    float  qv = cb[(size_t)idx * DCODE + d];
    double zv = z[(size_t)row * DCODE + d];
    double qs = zv + ((double)qv - zv);
    out_qst[(size_t)row * DCODE + d] = (float)qs;
    bf16 h = __float2bfloat16((float)qs);
    qstb[(size_t)row * DCODE + d] = *(ushort*)&h;
    double diff = (double)qv - zv;
    double s = diff * diff;
    #pragma unroll
    for (int off = 32; off; off >>= 1) s += __shfl_down(s, off, 64);
    __shared__ double sred[4];
    if ((d & 63) == 0) sred[d >> 6] = s;
    __syncthreads();
    if (d == 0) {
        atomicAdd(accum, (float)(sred[0] + sred[1] + sred[2] + sred[3]));
        out_idx[row] = (float)idx;
    }
}

__global__ void loss_k(const float* __restrict__ accum, float* __restrict__ out_loss)
{
    out_loss[0] = 1.25f * accum[0] / 4194304.0f;
}

// ===========================================================================
extern "C" void kernel_launch(void* const* d_in, const int* in_sizes, int n_in,
                              void* d_out, int out_size, void* d_ws, size_t ws_size,
                              hipStream_t stream)
{
    const float* x   = (const float*)d_in[0];
    const float* eW1 = (const float*)d_in[1];
    const float* eb1 = (const float*)d_in[2];
    const float* eW2 = (const float*)d_in[3];
    const float* eb2 = (const float*)d_in[4];
    const float* eW3 = (const float*)d_in[5];
    const float* eb3 = (const float*)d_in[6];
    const float* cbk = (const float*)d_in[7];
    const float* dW1 = (const float*)d_in[8];
    const float* db1 = (const float*)d_in[9];
    const float* dW2 = (const float*)d_in[10];
    const float* db2 = (const float*)d_in[11];
    const float* dW3 = (const float*)d_in[12];
    const float* db3 = (const float*)d_in[13];

    // --- sizes ---
    const size_t EPS1 = (size_t)3 * 2048 * 1024 * 2;   // 12.6 MB
    const size_t EPS2 = (size_t)3 * 1024 * 2048 * 2;   // 12.6 MB
    const size_t EPS3 = (size_t)3 * 256 * 1024 * 2;    // 1.6 MB
    const size_t EPS  = EPS1 + EPS2 + EPS3;
    const size_t FIX_W1 = (size_t)1024 * 256 * 2;
    const size_t FIX_W2 = (size_t)2048 * 1024 * 2;
    const size_t FIX_W3 = (size_t)1024 * 2048 * 2;
    const size_t ZB   = (size_t)BDIM * DCODE * 8;      // 33.6 MB (f64 z)
    const size_t QSTB = (size_t)BDIM * DCODE * 2;      // 8.4 MB
    const size_t IDXB = (size_t)BDIM * 4;
    const size_t NPT  = KCODE / 128;                   // 8 code tiles
    const size_t PSCB = (size_t)BDIM * NPT * 8;
    const size_t PIXB = (size_t)BDIM * NPT * 4;
    const size_t CBPB = (size_t)3 * KCODE * DCODE * 2; // 1.6 MB
    const size_t ZPLB = (size_t)3 * BDIM * DCODE * 2;  // 25.2 MB (< EPS)

    const size_t PERSIST = FIX_W1 + FIX_W2 + FIX_W3 + ZB + QSTB + IDXB
                         + PSCB + PIXB + CBPB + 8192 + 256;

    // regionA = [eP1|eP2|eP3|xpl|h1pl|h2pl]; reused for zpl (phase 2) and
    // decoder dh1b/dh2b (phase 4, aliasing xpl/h1pl). per-row chunk = 24576 B.
    int R = BDIM;
    while (R > 256 && PERSIST + EPS + (size_t)R * 24576 > ws_size) R >>= 1;
    const int nch = BDIM / R;

    char* ws = (char*)d_ws;
    size_t off = 0;
    ushort* eP1  = (ushort*)(ws + off); off += EPS1;
    ushort* eP2  = (ushort*)(ws + off); off += EPS2;
    ushort* eP3  = (ushort*)(ws + off); off += EPS3;
    ushort* xpl  = (ushort*)(ws + off); off += (size_t)R * 6144;
    ushort* h1pl = (ushort*)(ws + off); off += (size_t)R * 12288;
    ushort* h2pl = (ushort*)(ws + off); off += (size_t)R * 6144;
    ushort* zpl  = (ushort*)eP1;          // phase 2 alias (ZPLB < EPS)
    ushort* dh1b = xpl;                   // phase 4 alias: R x 1024 bf16
    ushort* dh2b = h1pl;                  // phase 4 alias: R x 2048 bf16
    ushort* Wt1  = (ushort*)(ws + off); off += FIX_W1;
    ushort* Wt2  = (ushort*)(ws + off); off += FIX_W2;
    ushort* Wt3  = (ushort*)(ws + off); off += FIX_W3;
    double* zb   = (double*)(ws + off); off += ZB;
    ushort* qstb = (ushort*)(ws + off); off += QSTB;
    int*    idxb = (int*)(ws + off);    off += IDXB;
    double* psc  = (double*)(ws + off); off += PSCB;
    int*    pix  = (int*)(ws + off);    off += PIXB;
    ushort* cbP  = (ushort*)(ws + off); off += CBPB;
    double* c2   = (double*)(ws + off); off += 8192;
    float*  accum = (float*)(ws + off);

    float* out      = (float*)d_out;
    float* out_rec  = out;
    float* out_qst  = out + (size_t)BDIM * DIN;
    float* out_loss = out_qst + (size_t)BDIM * DCODE;
    float* out_idx  = out_loss + 1;

    hipMemsetAsync(accum, 0, 16, stream);
    c2_k<<<KCODE, 64, 0, stream>>>(cbk, c2);
    wtrans<<<dim3(1024 / 64,  256 / 64), 256, 0, stream>>>(dW1, Wt1,  256, 1024);
    wtrans<<<dim3(2048 / 64, 1024 / 64), 256, 0, stream>>>(dW2, Wt2, 1024, 2048);
    wtrans<<<dim3(1024 / 64, 2048 / 64), 256, 0, stream>>>(dW3, Wt3, 2048, 1024);
    wsplit<<<dim3(2048 / 64, 1024 / 64), 256, 0, stream>>>(eW1, eP1, 1024, 2048);
    wsplit<<<dim3(1024 / 64, 2048 / 64), 256, 0, stream>>>(eW2, eP2, 2048, 1024);
    wsplit<<<dim3( 256 / 64, 1024 / 64), 256, 0, stream>>>(eW3, eP3, 1024,  256);
    xsplit<<<(KCODE * DCODE) / 1024, 256, 0, stream>>>(cbk, cbP, (size_t)KCODE * DCODE);

    // phase 1: encoder chunks -> full-size zb
    for (int c = 0; c < nch; ++c) {
        const float* xc = x + (size_t)c * R * DIN;
        double* zb_c = zb + (size_t)c * R * DCODE;
        xsplit<<<R, 256, 0, stream>>>(xc, xpl, (size_t)R * DIN);
        gemms<1, 0><<<dim3(DH1 / 128, R / 128), 512, 0, stream>>>(
            xpl, eP1, eb1, h1pl, R, DH1, DIN,
            (size_t)R * DIN, (size_t)DH1 * DIN, (size_t)R * DH1);
        gemms<1, 0><<<dim3(DH2 / 128, R / 128), 512, 0, stream>>>(
            h1pl, eP2, eb2, h2pl, R, DH2, DH1,
            (size_t)R * DH1, (size_t)DH2 * DH1, (size_t)R * DH2);
        gemms<0, 2><<<dim3(DCODE / 128, R / 128), 512, 0, stream>>>(
            h2pl, eP3, eb3, zb_c, R, DCODE, DH2,
            (size_t)R * DH2, (size_t)DCODE * DH2, 0);
    }

    // phase 2: VQ on matrix cores, full batch
    zsplit<<<(BDIM * DCODE) / 512, 256, 0, stream>>>(zb, zpl, (size_t)BDIM * DCODE);
    distm<<<dim3(KCODE / 128, BDIM / 128), 512, 0, stream>>>(zpl, cbP, c2, psc, pix);
    reduce8<<<BDIM / 256, 256, 0, stream>>>(psc, pix, idxb);

    // phase 3: gather + loss, full batch
    gather_k<<<BDIM, 256, 0, stream>>>(idxb, cbk, zb, qstb, out_qst, out_idx, accum);

    // phase 4: decoder chunks (reuse regionA chunk buffers)
    for (int c = 0; c < nch; ++c) {
        const ushort* qst_c = qstb + (size_t)c * R * DCODE;
        float* rec_c = out_rec + (size_t)c * R * DIN;
        gemmb<1, 1><<<dim3(DH2 / 128, R / 128), 256, 0, stream>>>(qst_c, Wt1, db1, dh1b, R, DH2, DCODE);
        gemmb<1, 1><<<dim3(DH1 / 128, R / 128), 256, 0, stream>>>(dh1b, Wt2, db2, dh2b, R, DH1, DH2);
        gemmb<0, 0><<<dim3(DIN / 128, R / 128), 256, 0, stream>>>(dh2b, Wt3, db3, rec_c, R, DIN, DH1);
    }

    loss_k<<<1, 1, 0, stream>>>(accum, out_loss);
}

// Round 3
// 1720.907 us; speedup vs baseline: 2.0093x; 1.0374x over previous
//
#include <hip/hip_runtime.h>
#include <hip/hip_bf16.h>
#include <stdint.h>

// ===========================================================================
// VQ-VAE forward, MI355X. Round 8: LDS writes off the critical pipe.
// R7 = 1785us; gemms was LDS-BW-bound (reads 434K + writes 144K + 123K
// conflict cyc vs 617K total; MFMA 77%). This round: global_load_lds DMA
// staging (m97 pattern) with linear [128][32] LDS + XOR slot swizzle
// (slot ^= (row>>1)&3) applied on BOTH global source addr and fragment
// reads. Applied to encoder gemms AND new decoder gemmb2. zsplit fused
// into gemm3 epilogue (OUTK=3). gather_k atomics -> per-block partials.
//
// Numerics unchanged from R7 (3-limb split-bf16, 6 products, f64 folds
// every 2 K-steps; distances via limb MFMA + c2; loss from f64 z).
// Layout: inputs f32; out f32: rec[16384*1024] | qst[16384*256] | loss[1]
// | idx[16384].
// ===========================================================================

#define BDIM  16384
#define DIN   1024
#define DH1   2048
#define DH2   1024
#define DCODE 256
#define KCODE 1024

typedef __hip_bfloat16 bf16;
typedef __attribute__((ext_vector_type(8))) short short8;
typedef __attribute__((ext_vector_type(4))) float f32x4;

// ---------------------------------------------------------------------------
// async global->LDS, 16B per lane (wave-uniform LDS base + lane*16)
// ---------------------------------------------------------------------------
__device__ __forceinline__ void gload16(const void* g, void* l)
{
    __builtin_amdgcn_global_load_lds(
        (const __attribute__((address_space(1))) unsigned int*)g,
        (__attribute__((address_space(3))) unsigned int*)l, 16, 0, 0);
}

// ---------------------------------------------------------------------------
// 3-limb bf16 split: f = h + m + l up to ~2^-24 relative.
// ---------------------------------------------------------------------------
__device__ __forceinline__ void split3(float f, ushort* h, ushort* m, ushort* l)
{
    bf16 bh = __float2bfloat16(f);
    float r1 = f - __bfloat162float(bh);
    bf16 bm = __float2bfloat16(r1);
    float r2 = r1 - __bfloat162float(bm);
    bf16 bl = __float2bfloat16(r2);
    *h = *(ushort*)&bh; *m = *(ushort*)&bm; *l = *(ushort*)&bl;
}

// ---------------------------------------------------------------------------
// split-bf16 MFMA GEMM with global_load_lds staging.
// A planes: [M][K] bf16 stride PA; Bt planes: [N][K] bf16 stride PB.
// 128x128 tile, BK=32, 512 thr / 8 waves, wave tile 32x64.
// LDS: linear [3][128][32], slot swizzle: phys = logical ^ ((row>>1)&3).
// OUTK: 0 = 3 limb planes (stride PC); 2 = f64; 3 = f64 + 3 limb planes
// (C2, stride PC).
// ---------------------------------------------------------------------------
template<int RELU, int OUTK>
__global__ __launch_bounds__(512, 2)
void gemms(const ushort* __restrict__ Apl, const ushort* __restrict__ Bpl,
           const float* __restrict__ bias, void* __restrict__ C,
           void* __restrict__ C2,
           int M, int N, int K, size_t PA, size_t PB, size_t PC)
{
    __shared__ __align__(16) short As[3][128][32];
    __shared__ __align__(16) short Bs[3][128][32];
    const int tid  = threadIdx.x;
    const int lane = tid & 63;
    const int wave = tid >> 6;                 // 0..7
    const int wm = (wave >> 1) << 5;           // {0,32,64,96}
    const int wn = (wave & 1) << 6;            // {0,64}
    const int fr = lane & 15, fq = lane >> 4;
    const int row0 = blockIdx.y << 7, col0 = blockIdx.x << 7;

    // staging: wave w covers rows [16w,16w+16) of each (matrix,plane)
    const int srow = (wave << 4) + (lane >> 2);      // 0..127
    const int sslot = lane & 3;                      // physical 8-short slot
    const int skg = (sslot ^ ((srow >> 1) & 3)) << 3; // logical k offset

    const ushort* AgT = Apl + (size_t)(row0 + srow) * K + skg;
    const ushort* BgT = Bpl + (size_t)(col0 + srow) * K + skg;

    f32x4  acc[2][4];
    double dacc[2][4][4];
    #pragma unroll
    for (int i = 0; i < 2; ++i)
        #pragma unroll
        for (int j = 0; j < 4; ++j) {
            acc[i][j] = (f32x4)0.0f;
            #pragma unroll
            for (int r = 0; r < 4; ++r) dacc[i][j][r] = 0.0;
        }

    const int nsteps = K >> 5;
    for (int s = 0; s < nsteps; ++s) {
        const int kb = s << 5;
        #pragma unroll
        for (int p = 0; p < 3; ++p) {
            gload16(AgT + (size_t)p * PA + kb, &As[p][wave << 4][0]);
            gload16(BgT + (size_t)p * PB + kb, &Bs[p][wave << 4][0]);
        }
        __syncthreads();   // drains vmcnt (loads) + all waves arrived

        short8 bh[4], bm[4], bl[4];
        #pragma unroll
        for (int j = 0; j < 4; ++j) {
            const int bn = wn + (j << 4) + fr;
            const int bs = (fq ^ ((bn >> 1) & 3)) << 3;
            bh[j] = *(const short8*)&Bs[0][bn][bs];
            bm[j] = *(const short8*)&Bs[1][bn][bs];
            bl[j] = *(const short8*)&Bs[2][bn][bs];
        }
        #pragma unroll
        for (int i = 0; i < 2; ++i) {
            const int an = wm + (i << 4) + fr;
            const int asl = (fq ^ ((an >> 1) & 3)) << 3;
            short8 ah = *(const short8*)&As[0][an][asl];
            short8 am = *(const short8*)&As[1][an][asl];
            short8 al = *(const short8*)&As[2][an][asl];
            #pragma unroll
            for (int j = 0; j < 4; ++j) {
                acc[i][j] = __builtin_amdgcn_mfma_f32_16x16x32_bf16(ah, bh[j], acc[i][j], 0, 0, 0);
                acc[i][j] = __builtin_amdgcn_mfma_f32_16x16x32_bf16(ah, bm[j], acc[i][j], 0, 0, 0);
                acc[i][j] = __builtin_amdgcn_mfma_f32_16x16x32_bf16(am, bh[j], acc[i][j], 0, 0, 0);
                acc[i][j] = __builtin_amdgcn_mfma_f32_16x16x32_bf16(ah, bl[j], acc[i][j], 0, 0, 0);
                acc[i][j] = __builtin_amdgcn_mfma_f32_16x16x32_bf16(al, bh[j], acc[i][j], 0, 0, 0);
                acc[i][j] = __builtin_amdgcn_mfma_f32_16x16x32_bf16(am, bm[j], acc[i][j], 0, 0, 0);
            }
        }

        if (s & 1) {   // fold f32 acc into f64 shadow every 2 K-steps (64 K)
            #pragma unroll
            for (int i = 0; i < 2; ++i)
                #pragma unroll
                for (int j = 0; j < 4; ++j) {
                    #pragma unroll
                    for (int r = 0; r < 4; ++r) dacc[i][j][r] += (double)acc[i][j][r];
                    acc[i][j] = (f32x4)0.0f;
                }
        }
        __syncthreads();   // reads done before next step's DMA overwrites
    }
    #pragma unroll
    for (int i = 0; i < 2; ++i)
        #pragma unroll
        for (int j = 0; j < 4; ++j)
            #pragma unroll
            for (int r = 0; r < 4; ++r) dacc[i][j][r] += (double)acc[i][j][r];

    // epilogue: D[m = fq*4 + r][n = fr] per 16x16 fragment (proven map)
    #pragma unroll
    for (int j = 0; j < 4; ++j) {
        const int n = col0 + wn + (j << 4) + fr;
        const double bv = (double)bias[n];
        #pragma unroll
        for (int i = 0; i < 2; ++i) {
            const int mb = row0 + wm + (i << 4) + (fq << 2);
            #pragma unroll
            for (int r = 0; r < 4; ++r) {
                double v = dacc[i][j][r] + bv;
                if (RELU) v = v > 0.0 ? v : 0.0;
                const size_t o = (size_t)(mb + r) * N + n;
                if (OUTK == 2 || OUTK == 3) ((double*)C)[o] = v;
                if (OUTK == 0 || OUTK == 3) {
                    ushort h, m, l;
                    split3((float)v, &h, &m, &l);
                    ushort* Cp = (ushort*)((OUTK == 0) ? C : C2);
                    Cp[o] = h; Cp[PC + o] = m; Cp[2 * PC + o] = l;
                }
            }
        }
    }
}

// ---------------------------------------------------------------------------
// split-bf16 MFMA distance + fused argmin (unchanged from R7, proven).
// Zpl: [3][BDIM][DCODE]; Cpl: [3][KCODE][DCODE].
// ---------------------------------------------------------------------------
__global__ __launch_bounds__(512, 2)
void distm(const ushort* __restrict__ Zpl, const ushort* __restrict__ Cpl,
           const double* __restrict__ c2, double* __restrict__ psc,
           int* __restrict__ pix)
{
    __shared__ __align__(16) short As[3][128][40];
    __shared__ __align__(16) short Bs[3][128][40];
    const int tid  = threadIdx.x;
    const int lane = tid & 63;
    const int wave = tid >> 6;
    const int wm = (wave >> 1) << 5;
    const int wn = (wave & 1) << 6;
    const int fr = lane & 15, fq = lane >> 4;
    const int row0 = blockIdx.y << 7, col0 = blockIdx.x << 7;
    const int sr = tid >> 2, sc = (tid & 3) << 3;
    const size_t PZ = (size_t)BDIM * DCODE;
    const size_t PC = (size_t)KCODE * DCODE;

    const ushort* Ag = Zpl + (size_t)(row0 + sr) * DCODE + sc;
    const ushort* Bg = Cpl + (size_t)(col0 + sr) * DCODE + sc;

    f32x4  acc[2][4];
    double dacc[2][4][4];
    #pragma unroll
    for (int i = 0; i < 2; ++i)
        #pragma unroll
        for (int j = 0; j < 4; ++j) {
            acc[i][j] = (f32x4)0.0f;
            #pragma unroll
            for (int r = 0; r < 4; ++r) dacc[i][j][r] = 0.0;
        }

    short8 sa[3], sb[3];
    #pragma unroll
    for (int p = 0; p < 3; ++p) {
        sa[p] = *(const short8*)(Ag + (size_t)p * PZ);
        sb[p] = *(const short8*)(Bg + (size_t)p * PC);
    }

    const int nsteps = DCODE >> 5;   // 8
    for (int s = 0; s < nsteps; ++s) {
        __syncthreads();
        #pragma unroll
        for (int p = 0; p < 3; ++p) {
            *(short8*)&As[p][sr][sc] = sa[p];
            *(short8*)&Bs[p][sr][sc] = sb[p];
        }
        __syncthreads();
        if (s + 1 < nsteps) {
            const int kb = (s + 1) << 5;
            #pragma unroll
            for (int p = 0; p < 3; ++p) {
                sa[p] = *(const short8*)(Ag + (size_t)p * PZ + kb);
                sb[p] = *(const short8*)(Bg + (size_t)p * PC + kb);
            }
        }

        short8 bh[4], bm[4], bl[4];
        #pragma unroll
        for (int j = 0; j < 4; ++j) {
            const int bn = wn + (j << 4) + fr;
            bh[j] = *(const short8*)&Bs[0][bn][fq << 3];
            bm[j] = *(const short8*)&Bs[1][bn][fq << 3];
            bl[j] = *(const short8*)&Bs[2][bn][fq << 3];
        }
        #pragma unroll
        for (int i = 0; i < 2; ++i) {
            const int an = wm + (i << 4) + fr;
            short8 ah = *(const short8*)&As[0][an][fq << 3];
            short8 am = *(const short8*)&As[1][an][fq << 3];
            short8 al = *(const short8*)&As[2][an][fq << 3];
            #pragma unroll
            for (int j = 0; j < 4; ++j) {
                acc[i][j] = __builtin_amdgcn_mfma_f32_16x16x32_bf16(ah, bh[j], acc[i][j], 0, 0, 0);
                acc[i][j] = __builtin_amdgcn_mfma_f32_16x16x32_bf16(ah, bm[j], acc[i][j], 0, 0, 0);
                acc[i][j] = __builtin_amdgcn_mfma_f32_16x16x32_bf16(am, bh[j], acc[i][j], 0, 0, 0);
                acc[i][j] = __builtin_amdgcn_mfma_f32_16x16x32_bf16(ah, bl[j], acc[i][j], 0, 0, 0);
                acc[i][j] = __builtin_amdgcn_mfma_f32_16x16x32_bf16(al, bh[j], acc[i][j], 0, 0, 0);
                acc[i][j] = __builtin_amdgcn_mfma_f32_16x16x32_bf16(am, bm[j], acc[i][j], 0, 0, 0);
            }
        }

        if (s & 1) {
            #pragma unroll
            for (int i = 0; i < 2; ++i)
                #pragma unroll
                for (int j = 0; j < 4; ++j) {
                    #pragma unroll
                    for (int r = 0; r < 4; ++r) dacc[i][j][r] += (double)acc[i][j][r];
                    acc[i][j] = (f32x4)0.0f;
                }
        }
    }
    #pragma unroll
    for (int i = 0; i < 2; ++i)
        #pragma unroll
        for (int j = 0; j < 4; ++j)
            #pragma unroll
            for (int r = 0; r < 4; ++r) dacc[i][j][r] += (double)acc[i][j][r];

    // --- fused argmin epilogue ---
    __syncthreads();
    double* scb = (double*)&As[0][0][0];   // [128][2] scores
    int*    sib = (int*)(scb + 256);       // [128][2] indices

    #pragma unroll
    for (int i = 0; i < 2; ++i) {
        #pragma unroll
        for (int r = 0; r < 4; ++r) {
            double bs = 1e300; int bi = 0;
            #pragma unroll
            for (int j = 0; j < 4; ++j) {
                const int n = col0 + wn + (j << 4) + fr;
                const double s = c2[n] - 2.0 * dacc[i][j][r];
                if (s < bs) { bs = s; bi = n; }
            }
            #pragma unroll
            for (int msk = 1; msk < 16; msk <<= 1) {
                double os = __shfl_xor(bs, msk, 64);
                int    oi = __shfl_xor(bi, msk, 64);
                if (os < bs || (os == bs && oi < bi)) { bs = os; bi = oi; }
            }
            if (fr == 0) {
                const int lr = wm + (i << 4) + (fq << 2) + r;
                scb[lr * 2 + (wave & 1)] = bs;
                sib[lr * 2 + (wave & 1)] = bi;
            }
        }
    }
    __syncthreads();
    if (tid < 128) {
        double s0 = scb[tid * 2], s1 = scb[tid * 2 + 1];
        int    i0 = sib[tid * 2], i1 = sib[tid * 2 + 1];
        const bool t1 = (s1 < s0) || (s1 == s0 && i1 < i0);
        const size_t o = (size_t)(row0 + tid) * (KCODE / 128) + blockIdx.x;
        psc[o] = t1 ? s1 : s0;
        pix[o] = t1 ? i1 : i0;
    }
}

// ---------------------------------------------------------------------------
// reduce partial argmins: [row][8] -> idx
// ---------------------------------------------------------------------------
__global__ __launch_bounds__(256)
void reduce8(const double* __restrict__ psc, const int* __restrict__ pix,
             int* __restrict__ idx_out)
{
    const int row = blockIdx.x * 256 + threadIdx.x;
    const double* ps = psc + (size_t)row * (KCODE / 128);
    const int*    pi = pix + (size_t)row * (KCODE / 128);
    double m = ps[0]; int mi = pi[0];
    #pragma unroll
    for (int t = 1; t < KCODE / 128; ++t) {
        double s = ps[t]; int c = pi[t];
        if (s < m || (s == m && c < mi)) { m = s; mi = c; }
    }
    idx_out[row] = mi;
}

// ---------------------------------------------------------------------------
// bf16 MFMA GEMM, global_load_lds staging (decoder). A:[M][K], Bt:[N][K].
// 128x128 tile, BK=32, 256 thr / 4 waves, wave tile 64x64.
// LDS linear [128][32], slot swizzle phys = logical ^ ((row>>1)&3).
// ---------------------------------------------------------------------------
template<int RELU, int OUTBF>
__global__ __launch_bounds__(256)
void gemmb2(const ushort* __restrict__ A, const ushort* __restrict__ Bt,
            const float* __restrict__ bias, void* __restrict__ C,
            int M, int N, int K)
{
    __shared__ __align__(16) short As[128][32];
    __shared__ __align__(16) short Bs[128][32];
    const int tid  = threadIdx.x;
    const int lane = tid & 63;
    const int wave = tid >> 6;                  // 0..3
    const int wm = (wave >> 1) << 6, wn = (wave & 1) << 6;
    const int fr = lane & 15;
    const int fq = lane >> 4;
    const int row0 = blockIdx.y << 7, col0 = blockIdx.x << 7;

    // staging: wave w covers rows [32w, 32w+32) as two 16-row chunks
    const int sr0 = (wave << 5) + (lane >> 2);       // chunk 0 row
    const int sslot = lane & 3;
    const int kg0 = (sslot ^ ((sr0 >> 1) & 3)) << 3;
    const int sr1 = sr0 + 16;
    const int kg1 = (sslot ^ ((sr1 >> 1) & 3)) << 3;

    const ushort* Ag0 = A  + (size_t)(row0 + sr0) * K + kg0;
    const ushort* Ag1 = A  + (size_t)(row0 + sr1) * K + kg1;
    const ushort* Bg0 = Bt + (size_t)(col0 + sr0) * K + kg0;
    const ushort* Bg1 = Bt + (size_t)(col0 + sr1) * K + kg1;

    f32x4 acc[4][4];
    #pragma unroll
    for (int i = 0; i < 4; ++i)
        #pragma unroll
        for (int j = 0; j < 4; ++j) acc[i][j] = (f32x4)0.0f;

    for (int kb = 0; kb < K; kb += 32) {
        gload16(Ag0 + kb, &As[(wave << 5)][0]);
        gload16(Ag1 + kb, &As[(wave << 5) + 16][0]);
        gload16(Bg0 + kb, &Bs[(wave << 5)][0]);
        gload16(Bg1 + kb, &Bs[(wave << 5) + 16][0]);
        __syncthreads();

        short8 af[4], bf[4];
        #pragma unroll
        for (int i = 0; i < 4; ++i) {
            const int an = wm + (i << 4) + fr;
            af[i] = *(const short8*)&As[an][(fq ^ ((an >> 1) & 3)) << 3];
        }
        #pragma unroll
        for (int j = 0; j < 4; ++j) {
            const int bn = wn + (j << 4) + fr;
            bf[j] = *(const short8*)&Bs[bn][(fq ^ ((bn >> 1) & 3)) << 3];
        }
        #pragma unroll
        for (int i = 0; i < 4; ++i)
            #pragma unroll
            for (int j = 0; j < 4; ++j)
                acc[i][j] = __builtin_amdgcn_mfma_f32_16x16x32_bf16(
                                af[i], bf[j], acc[i][j], 0, 0, 0);
        __syncthreads();
    }

    #pragma unroll
    for (int j = 0; j < 4; ++j) {
        const int n = col0 + wn + (j << 4) + fr;
        const float bv = bias[n];
        #pragma unroll
        for (int i = 0; i < 4; ++i) {
            const int mb = row0 + wm + (i << 4) + (fq << 2);
            #pragma unroll
            for (int r = 0; r < 4; ++r) {
                float v = acc[i][j][r] + bv;
                if (RELU) v = fmaxf(v, 0.0f);
                size_t o = (size_t)(mb + r) * N + n;
                if (OUTBF) ((bf16*)C)[o]  = __float2bfloat16(v);
                else       ((float*)C)[o] = v;
            }
        }
    }
}

// ---------------------------------------------------------------------------
// decoder weight transpose + f32->bf16 (unchanged)
// ---------------------------------------------------------------------------
__global__ __launch_bounds__(256)
void wtrans(const float* __restrict__ W, ushort* __restrict__ Wt, int K, int N)
{
    __shared__ float tile[64][65];
    const int tid = threadIdx.x;
    const int kb = blockIdx.y << 6, nb = blockIdx.x << 6;
    const int r = tid >> 4, c4 = (tid & 15) << 2;
    #pragma unroll
    for (int s = 0; s < 4; ++s) {
        float4 v = *(const float4*)(W + (size_t)(kb + r + (s << 4)) * N + nb + c4);
        tile[r + (s << 4)][c4 + 0] = v.x; tile[r + (s << 4)][c4 + 1] = v.y;
        tile[r + (s << 4)][c4 + 2] = v.z; tile[r + (s << 4)][c4 + 3] = v.w;
    }
    __syncthreads();
    #pragma unroll
    for (int s = 0; s < 4; ++s) {
        const int n = r + (s << 4);
        ushort u[4];
        #pragma unroll
        for (int l = 0; l < 4; ++l) {
            bf16 h = __float2bfloat16(tile[c4 + l][n]);
            u[l] = *(ushort*)&h;
        }
        *(ushort4*)(Wt + (size_t)(nb + n) * K + kb + c4) = make_ushort4(u[0], u[1], u[2], u[3]);
    }
}

// ---------------------------------------------------------------------------
// encoder weight transpose + 3-limb split: planes [N][K], stride N*K
// ---------------------------------------------------------------------------
__global__ __launch_bounds__(256)
void wsplit(const float* __restrict__ W, ushort* __restrict__ Wt, int K, int N)
{
    __shared__ float tile[64][65];
    const int tid = threadIdx.x;
    const int kb = blockIdx.y << 6, nb = blockIdx.x << 6;
    const int r = tid >> 4, c4 = (tid & 15) << 2;
    const size_t NK = (size_t)N * K;
    #pragma unroll
    for (int s = 0; s < 4; ++s) {
        float4 v = *(const float4*)(W + (size_t)(kb + r + (s << 4)) * N + nb + c4);
        tile[r + (s << 4)][c4 + 0] = v.x; tile[r + (s << 4)][c4 + 1] = v.y;
        tile[r + (s << 4)][c4 + 2] = v.z; tile[r + (s << 4)][c4 + 3] = v.w;
    }
    __syncthreads();
    #pragma unroll
    for (int s = 0; s < 4; ++s) {
        const int n = r + (s << 4);
        ushort h[4], m[4], l[4];
        #pragma unroll
        for (int e = 0; e < 4; ++e) split3(tile[c4 + e][n], &h[e], &m[e], &l[e]);
        const size_t o = (size_t)(nb + n) * K + kb + c4;
        *(ushort4*)(Wt + o)          = make_ushort4(h[0], h[1], h[2], h[3]);
        *(ushort4*)(Wt + NK + o)     = make_ushort4(m[0], m[1], m[2], m[3]);
        *(ushort4*)(Wt + 2 * NK + o) = make_ushort4(l[0], l[1], l[2], l[3]);
    }
}

// ---------------------------------------------------------------------------
// f32 row-major -> 3 bf16 limb planes, plane stride P (x and codebook)
// ---------------------------------------------------------------------------
__global__ __launch_bounds__(256)
void xsplit(const float* __restrict__ X, ushort* __restrict__ Xp, size_t P)
{
    const size_t i = ((size_t)blockIdx.x * 256 + threadIdx.x) << 2;
    float4 v = *(const float4*)(X + i);
    ushort h[4], m[4], l[4];
    split3(v.x, &h[0], &m[0], &l[0]);
    split3(v.y, &h[1], &m[1], &l[1]);
    split3(v.z, &h[2], &m[2], &l[2]);
    split3(v.w, &h[3], &m[3], &l[3]);
    *(ushort4*)(Xp + i)         = make_ushort4(h[0], h[1], h[2], h[3]);
    *(ushort4*)(Xp + P + i)     = make_ushort4(m[0], m[1], m[2], m[3]);
    *(ushort4*)(Xp + 2 * P + i) = make_ushort4(l[0], l[1], l[2], l[3]);
}

// ---------------------------------------------------------------------------
// codebook squared norms (f64)
// ---------------------------------------------------------------------------
__global__ __launch_bounds__(64)
void c2_k(const float* __restrict__ cb, double* __restrict__ c2)
{
    int code = blockIdx.x, l = threadIdx.x;
    float4 v = *(const float4*)(cb + (size_t)code * DCODE + (l << 2));
    double s = (double)v.x * v.x + (double)v.y * v.y
             + (double)v.z * v.z + (double)v.w * v.w;
    #pragma unroll
    for (int off = 32; off; off >>= 1) s += __shfl_down(s, off, 64);
    if (l == 0) c2[code] = s;
}

// ---------------------------------------------------------------------------
// gather + straight-through + loss partials + idx. 4 rows/block, no atomics.
// ---------------------------------------------------------------------------
__global__ __launch_bounds__(256)
void gather_k(const int* __restrict__ idx_in, const float* __restrict__ cb,
              const double* __restrict__ z, ushort* __restrict__ qstb,
              float* __restrict__ out_qst, float* __restrict__ out_idx,
              double* __restrict__ psum)
{
    const int tid  = threadIdx.x;
    const int row  = (blockIdx.x << 2) + (tid >> 6);
    const int lane = tid & 63;
    const int d    = lane << 2;
    const int idx  = idx_in[row];

    float4 qv = *(const float4*)(cb + (size_t)idx * DCODE + d);
    const double* zp = z + (size_t)row * DCODE + d;
    double2 z0 = *(const double2*)(zp);
    double2 z1 = *(const double2*)(zp + 2);

    double q[4] = {(double)qv.x, (double)qv.y, (double)qv.z, (double)qv.w};
    double zz[4] = {z0.x, z0.y, z1.x, z1.y};
    double qs[4];
    double s = 0.0;
    #pragma unroll
    for (int e = 0; e < 4; ++e) {
        double diff = q[e] - zz[e];
        qs[e] = zz[e] + diff;
        s += diff * diff;
    }
    *(float4*)(out_qst + (size_t)row * DCODE + d) =
        make_float4((float)qs[0], (float)qs[1], (float)qs[2], (float)qs[3]);
    ushort u[4];
    #pragma unroll
    for (int e = 0; e < 4; ++e) {
        bf16 h = __float2bfloat16((float)qs[e]);
        u[e] = *(ushort*)&h;
    }
    *(ushort4*)(qstb + (size_t)row * DCODE + d) = make_ushort4(u[0], u[1], u[2], u[3]);

    #pragma unroll
    for (int off = 32; off; off >>= 1) s += __shfl_down(s, off, 64);
    __shared__ double sred[4];
    if (lane == 0) {
        sred[tid >> 6] = s;
        out_idx[row] = (float)idx;
    }
    __syncthreads();
    if (tid == 0) psum[blockIdx.x] = sred[0] + sred[1] + sred[2] + sred[3];
}

// ---------------------------------------------------------------------------
// final loss reduce over BDIM/4 block partials
// ---------------------------------------------------------------------------
__global__ __launch_bounds__(256)
void loss_k(const double* __restrict__ psum, float* __restrict__ out_loss)
{
    const int tid = threadIdx.x;
    double s = 0.0;
    for (int i = tid; i < BDIM / 4; i += 256) s += psum[i];
    #pragma unroll
    for (int off = 32; off; off >>= 1) s += __shfl_down(s, off, 64);
    __shared__ double sred[4];
    if ((tid & 63) == 0) sred[tid >> 6] = s;
    __syncthreads();
    if (tid == 0)
        out_loss[0] = (float)(1.25 * (sred[0] + sred[1] + sred[2] + sred[3]) / 4194304.0);
}

// ===========================================================================
extern "C" void kernel_launch(void* const* d_in, const int* in_sizes, int n_in,
                              void* d_out, int out_size, void* d_ws, size_t ws_size,
                              hipStream_t stream)
{
    const float* x   = (const float*)d_in[0];
    const float* eW1 = (const float*)d_in[1];
    const float* eb1 = (const float*)d_in[2];
    const float* eW2 = (const float*)d_in[3];
    const float* eb2 = (const float*)d_in[4];
    const float* eW3 = (const float*)d_in[5];
    const float* eb3 = (const float*)d_in[6];
    const float* cbk = (const float*)d_in[7];
    const float* dW1 = (const float*)d_in[8];
    const float* db1 = (const float*)d_in[9];
    const float* dW2 = (const float*)d_in[10];
    const float* db2 = (const float*)d_in[11];
    const float* dW3 = (const float*)d_in[12];
    const float* db3 = (const float*)d_in[13];

    // --- sizes ---
    const size_t EPS1 = (size_t)3 * 2048 * 1024 * 2;
    const size_t EPS2 = (size_t)3 * 1024 * 2048 * 2;
    const size_t EPS3 = (size_t)3 * 256 * 1024 * 2;
    const size_t EPS  = EPS1 + EPS2 + EPS3;
    const size_t FIX_W1 = (size_t)1024 * 256 * 2;
    const size_t FIX_W2 = (size_t)2048 * 1024 * 2;
    const size_t FIX_W3 = (size_t)1024 * 2048 * 2;
    const size_t ZB   = (size_t)BDIM * DCODE * 8;
    const size_t ZPLB = (size_t)3 * BDIM * DCODE * 2;
    const size_t QSTB = (size_t)BDIM * DCODE * 2;
    const size_t IDXB = (size_t)BDIM * 4;
    const size_t NPT  = KCODE / 128;
    const size_t PSCB = (size_t)BDIM * NPT * 8;
    const size_t PIXB = (size_t)BDIM * NPT * 4;
    const size_t CBPB = (size_t)3 * KCODE * DCODE * 2;
    const size_t PSUM = (size_t)(BDIM / 4) * 8;

    const size_t PERSIST = FIX_W1 + FIX_W2 + FIX_W3 + ZB + ZPLB + QSTB + IDXB
                         + PSCB + PIXB + CBPB + PSUM + 8192 + 256;

    // per-row chunk region: xpl 6144 | h1pl 12288 | h2pl 6144
    int R = BDIM;
    while (R > 256 && PERSIST + EPS + (size_t)R * 24576 > ws_size) R >>= 1;
    const int nch = BDIM / R;

    char* ws = (char*)d_ws;
    size_t off = 0;
    ushort* eP1  = (ushort*)(ws + off); off += EPS1;
    ushort* eP2  = (ushort*)(ws + off); off += EPS2;
    ushort* eP3  = (ushort*)(ws + off); off += EPS3;
    ushort* xpl  = (ushort*)(ws + off); off += (size_t)R * 6144;
    ushort* h1pl = (ushort*)(ws + off); off += (size_t)R * 12288;
    ushort* h2pl = (ushort*)(ws + off); off += (size_t)R * 6144;
    ushort* dh1b = xpl;                   // phase-4 alias: R x 1024 bf16
    ushort* dh2b = h1pl;                  // phase-4 alias: R x 2048 bf16
    ushort* Wt1  = (ushort*)(ws + off); off += FIX_W1;
    ushort* Wt2  = (ushort*)(ws + off); off += FIX_W2;
    ushort* Wt3  = (ushort*)(ws + off); off += FIX_W3;
    double* zb   = (double*)(ws + off); off += ZB;
    ushort* zpl  = (ushort*)(ws + off); off += ZPLB;
    ushort* qstb = (ushort*)(ws + off); off += QSTB;
    int*    idxb = (int*)(ws + off);    off += IDXB;
    double* psc  = (double*)(ws + off); off += PSCB;
    int*    pix  = (int*)(ws + off);    off += PIXB;
    ushort* cbP  = (ushort*)(ws + off); off += CBPB;
    double* psum = (double*)(ws + off); off += PSUM;
    double* c2   = (double*)(ws + off); off += 8192;

    float* out      = (float*)d_out;
    float* out_rec  = out;
    float* out_qst  = out + (size_t)BDIM * DIN;
    float* out_loss = out_qst + (size_t)BDIM * DCODE;
    float* out_idx  = out_loss + 1;

    c2_k<<<KCODE, 64, 0, stream>>>(cbk, c2);
    wtrans<<<dim3(1024 / 64,  256 / 64), 256, 0, stream>>>(dW1, Wt1,  256, 1024);
    wtrans<<<dim3(2048 / 64, 1024 / 64), 256, 0, stream>>>(dW2, Wt2, 1024, 2048);
    wtrans<<<dim3(1024 / 64, 2048 / 64), 256, 0, stream>>>(dW3, Wt3, 2048, 1024);
    wsplit<<<dim3(2048 / 64, 1024 / 64), 256, 0, stream>>>(eW1, eP1, 1024, 2048);
    wsplit<<<dim3(1024 / 64, 2048 / 64), 256, 0, stream>>>(eW2, eP2, 2048, 1024);
    wsplit<<<dim3( 256 / 64, 1024 / 64), 256, 0, stream>>>(eW3, eP3, 1024,  256);
    xsplit<<<(KCODE * DCODE) / 1024, 256, 0, stream>>>(cbk, cbP, (size_t)KCODE * DCODE);

    // phase 1: encoder chunks -> zb (f64) + zpl (limb planes, fused)
    for (int c = 0; c < nch; ++c) {
        const float* xc = x + (size_t)c * R * DIN;
        double* zb_c  = zb + (size_t)c * R * DCODE;
        ushort* zpl_c = zpl + (size_t)c * R * DCODE;
        xsplit<<<R, 256, 0, stream>>>(xc, xpl, (size_t)R * DIN);
        gemms<1, 0><<<dim3(DH1 / 128, R / 128), 512, 0, stream>>>(
            xpl, eP1, eb1, h1pl, nullptr, R, DH1, DIN,
            (size_t)R * DIN, (size_t)DH1 * DIN, (size_t)R * DH1);
        gemms<1, 0><<<dim3(DH2 / 128, R / 128), 512, 0, stream>>>(
            h1pl, eP2, eb2, h2pl, nullptr, R, DH2, DH1,
            (size_t)R * DH1, (size_t)DH2 * DH1, (size_t)R * DH2);
        gemms<0, 3><<<dim3(DCODE / 128, R / 128), 512, 0, stream>>>(
            h2pl, eP3, eb3, zb_c, zpl_c, R, DCODE, DH2,
            (size_t)R * DH2, (size_t)DCODE * DH2, (size_t)BDIM * DCODE);
    }

    // phase 2: VQ on matrix cores, full batch
    distm<<<dim3(KCODE / 128, BDIM / 128), 512, 0, stream>>>(zpl, cbP, c2, psc, pix);
    reduce8<<<BDIM / 256, 256, 0, stream>>>(psc, pix, idxb);

    // phase 3: gather + loss partials, full batch
    gather_k<<<BDIM / 4, 256, 0, stream>>>(idxb, cbk, zb, qstb, out_qst, out_idx, psum);

    // phase 4: decoder chunks
    for (int c = 0; c < nch; ++c) {
        const ushort* qst_c = qstb + (size_t)c * R * DCODE;
        float* rec_c = out_rec + (size_t)c * R * DIN;
        gemmb2<1, 1><<<dim3(DH2 / 128, R / 128), 256, 0, stream>>>(qst_c, Wt1, db1, dh1b, R, DH2, DCODE);
        gemmb2<1, 1><<<dim3(DH1 / 128, R / 128), 256, 0, stream>>>(dh1b, Wt2, db2, dh2b, R, DH1, DH2);
        gemmb2<0, 0><<<dim3(DIN / 128, R / 128), 256, 0, stream>>>(dh2b, Wt3, db3, rec_c, R, DIN, DH1);
    }

    loss_k<<<1, 256, 0, stream>>>(psum, out_loss);
}

// Round 4
// 1587.702 us; speedup vs baseline: 2.1779x; 1.0839x over previous
//
#include <hip/hip_runtime.h>
#include <hip/hip_bf16.h>
#include <stdint.h>

// ===========================================================================
// VQ-VAE forward, MI355X. Round 9: pipelined DMA staging (T3-minimum).
// R8 = 1721us: global_load_lds removed bank conflicts (3e7 -> 0) but the
// __syncthreads vmcnt(0) drain exposed full load latency each K-step
// (gemms 257 -> 300us, MfmaUtil 34 -> 28.6). This round: LDS double-buffer
// + issue-next-STAGE-before-compute + counted s_waitcnt vmcnt(6) + raw
// s_barrier (prefetch stays in flight across barriers). Applied to gemms
// (encoder) and gemmb2 (decoder). distm unchanged.
//
// Numerics unchanged (3-limb split-bf16, 6 products, f64 folds every 2
// K-steps; distances via limb MFMA + c2; loss from f64 z).
// Layout: inputs f32; out f32: rec[16384*1024] | qst[16384*256] | loss[1]
// | idx[16384].
// ===========================================================================

#define BDIM  16384
#define DIN   1024
#define DH1   2048
#define DH2   1024
#define DCODE 256
#define KCODE 1024

typedef __hip_bfloat16 bf16;
typedef __attribute__((ext_vector_type(8))) short short8;
typedef __attribute__((ext_vector_type(4))) float f32x4;

// ---------------------------------------------------------------------------
// async global->LDS, 16B per lane (wave-uniform LDS base + lane*16)
// ---------------------------------------------------------------------------
__device__ __forceinline__ void gload16(const void* g, void* l)
{
    __builtin_amdgcn_global_load_lds(
        (const __attribute__((address_space(1))) unsigned int*)g,
        (__attribute__((address_space(3))) unsigned int*)l, 16, 0, 0);
}

// ---------------------------------------------------------------------------
// 3-limb bf16 split: f = h + m + l up to ~2^-24 relative.
// ---------------------------------------------------------------------------
__device__ __forceinline__ void split3(float f, ushort* h, ushort* m, ushort* l)
{
    bf16 bh = __float2bfloat16(f);
    float r1 = f - __bfloat162float(bh);
    bf16 bm = __float2bfloat16(r1);
    float r2 = r1 - __bfloat162float(bm);
    bf16 bl = __float2bfloat16(r2);
    *h = *(ushort*)&bh; *m = *(ushort*)&bm; *l = *(ushort*)&bl;
}

// ---------------------------------------------------------------------------
// split-bf16 MFMA GEMM, double-buffered DMA staging + counted vmcnt.
// A planes: [M][K] bf16 stride PA; Bt planes: [N][K] bf16 stride PB.
// 128x128 tile, BK=32, 512 thr / 8 waves, wave tile 32x64.
// LDS: [2][3][128][32] per matrix (96 KB total), slot swizzle
// phys = logical ^ ((row>>1)&3) on global src AND fragment read.
// OUTK: 0 = 3 limb planes (stride PC); 2 = f64; 3 = f64 + limb planes (C2).
// ---------------------------------------------------------------------------
template<int RELU, int OUTK>
__global__ __launch_bounds__(512, 2)
void gemms(const ushort* __restrict__ Apl, const ushort* __restrict__ Bpl,
           const float* __restrict__ bias, void* __restrict__ C,
           void* __restrict__ C2,
           int M, int N, int K, size_t PA, size_t PB, size_t PC)
{
    __shared__ __align__(16) short As[2][3][128][32];
    __shared__ __align__(16) short Bs[2][3][128][32];
    const int tid  = threadIdx.x;
    const int lane = tid & 63;
    const int wave = tid >> 6;                 // 0..7
    const int wm = (wave >> 1) << 5;           // {0,32,64,96}
    const int wn = (wave & 1) << 6;            // {0,64}
    const int fr = lane & 15, fq = lane >> 4;
    const int row0 = blockIdx.y << 7, col0 = blockIdx.x << 7;

    // staging: wave w covers rows [16w,16w+16) of each (matrix,plane)
    const int srow = (wave << 4) + (lane >> 2);       // 0..127
    const int sslot = lane & 3;                       // physical 8-short slot
    const int skg = (sslot ^ ((srow >> 1) & 3)) << 3; // logical k offset

    const ushort* AgT = Apl + (size_t)(row0 + srow) * K + skg;
    const ushort* BgT = Bpl + (size_t)(col0 + srow) * K + skg;

    f32x4  acc[2][4];
    double dacc[2][4][4];
    #pragma unroll
    for (int i = 0; i < 2; ++i)
        #pragma unroll
        for (int j = 0; j < 4; ++j) {
            acc[i][j] = (f32x4)0.0f;
            #pragma unroll
            for (int r = 0; r < 4; ++r) dacc[i][j][r] = 0.0;
        }

    auto stage = [&](int b, int kb) {
        #pragma unroll
        for (int p = 0; p < 3; ++p) {
            gload16(AgT + (size_t)p * PA + kb, &As[b][p][wave << 4][0]);
            gload16(BgT + (size_t)p * PB + kb, &Bs[b][p][wave << 4][0]);
        }
    };

    stage(0, 0);
    const int nsteps = K >> 5;
    for (int s = 0; s < nsteps; ++s) {
        const int b = s & 1;
        if (s + 1 < nsteps) {
            stage(b ^ 1, (s + 1) << 5);   // issue next tile into other buffer
            asm volatile("s_waitcnt vmcnt(6)" ::: "memory");  // cur buf done
        } else {
            asm volatile("s_waitcnt vmcnt(0)" ::: "memory");
        }
        __builtin_amdgcn_s_barrier();          // all waves' cur loads landed
        __builtin_amdgcn_sched_barrier(0);

        short8 bh[4], bm[4], bl[4];
        #pragma unroll
        for (int j = 0; j < 4; ++j) {
            const int bn = wn + (j << 4) + fr;
            const int bsl = (fq ^ ((bn >> 1) & 3)) << 3;
            bh[j] = *(const short8*)&Bs[b][0][bn][bsl];
            bm[j] = *(const short8*)&Bs[b][1][bn][bsl];
            bl[j] = *(const short8*)&Bs[b][2][bn][bsl];
        }
        #pragma unroll
        for (int i = 0; i < 2; ++i) {
            const int an = wm + (i << 4) + fr;
            const int asl = (fq ^ ((an >> 1) & 3)) << 3;
            short8 ah = *(const short8*)&As[b][0][an][asl];
            short8 am = *(const short8*)&As[b][1][an][asl];
            short8 al = *(const short8*)&As[b][2][an][asl];
            #pragma unroll
            for (int j = 0; j < 4; ++j) {
                acc[i][j] = __builtin_amdgcn_mfma_f32_16x16x32_bf16(ah, bh[j], acc[i][j], 0, 0, 0);
                acc[i][j] = __builtin_amdgcn_mfma_f32_16x16x32_bf16(ah, bm[j], acc[i][j], 0, 0, 0);
                acc[i][j] = __builtin_amdgcn_mfma_f32_16x16x32_bf16(am, bh[j], acc[i][j], 0, 0, 0);
                acc[i][j] = __builtin_amdgcn_mfma_f32_16x16x32_bf16(ah, bl[j], acc[i][j], 0, 0, 0);
                acc[i][j] = __builtin_amdgcn_mfma_f32_16x16x32_bf16(al, bh[j], acc[i][j], 0, 0, 0);
                acc[i][j] = __builtin_amdgcn_mfma_f32_16x16x32_bf16(am, bm[j], acc[i][j], 0, 0, 0);
            }
        }

        if (s & 1) {   // fold f32 acc into f64 shadow every 2 K-steps (64 K)
            #pragma unroll
            for (int i = 0; i < 2; ++i)
                #pragma unroll
                for (int j = 0; j < 4; ++j) {
                    #pragma unroll
                    for (int r = 0; r < 4; ++r) dacc[i][j][r] += (double)acc[i][j][r];
                    acc[i][j] = (f32x4)0.0f;
                }
        }
        __builtin_amdgcn_sched_barrier(0);
        __builtin_amdgcn_s_barrier();   // all reads of buf b done before restage
    }
    #pragma unroll
    for (int i = 0; i < 2; ++i)
        #pragma unroll
        for (int j = 0; j < 4; ++j)
            #pragma unroll
            for (int r = 0; r < 4; ++r) dacc[i][j][r] += (double)acc[i][j][r];

    // epilogue: D[m = fq*4 + r][n = fr] per 16x16 fragment (proven map)
    #pragma unroll
    for (int j = 0; j < 4; ++j) {
        const int n = col0 + wn + (j << 4) + fr;
        const double bv = (double)bias[n];
        #pragma unroll
        for (int i = 0; i < 2; ++i) {
            const int mb = row0 + wm + (i << 4) + (fq << 2);
            #pragma unroll
            for (int r = 0; r < 4; ++r) {
                double v = dacc[i][j][r] + bv;
                if (RELU) v = v > 0.0 ? v : 0.0;
                const size_t o = (size_t)(mb + r) * N + n;
                if (OUTK == 2 || OUTK == 3) ((double*)C)[o] = v;
                if (OUTK == 0 || OUTK == 3) {
                    ushort h, m, l;
                    split3((float)v, &h, &m, &l);
                    ushort* Cp = (ushort*)((OUTK == 0) ? C : C2);
                    Cp[o] = h; Cp[PC + o] = m; Cp[2 * PC + o] = l;
                }
            }
        }
    }
}

// ---------------------------------------------------------------------------
// split-bf16 MFMA distance + fused argmin (unchanged, proven).
// Zpl: [3][BDIM][DCODE]; Cpl: [3][KCODE][DCODE].
// ---------------------------------------------------------------------------
__global__ __launch_bounds__(512, 2)
void distm(const ushort* __restrict__ Zpl, const ushort* __restrict__ Cpl,
           const double* __restrict__ c2, double* __restrict__ psc,
           int* __restrict__ pix)
{
    __shared__ __align__(16) short As[3][128][40];
    __shared__ __align__(16) short Bs[3][128][40];
    const int tid  = threadIdx.x;
    const int lane = tid & 63;
    const int wave = tid >> 6;
    const int wm = (wave >> 1) << 5;
    const int wn = (wave & 1) << 6;
    const int fr = lane & 15, fq = lane >> 4;
    const int row0 = blockIdx.y << 7, col0 = blockIdx.x << 7;
    const int sr = tid >> 2, sc = (tid & 3) << 3;
    const size_t PZ = (size_t)BDIM * DCODE;
    const size_t PC = (size_t)KCODE * DCODE;

    const ushort* Ag = Zpl + (size_t)(row0 + sr) * DCODE + sc;
    const ushort* Bg = Cpl + (size_t)(col0 + sr) * DCODE + sc;

    f32x4  acc[2][4];
    double dacc[2][4][4];
    #pragma unroll
    for (int i = 0; i < 2; ++i)
        #pragma unroll
        for (int j = 0; j < 4; ++j) {
            acc[i][j] = (f32x4)0.0f;
            #pragma unroll
            for (int r = 0; r < 4; ++r) dacc[i][j][r] = 0.0;
        }

    short8 sa[3], sb[3];
    #pragma unroll
    for (int p = 0; p < 3; ++p) {
        sa[p] = *(const short8*)(Ag + (size_t)p * PZ);
        sb[p] = *(const short8*)(Bg + (size_t)p * PC);
    }

    const int nsteps = DCODE >> 5;   // 8
    for (int s = 0; s < nsteps; ++s) {
        __syncthreads();
        #pragma unroll
        for (int p = 0; p < 3; ++p) {
            *(short8*)&As[p][sr][sc] = sa[p];
            *(short8*)&Bs[p][sr][sc] = sb[p];
        }
        __syncthreads();
        if (s + 1 < nsteps) {
            const int kb = (s + 1) << 5;
            #pragma unroll
            for (int p = 0; p < 3; ++p) {
                sa[p] = *(const short8*)(Ag + (size_t)p * PZ + kb);
                sb[p] = *(const short8*)(Bg + (size_t)p * PC + kb);
            }
        }

        short8 bh[4], bm[4], bl[4];
        #pragma unroll
        for (int j = 0; j < 4; ++j) {
            const int bn = wn + (j << 4) + fr;
            bh[j] = *(const short8*)&Bs[0][bn][fq << 3];
            bm[j] = *(const short8*)&Bs[1][bn][fq << 3];
            bl[j] = *(const short8*)&Bs[2][bn][fq << 3];
        }
        #pragma unroll
        for (int i = 0; i < 2; ++i) {
            const int an = wm + (i << 4) + fr;
            short8 ah = *(const short8*)&As[0][an][fq << 3];
            short8 am = *(const short8*)&As[1][an][fq << 3];
            short8 al = *(const short8*)&As[2][an][fq << 3];
            #pragma unroll
            for (int j = 0; j < 4; ++j) {
                acc[i][j] = __builtin_amdgcn_mfma_f32_16x16x32_bf16(ah, bh[j], acc[i][j], 0, 0, 0);
                acc[i][j] = __builtin_amdgcn_mfma_f32_16x16x32_bf16(ah, bm[j], acc[i][j], 0, 0, 0);
                acc[i][j] = __builtin_amdgcn_mfma_f32_16x16x32_bf16(am, bh[j], acc[i][j], 0, 0, 0);
                acc[i][j] = __builtin_amdgcn_mfma_f32_16x16x32_bf16(ah, bl[j], acc[i][j], 0, 0, 0);
                acc[i][j] = __builtin_amdgcn_mfma_f32_16x16x32_bf16(al, bh[j], acc[i][j], 0, 0, 0);
                acc[i][j] = __builtin_amdgcn_mfma_f32_16x16x32_bf16(am, bm[j], acc[i][j], 0, 0, 0);
            }
        }

        if (s & 1) {
            #pragma unroll
            for (int i = 0; i < 2; ++i)
                #pragma unroll
                for (int j = 0; j < 4; ++j) {
                    #pragma unroll
                    for (int r = 0; r < 4; ++r) dacc[i][j][r] += (double)acc[i][j][r];
                    acc[i][j] = (f32x4)0.0f;
                }
        }
    }
    #pragma unroll
    for (int i = 0; i < 2; ++i)
        #pragma unroll
        for (int j = 0; j < 4; ++j)
            #pragma unroll
            for (int r = 0; r < 4; ++r) dacc[i][j][r] += (double)acc[i][j][r];

    // --- fused argmin epilogue ---
    __syncthreads();
    double* scb = (double*)&As[0][0][0];   // [128][2] scores
    int*    sib = (int*)(scb + 256);       // [128][2] indices

    #pragma unroll
    for (int i = 0; i < 2; ++i) {
        #pragma unroll
        for (int r = 0; r < 4; ++r) {
            double bs = 1e300; int bi = 0;
            #pragma unroll
            for (int j = 0; j < 4; ++j) {
                const int n = col0 + wn + (j << 4) + fr;
                const double s = c2[n] - 2.0 * dacc[i][j][r];
                if (s < bs) { bs = s; bi = n; }
            }
            #pragma unroll
            for (int msk = 1; msk < 16; msk <<= 1) {
                double os = __shfl_xor(bs, msk, 64);
                int    oi = __shfl_xor(bi, msk, 64);
                if (os < bs || (os == bs && oi < bi)) { bs = os; bi = oi; }
            }
            if (fr == 0) {
                const int lr = wm + (i << 4) + (fq << 2) + r;
                scb[lr * 2 + (wave & 1)] = bs;
                sib[lr * 2 + (wave & 1)] = bi;
            }
        }
    }
    __syncthreads();
    if (tid < 128) {
        double s0 = scb[tid * 2], s1 = scb[tid * 2 + 1];
        int    i0 = sib[tid * 2], i1 = sib[tid * 2 + 1];
        const bool t1 = (s1 < s0) || (s1 == s0 && i1 < i0);
        const size_t o = (size_t)(row0 + tid) * (KCODE / 128) + blockIdx.x;
        psc[o] = t1 ? s1 : s0;
        pix[o] = t1 ? i1 : i0;
    }
}

// ---------------------------------------------------------------------------
// reduce partial argmins: [row][8] -> idx
// ---------------------------------------------------------------------------
__global__ __launch_bounds__(256)
void reduce8(const double* __restrict__ psc, const int* __restrict__ pix,
             int* __restrict__ idx_out)
{
    const int row = blockIdx.x * 256 + threadIdx.x;
    const double* ps = psc + (size_t)row * (KCODE / 128);
    const int*    pi = pix + (size_t)row * (KCODE / 128);
    double m = ps[0]; int mi = pi[0];
    #pragma unroll
    for (int t = 1; t < KCODE / 128; ++t) {
        double s = ps[t]; int c = pi[t];
        if (s < m || (s == m && c < mi)) { m = s; mi = c; }
    }
    idx_out[row] = mi;
}

// ---------------------------------------------------------------------------
// bf16 MFMA GEMM (decoder), double-buffered DMA staging + counted vmcnt.
// A:[M][K], Bt:[N][K]. 128x128 tile, BK=32, 256 thr / 4 waves, wave 64x64.
// LDS [2][128][32] per matrix (32 KB), slot swizzle as gemms.
// ---------------------------------------------------------------------------
template<int RELU, int OUTBF>
__global__ __launch_bounds__(256)
void gemmb2(const ushort* __restrict__ A, const ushort* __restrict__ Bt,
            const float* __restrict__ bias, void* __restrict__ C,
            int M, int N, int K)
{
    __shared__ __align__(16) short As[2][128][32];
    __shared__ __align__(16) short Bs[2][128][32];
    const int tid  = threadIdx.x;
    const int lane = tid & 63;
    const int wave = tid >> 6;                  // 0..3
    const int wm = (wave >> 1) << 6, wn = (wave & 1) << 6;
    const int fr = lane & 15;
    const int fq = lane >> 4;
    const int row0 = blockIdx.y << 7, col0 = blockIdx.x << 7;

    // staging: wave w covers rows [32w, 32w+32) as two 16-row chunks
    const int sr0 = (wave << 5) + (lane >> 2);
    const int sslot = lane & 3;
    const int kg0 = (sslot ^ ((sr0 >> 1) & 3)) << 3;
    const int sr1 = sr0 + 16;
    const int kg1 = (sslot ^ ((sr1 >> 1) & 3)) << 3;

    const ushort* Ag0 = A  + (size_t)(row0 + sr0) * K + kg0;
    const ushort* Ag1 = A  + (size_t)(row0 + sr1) * K + kg1;
    const ushort* Bg0 = Bt + (size_t)(col0 + sr0) * K + kg0;
    const ushort* Bg1 = Bt + (size_t)(col0 + sr1) * K + kg1;

    f32x4 acc[4][4];
    #pragma unroll
    for (int i = 0; i < 4; ++i)
        #pragma unroll
        for (int j = 0; j < 4; ++j) acc[i][j] = (f32x4)0.0f;

    auto stage = [&](int b, int kb) {
        gload16(Ag0 + kb, &As[b][wave << 5][0]);
        gload16(Ag1 + kb, &As[b][(wave << 5) + 16][0]);
        gload16(Bg0 + kb, &Bs[b][wave << 5][0]);
        gload16(Bg1 + kb, &Bs[b][(wave << 5) + 16][0]);
    };

    stage(0, 0);
    const int nsteps = K >> 5;
    for (int s = 0; s < nsteps; ++s) {
        const int b = s & 1;
        if (s + 1 < nsteps) {
            stage(b ^ 1, (s + 1) << 5);
            asm volatile("s_waitcnt vmcnt(4)" ::: "memory");
        } else {
            asm volatile("s_waitcnt vmcnt(0)" ::: "memory");
        }
        __builtin_amdgcn_s_barrier();
        __builtin_amdgcn_sched_barrier(0);

        short8 af[4], bf[4];
        #pragma unroll
        for (int i = 0; i < 4; ++i) {
            const int an = wm + (i << 4) + fr;
            af[i] = *(const short8*)&As[b][an][(fq ^ ((an >> 1) & 3)) << 3];
        }
        #pragma unroll
        for (int j = 0; j < 4; ++j) {
            const int bn = wn + (j << 4) + fr;
            bf[j] = *(const short8*)&Bs[b][bn][(fq ^ ((bn >> 1) & 3)) << 3];
        }
        #pragma unroll
        for (int i = 0; i < 4; ++i)
            #pragma unroll
            for (int j = 0; j < 4; ++j)
                acc[i][j] = __builtin_amdgcn_mfma_f32_16x16x32_bf16(
                                af[i], bf[j], acc[i][j], 0, 0, 0);

        __builtin_amdgcn_sched_barrier(0);
        __builtin_amdgcn_s_barrier();
    }

    #pragma unroll
    for (int j = 0; j < 4; ++j) {
        const int n = col0 + wn + (j << 4) + fr;
        const float bv = bias[n];
        #pragma unroll
        for (int i = 0; i < 4; ++i) {
            const int mb = row0 + wm + (i << 4) + (fq << 2);
            #pragma unroll
            for (int r = 0; r < 4; ++r) {
                float v = acc[i][j][r] + bv;
                if (RELU) v = fmaxf(v, 0.0f);
                size_t o = (size_t)(mb + r) * N + n;
                if (OUTBF) ((bf16*)C)[o]  = __float2bfloat16(v);
                else       ((float*)C)[o] = v;
            }
        }
    }
}

// ---------------------------------------------------------------------------
// decoder weight transpose + f32->bf16 (unchanged)
// ---------------------------------------------------------------------------
__global__ __launch_bounds__(256)
void wtrans(const float* __restrict__ W, ushort* __restrict__ Wt, int K, int N)
{
    __shared__ float tile[64][65];
    const int tid = threadIdx.x;
    const int kb = blockIdx.y << 6, nb = blockIdx.x << 6;
    const int r = tid >> 4, c4 = (tid & 15) << 2;
    #pragma unroll
    for (int s = 0; s < 4; ++s) {
        float4 v = *(const float4*)(W + (size_t)(kb + r + (s << 4)) * N + nb + c4);
        tile[r + (s << 4)][c4 + 0] = v.x; tile[r + (s << 4)][c4 + 1] = v.y;
        tile[r + (s << 4)][c4 + 2] = v.z; tile[r + (s << 4)][c4 + 3] = v.w;
    }
    __syncthreads();
    #pragma unroll
    for (int s = 0; s < 4; ++s) {
        const int n = r + (s << 4);
        ushort u[4];
        #pragma unroll
        for (int l = 0; l < 4; ++l) {
            bf16 h = __float2bfloat16(tile[c4 + l][n]);
            u[l] = *(ushort*)&h;
        }
        *(ushort4*)(Wt + (size_t)(nb + n) * K + kb + c4) = make_ushort4(u[0], u[1], u[2], u[3]);
    }
}

// ---------------------------------------------------------------------------
// encoder weight transpose + 3-limb split: planes [N][K], stride N*K
// ---------------------------------------------------------------------------
__global__ __launch_bounds__(256)
void wsplit(const float* __restrict__ W, ushort* __restrict__ Wt, int K, int N)
{
    __shared__ float tile[64][65];
    const int tid = threadIdx.x;
    const int kb = blockIdx.y << 6, nb = blockIdx.x << 6;
    const int r = tid >> 4, c4 = (tid & 15) << 2;
    const size_t NK = (size_t)N * K;
    #pragma unroll
    for (int s = 0; s < 4; ++s) {
        float4 v = *(const float4*)(W + (size_t)(kb + r + (s << 4)) * N + nb + c4);
        tile[r + (s << 4)][c4 + 0] = v.x; tile[r + (s << 4)][c4 + 1] = v.y;
        tile[r + (s << 4)][c4 + 2] = v.z; tile[r + (s << 4)][c4 + 3] = v.w;
    }
    __syncthreads();
    #pragma unroll
    for (int s = 0; s < 4; ++s) {
        const int n = r + (s << 4);
        ushort h[4], m[4], l[4];
        #pragma unroll
        for (int e = 0; e < 4; ++e) split3(tile[c4 + e][n], &h[e], &m[e], &l[e]);
        const size_t o = (size_t)(nb + n) * K + kb + c4;
        *(ushort4*)(Wt + o)          = make_ushort4(h[0], h[1], h[2], h[3]);
        *(ushort4*)(Wt + NK + o)     = make_ushort4(m[0], m[1], m[2], m[3]);
        *(ushort4*)(Wt + 2 * NK + o) = make_ushort4(l[0], l[1], l[2], l[3]);
    }
}

// ---------------------------------------------------------------------------
// f32 row-major -> 3 bf16 limb planes, plane stride P (x and codebook)
// ---------------------------------------------------------------------------
__global__ __launch_bounds__(256)
void xsplit(const float* __restrict__ X, ushort* __restrict__ Xp, size_t P)
{
    const size_t i = ((size_t)blockIdx.x * 256 + threadIdx.x) << 2;
    float4 v = *(const float4*)(X + i);
    ushort h[4], m[4], l[4];
    split3(v.x, &h[0], &m[0], &l[0]);
    split3(v.y, &h[1], &m[1], &l[1]);
    split3(v.z, &h[2], &m[2], &l[2]);
    split3(v.w, &h[3], &m[3], &l[3]);
    *(ushort4*)(Xp + i)         = make_ushort4(h[0], h[1], h[2], h[3]);
    *(ushort4*)(Xp + P + i)     = make_ushort4(m[0], m[1], m[2], m[3]);
    *(ushort4*)(Xp + 2 * P + i) = make_ushort4(l[0], l[1], l[2], l[3]);
}

// ---------------------------------------------------------------------------
// codebook squared norms (f64)
// ---------------------------------------------------------------------------
__global__ __launch_bounds__(64)
void c2_k(const float* __restrict__ cb, double* __restrict__ c2)
{
    int code = blockIdx.x, l = threadIdx.x;
    float4 v = *(const float4*)(cb + (size_t)code * DCODE + (l << 2));
    double s = (double)v.x * v.x + (double)v.y * v.y
             + (double)v.z * v.z + (double)v.w * v.w;
    #pragma unroll
    for (int off = 32; off; off >>= 1) s += __shfl_down(s, off, 64);
    if (l == 0) c2[code] = s;
}

// ---------------------------------------------------------------------------
// gather + straight-through + loss partials + idx. 4 rows/block, no atomics.
// ---------------------------------------------------------------------------
__global__ __launch_bounds__(256)
void gather_k(const int* __restrict__ idx_in, const float* __restrict__ cb,
              const double* __restrict__ z, ushort* __restrict__ qstb,
              float* __restrict__ out_qst, float* __restrict__ out_idx,
              double* __restrict__ psum)
{
    const int tid  = threadIdx.x;
    const int row  = (blockIdx.x << 2) + (tid >> 6);
    const int lane = tid & 63;
    const int d    = lane << 2;
    const int idx  = idx_in[row];

    float4 qv = *(const float4*)(cb + (size_t)idx * DCODE + d);
    const double* zp = z + (size_t)row * DCODE + d;
    double2 z0 = *(const double2*)(zp);
    double2 z1 = *(const double2*)(zp + 2);

    double q[4] = {(double)qv.x, (double)qv.y, (double)qv.z, (double)qv.w};
    double zz[4] = {z0.x, z0.y, z1.x, z1.y};
    double qs[4];
    double s = 0.0;
    #pragma unroll
    for (int e = 0; e < 4; ++e) {
        double diff = q[e] - zz[e];
        qs[e] = zz[e] + diff;
        s += diff * diff;
    }
    *(float4*)(out_qst + (size_t)row * DCODE + d) =
        make_float4((float)qs[0], (float)qs[1], (float)qs[2], (float)qs[3]);
    ushort u[4];
    #pragma unroll
    for (int e = 0; e < 4; ++e) {
        bf16 h = __float2bfloat16((float)qs[e]);
        u[e] = *(ushort*)&h;
    }
    *(ushort4*)(qstb + (size_t)row * DCODE + d) = make_ushort4(u[0], u[1], u[2], u[3]);

    #pragma unroll
    for (int off = 32; off; off >>= 1) s += __shfl_down(s, off, 64);
    __shared__ double sred[4];
    if (lane == 0) {
        sred[tid >> 6] = s;
        out_idx[row] = (float)idx;
    }
    __syncthreads();
    if (tid == 0) psum[blockIdx.x] = sred[0] + sred[1] + sred[2] + sred[3];
}

// ---------------------------------------------------------------------------
// final loss reduce over BDIM/4 block partials
// ---------------------------------------------------------------------------
__global__ __launch_bounds__(256)
void loss_k(const double* __restrict__ psum, float* __restrict__ out_loss)
{
    const int tid = threadIdx.x;
    double s = 0.0;
    for (int i = tid; i < BDIM / 4; i += 256) s += psum[i];
    #pragma unroll
    for (int off = 32; off; off >>= 1) s += __shfl_down(s, off, 64);
    __shared__ double sred[4];
    if ((tid & 63) == 0) sred[tid >> 6] = s;
    __syncthreads();
    if (tid == 0)
        out_loss[0] = (float)(1.25 * (sred[0] + sred[1] + sred[2] + sred[3]) / 4194304.0);
}

// ===========================================================================
extern "C" void kernel_launch(void* const* d_in, const int* in_sizes, int n_in,
                              void* d_out, int out_size, void* d_ws, size_t ws_size,
                              hipStream_t stream)
{
    const float* x   = (const float*)d_in[0];
    const float* eW1 = (const float*)d_in[1];
    const float* eb1 = (const float*)d_in[2];
    const float* eW2 = (const float*)d_in[3];
    const float* eb2 = (const float*)d_in[4];
    const float* eW3 = (const float*)d_in[5];
    const float* eb3 = (const float*)d_in[6];
    const float* cbk = (const float*)d_in[7];
    const float* dW1 = (const float*)d_in[8];
    const float* db1 = (const float*)d_in[9];
    const float* dW2 = (const float*)d_in[10];
    const float* db2 = (const float*)d_in[11];
    const float* dW3 = (const float*)d_in[12];
    const float* db3 = (const float*)d_in[13];

    // --- sizes ---
    const size_t EPS1 = (size_t)3 * 2048 * 1024 * 2;
    const size_t EPS2 = (size_t)3 * 1024 * 2048 * 2;
    const size_t EPS3 = (size_t)3 * 256 * 1024 * 2;
    const size_t EPS  = EPS1 + EPS2 + EPS3;
    const size_t FIX_W1 = (size_t)1024 * 256 * 2;
    const size_t FIX_W2 = (size_t)2048 * 1024 * 2;
    const size_t FIX_W3 = (size_t)1024 * 2048 * 2;
    const size_t ZB   = (size_t)BDIM * DCODE * 8;
    const size_t ZPLB = (size_t)3 * BDIM * DCODE * 2;
    const size_t QSTB = (size_t)BDIM * DCODE * 2;
    const size_t IDXB = (size_t)BDIM * 4;
    const size_t NPT  = KCODE / 128;
    const size_t PSCB = (size_t)BDIM * NPT * 8;
    const size_t PIXB = (size_t)BDIM * NPT * 4;
    const size_t CBPB = (size_t)3 * KCODE * DCODE * 2;
    const size_t PSUM = (size_t)(BDIM / 4) * 8;

    const size_t PERSIST = FIX_W1 + FIX_W2 + FIX_W3 + ZB + ZPLB + QSTB + IDXB
                         + PSCB + PIXB + CBPB + PSUM + 8192 + 256;

    // per-row chunk region: xpl 6144 | h1pl 12288 | h2pl 6144
    int R = BDIM;
    while (R > 256 && PERSIST + EPS + (size_t)R * 24576 > ws_size) R >>= 1;
    const int nch = BDIM / R;

    char* ws = (char*)d_ws;
    size_t off = 0;
    ushort* eP1  = (ushort*)(ws + off); off += EPS1;
    ushort* eP2  = (ushort*)(ws + off); off += EPS2;
    ushort* eP3  = (ushort*)(ws + off); off += EPS3;
    ushort* xpl  = (ushort*)(ws + off); off += (size_t)R * 6144;
    ushort* h1pl = (ushort*)(ws + off); off += (size_t)R * 12288;
    ushort* h2pl = (ushort*)(ws + off); off += (size_t)R * 6144;
    ushort* dh1b = xpl;                   // phase-4 alias: R x 1024 bf16
    ushort* dh2b = h1pl;                  // phase-4 alias: R x 2048 bf16
    ushort* Wt1  = (ushort*)(ws + off); off += FIX_W1;
    ushort* Wt2  = (ushort*)(ws + off); off += FIX_W2;
    ushort* Wt3  = (ushort*)(ws + off); off += FIX_W3;
    double* zb   = (double*)(ws + off); off += ZB;
    ushort* zpl  = (ushort*)(ws + off); off += ZPLB;
    ushort* qstb = (ushort*)(ws + off); off += QSTB;
    int*    idxb = (int*)(ws + off);    off += IDXB;
    double* psc  = (double*)(ws + off); off += PSCB;
    int*    pix  = (int*)(ws + off);    off += PIXB;
    ushort* cbP  = (ushort*)(ws + off); off += CBPB;
    double* psum = (double*)(ws + off); off += PSUM;
    double* c2   = (double*)(ws + off); off += 8192;

    float* out      = (float*)d_out;
    float* out_rec  = out;
    float* out_qst  = out + (size_t)BDIM * DIN;
    float* out_loss = out_qst + (size_t)BDIM * DCODE;
    float* out_idx  = out_loss + 1;

    c2_k<<<KCODE, 64, 0, stream>>>(cbk, c2);
    wtrans<<<dim3(1024 / 64,  256 / 64), 256, 0, stream>>>(dW1, Wt1,  256, 1024);
    wtrans<<<dim3(2048 / 64, 1024 / 64), 256, 0, stream>>>(dW2, Wt2, 1024, 2048);
    wtrans<<<dim3(1024 / 64, 2048 / 64), 256, 0, stream>>>(dW3, Wt3, 2048, 1024);
    wsplit<<<dim3(2048 / 64, 1024 / 64), 256, 0, stream>>>(eW1, eP1, 1024, 2048);
    wsplit<<<dim3(1024 / 64, 2048 / 64), 256, 0, stream>>>(eW2, eP2, 2048, 1024);
    wsplit<<<dim3( 256 / 64, 1024 / 64), 256, 0, stream>>>(eW3, eP3, 1024,  256);
    xsplit<<<(KCODE * DCODE) / 1024, 256, 0, stream>>>(cbk, cbP, (size_t)KCODE * DCODE);

    // phase 1: encoder chunks -> zb (f64) + zpl (limb planes, fused)
    for (int c = 0; c < nch; ++c) {
        const float* xc = x + (size_t)c * R * DIN;
        double* zb_c  = zb + (size_t)c * R * DCODE;
        ushort* zpl_c = zpl + (size_t)c * R * DCODE;
        xsplit<<<R, 256, 0, stream>>>(xc, xpl, (size_t)R * DIN);
        gemms<1, 0><<<dim3(DH1 / 128, R / 128), 512, 0, stream>>>(
            xpl, eP1, eb1, h1pl, nullptr, R, DH1, DIN,
            (size_t)R * DIN, (size_t)DH1 * DIN, (size_t)R * DH1);
        gemms<1, 0><<<dim3(DH2 / 128, R / 128), 512, 0, stream>>>(
            h1pl, eP2, eb2, h2pl, nullptr, R, DH2, DH1,
            (size_t)R * DH1, (size_t)DH2 * DH1, (size_t)R * DH2);
        gemms<0, 3><<<dim3(DCODE / 128, R / 128), 512, 0, stream>>>(
            h2pl, eP3, eb3, zb_c, zpl_c, R, DCODE, DH2,
            (size_t)R * DH2, (size_t)DCODE * DH2, (size_t)BDIM * DCODE);
    }

    // phase 2: VQ on matrix cores, full batch
    distm<<<dim3(KCODE / 128, BDIM / 128), 512, 0, stream>>>(zpl, cbP, c2, psc, pix);
    reduce8<<<BDIM / 256, 256, 0, stream>>>(psc, pix, idxb);

    // phase 3: gather + loss partials, full batch
    gather_k<<<BDIM / 4, 256, 0, stream>>>(idxb, cbk, zb, qstb, out_qst, out_idx, psum);

    // phase 4: decoder chunks
    for (int c = 0; c < nch; ++c) {
        const ushort* qst_c = qstb + (size_t)c * R * DCODE;
        float* rec_c = out_rec + (size_t)c * R * DIN;
        gemmb2<1, 1><<<dim3(DH2 / 128, R / 128), 256, 0, stream>>>(qst_c, Wt1, db1, dh1b, R, DH2, DCODE);
        gemmb2<1, 1><<<dim3(DH1 / 128, R / 128), 256, 0, stream>>>(dh1b, Wt2, db2, dh2b, R, DH1, DH2);
        gemmb2<0, 0><<<dim3(DIN / 128, R / 128), 256, 0, stream>>>(dh2b, Wt3, db3, rec_c, R, DIN, DH1);
    }

    loss_k<<<1, 256, 0, stream>>>(psum, out_loss);
}

// Round 5
// 1549.939 us; speedup vs baseline: 2.2310x; 1.0244x over previous
//
#include <hip/hip_runtime.h>
#include <hip/hip_bf16.h>
#include <stdint.h>

// ===========================================================================
// VQ-VAE forward, MI355X. Round 10: XCD-chunked swizzle + 3-deep pipeline.
// R9 = 1588us: gemms 277us vs 100us MFMA floor (MfmaUtil 32). FETCH 406MB =
// 8x unique A (round-robin XCD placement re-fetches each A-panel per XCD);
// depth-1 prefetch (1 K-step = ~466cyc cover) can't hide the resulting
// L2-miss latency. This round: (a) 1D launch + chunked XCD swizzle
// (wg = (wg%8)*(nwg/8)+wg/8, guarded to bijective cases) so each XCD owns
// contiguous row-panels -> A fetched once per XCD; (b) LDS triple-buffer,
// stage s+2 ahead, vmcnt(12) [gemms] / vmcnt(8) [gemmb2] -> 2-K-step
// latency budget (~930cyc) covers HBM-class misses. distm gets the swizzle.
//
// Numerics unchanged (3-limb split-bf16, 6 products, f64 folds every 2
// K-steps; distances via limb MFMA + c2; loss from f64 z).
// Layout: inputs f32; out f32: rec[16384*1024] | qst[16384*256] | loss[1]
// | idx[16384].
// ===========================================================================

#define BDIM  16384
#define DIN   1024
#define DH1   2048
#define DH2   1024
#define DCODE 256
#define KCODE 1024

typedef __hip_bfloat16 bf16;
typedef __attribute__((ext_vector_type(8))) short short8;
typedef __attribute__((ext_vector_type(4))) float f32x4;

// ---------------------------------------------------------------------------
// async global->LDS, 16B per lane (wave-uniform LDS base + lane*16)
// ---------------------------------------------------------------------------
__device__ __forceinline__ void gload16(const void* g, void* l)
{
    __builtin_amdgcn_global_load_lds(
        (const __attribute__((address_space(1))) unsigned int*)g,
        (__attribute__((address_space(3))) unsigned int*)l, 16, 0, 0);
}

// ---------------------------------------------------------------------------
// chunked XCD swizzle: XCD j owns contiguous tile range. bijective iff
// nwg % 8 == 0 (all our grids); otherwise identity.
// ---------------------------------------------------------------------------
__device__ __forceinline__ void swz_xcd(int gxlog, int* bx, int* by)
{
    unsigned wg = blockIdx.x;
    const unsigned nwg = gridDim.x;
    if ((nwg & 7u) == 0u) wg = (wg & 7u) * (nwg >> 3) + (wg >> 3);
    *bx = wg & ((1u << gxlog) - 1u);
    *by = wg >> gxlog;
}

// ---------------------------------------------------------------------------
// 3-limb bf16 split: f = h + m + l up to ~2^-24 relative.
// ---------------------------------------------------------------------------
__device__ __forceinline__ void split3(float f, ushort* h, ushort* m, ushort* l)
{
    bf16 bh = __float2bfloat16(f);
    float r1 = f - __bfloat162float(bh);
    bf16 bm = __float2bfloat16(r1);
    float r2 = r1 - __bfloat162float(bm);
    bf16 bl = __float2bfloat16(r2);
    *h = *(ushort*)&bh; *m = *(ushort*)&bm; *l = *(ushort*)&bl;
}

// ---------------------------------------------------------------------------
// split-bf16 MFMA GEMM, triple-buffered DMA staging + counted vmcnt +
// XCD-chunked swizzle. A planes: [M][K] bf16 stride PA; Bt: [N][K] stride PB.
// 128x128 tile, BK=32, 512 thr / 8 waves, wave tile 32x64.
// LDS: [3][3][128][32] per matrix (144 KB total), slot swizzle
// phys = logical ^ ((row>>1)&3) on global src AND fragment read.
// OUTK: 0 = 3 limb planes (stride PC); 2 = f64; 3 = f64 + limb planes (C2).
// ---------------------------------------------------------------------------
template<int RELU, int OUTK>
__global__ __launch_bounds__(512, 2)
void gemms(const ushort* __restrict__ Apl, const ushort* __restrict__ Bpl,
           const float* __restrict__ bias, void* __restrict__ C,
           void* __restrict__ C2,
           int M, int N, int K, size_t PA, size_t PB, size_t PC, int gxlog)
{
    __shared__ __align__(16) short As[3][3][128][32];   // [buf][plane][row][k]
    __shared__ __align__(16) short Bs[3][3][128][32];
    const int tid  = threadIdx.x;
    const int lane = tid & 63;
    const int wave = tid >> 6;                 // 0..7
    const int wm = (wave >> 1) << 5;           // {0,32,64,96}
    const int wn = (wave & 1) << 6;            // {0,64}
    const int fr = lane & 15, fq = lane >> 4;
    int bx, by;
    swz_xcd(gxlog, &bx, &by);
    const int row0 = by << 7, col0 = bx << 7;

    // staging: wave w covers rows [16w,16w+16) of each (matrix,plane)
    const int srow = (wave << 4) + (lane >> 2);       // 0..127
    const int sslot = lane & 3;                       // physical 8-short slot
    const int skg = (sslot ^ ((srow >> 1) & 3)) << 3; // logical k offset

    const ushort* AgT = Apl + (size_t)(row0 + srow) * K + skg;
    const ushort* BgT = Bpl + (size_t)(col0 + srow) * K + skg;

    f32x4  acc[2][4];
    double dacc[2][4][4];
    #pragma unroll
    for (int i = 0; i < 2; ++i)
        #pragma unroll
        for (int j = 0; j < 4; ++j) {
            acc[i][j] = (f32x4)0.0f;
            #pragma unroll
            for (int r = 0; r < 4; ++r) dacc[i][j][r] = 0.0;
        }

    auto stage = [&](int b, int kb) {
        #pragma unroll
        for (int p = 0; p < 3; ++p) {
            gload16(AgT + (size_t)p * PA + kb, &As[b][p][wave << 4][0]);
            gload16(BgT + (size_t)p * PB + kb, &Bs[b][p][wave << 4][0]);
        }
    };

    stage(0, 0);
    stage(1, 32);
    const int nsteps = K >> 5;
    int b = 0, sb = 2;                     // compute buf, next stage buf
    for (int s = 0; s < nsteps; ++s) {
        if (s + 2 < nsteps) {
            stage(sb, (s + 2) << 5);       // issue 2-ahead
            sb = (sb == 2) ? 0 : sb + 1;
            asm volatile("s_waitcnt vmcnt(12)" ::: "memory");  // buf s landed
        } else if (s + 1 < nsteps) {
            asm volatile("s_waitcnt vmcnt(6)" ::: "memory");
        } else {
            asm volatile("s_waitcnt vmcnt(0)" ::: "memory");
        }
        __builtin_amdgcn_s_barrier();          // all waves' cur loads landed
        __builtin_amdgcn_sched_barrier(0);

        short8 bh[4], bm[4], bl[4];
        #pragma unroll
        for (int j = 0; j < 4; ++j) {
            const int bn = wn + (j << 4) + fr;
            const int bsl = (fq ^ ((bn >> 1) & 3)) << 3;
            bh[j] = *(const short8*)&Bs[b][0][bn][bsl];
            bm[j] = *(const short8*)&Bs[b][1][bn][bsl];
            bl[j] = *(const short8*)&Bs[b][2][bn][bsl];
        }
        #pragma unroll
        for (int i = 0; i < 2; ++i) {
            const int an = wm + (i << 4) + fr;
            const int asl = (fq ^ ((an >> 1) & 3)) << 3;
            short8 ah = *(const short8*)&As[b][0][an][asl];
            short8 am = *(const short8*)&As[b][1][an][asl];
            short8 al = *(const short8*)&As[b][2][an][asl];
            #pragma unroll
            for (int j = 0; j < 4; ++j) {
                acc[i][j] = __builtin_amdgcn_mfma_f32_16x16x32_bf16(ah, bh[j], acc[i][j], 0, 0, 0);
                acc[i][j] = __builtin_amdgcn_mfma_f32_16x16x32_bf16(ah, bm[j], acc[i][j], 0, 0, 0);
                acc[i][j] = __builtin_amdgcn_mfma_f32_16x16x32_bf16(am, bh[j], acc[i][j], 0, 0, 0);
                acc[i][j] = __builtin_amdgcn_mfma_f32_16x16x32_bf16(ah, bl[j], acc[i][j], 0, 0, 0);
                acc[i][j] = __builtin_amdgcn_mfma_f32_16x16x32_bf16(al, bh[j], acc[i][j], 0, 0, 0);
                acc[i][j] = __builtin_amdgcn_mfma_f32_16x16x32_bf16(am, bm[j], acc[i][j], 0, 0, 0);
            }
        }

        if (s & 1) {   // fold f32 acc into f64 shadow every 2 K-steps (64 K)
            #pragma unroll
            for (int i = 0; i < 2; ++i)
                #pragma unroll
                for (int j = 0; j < 4; ++j) {
                    #pragma unroll
                    for (int r = 0; r < 4; ++r) dacc[i][j][r] += (double)acc[i][j][r];
                    acc[i][j] = (f32x4)0.0f;
                }
        }
        b = (b == 2) ? 0 : b + 1;
        __builtin_amdgcn_sched_barrier(0);
        __builtin_amdgcn_s_barrier();   // all reads of buf done before restage
    }
    #pragma unroll
    for (int i = 0; i < 2; ++i)
        #pragma unroll
        for (int j = 0; j < 4; ++j)
            #pragma unroll
            for (int r = 0; r < 4; ++r) dacc[i][j][r] += (double)acc[i][j][r];

    // epilogue: D[m = fq*4 + r][n = fr] per 16x16 fragment (proven map)
    #pragma unroll
    for (int j = 0; j < 4; ++j) {
        const int n = col0 + wn + (j << 4) + fr;
        const double bv = (double)bias[n];
        #pragma unroll
        for (int i = 0; i < 2; ++i) {
            const int mb = row0 + wm + (i << 4) + (fq << 2);
            #pragma unroll
            for (int r = 0; r < 4; ++r) {
                double v = dacc[i][j][r] + bv;
                if (RELU) v = v > 0.0 ? v : 0.0;
                const size_t o = (size_t)(mb + r) * N + n;
                if (OUTK == 2 || OUTK == 3) ((double*)C)[o] = v;
                if (OUTK == 0 || OUTK == 3) {
                    ushort h, m, l;
                    split3((float)v, &h, &m, &l);
                    ushort* Cp = (ushort*)((OUTK == 0) ? C : C2);
                    Cp[o] = h; Cp[PC + o] = m; Cp[2 * PC + o] = l;
                }
            }
        }
    }
}

// ---------------------------------------------------------------------------
// split-bf16 MFMA distance + fused argmin (R7 structure + XCD swizzle).
// Zpl: [3][BDIM][DCODE]; Cpl: [3][KCODE][DCODE]. 1D grid, gx=8 (gxlog=3).
// ---------------------------------------------------------------------------
__global__ __launch_bounds__(512, 2)
void distm(const ushort* __restrict__ Zpl, const ushort* __restrict__ Cpl,
           const double* __restrict__ c2, double* __restrict__ psc,
           int* __restrict__ pix)
{
    __shared__ __align__(16) short As[3][128][40];
    __shared__ __align__(16) short Bs[3][128][40];
    const int tid  = threadIdx.x;
    const int lane = tid & 63;
    const int wave = tid >> 6;
    const int wm = (wave >> 1) << 5;
    const int wn = (wave & 1) << 6;
    const int fr = lane & 15, fq = lane >> 4;
    int bx, by;
    swz_xcd(3, &bx, &by);
    const int row0 = by << 7, col0 = bx << 7;
    const int sr = tid >> 2, sc = (tid & 3) << 3;
    const size_t PZ = (size_t)BDIM * DCODE;
    const size_t PC = (size_t)KCODE * DCODE;

    const ushort* Ag = Zpl + (size_t)(row0 + sr) * DCODE + sc;
    const ushort* Bg = Cpl + (size_t)(col0 + sr) * DCODE + sc;

    f32x4  acc[2][4];
    double dacc[2][4][4];
    #pragma unroll
    for (int i = 0; i < 2; ++i)
        #pragma unroll
        for (int j = 0; j < 4; ++j) {
            acc[i][j] = (f32x4)0.0f;
            #pragma unroll
            for (int r = 0; r < 4; ++r) dacc[i][j][r] = 0.0;
        }

    short8 sa[3], sb[3];
    #pragma unroll
    for (int p = 0; p < 3; ++p) {
        sa[p] = *(const short8*)(Ag + (size_t)p * PZ);
        sb[p] = *(const short8*)(Bg + (size_t)p * PC);
    }

    const int nsteps = DCODE >> 5;   // 8
    for (int s = 0; s < nsteps; ++s) {
        __syncthreads();
        #pragma unroll
        for (int p = 0; p < 3; ++p) {
            *(short8*)&As[p][sr][sc] = sa[p];
            *(short8*)&Bs[p][sr][sc] = sb[p];
        }
        __syncthreads();
        if (s + 1 < nsteps) {
            const int kb = (s + 1) << 5;
            #pragma unroll
            for (int p = 0; p < 3; ++p) {
                sa[p] = *(const short8*)(Ag + (size_t)p * PZ + kb);
                sb[p] = *(const short8*)(Bg + (size_t)p * PC + kb);
            }
        }

        short8 bh[4], bm[4], bl[4];
        #pragma unroll
        for (int j = 0; j < 4; ++j) {
            const int bn = wn + (j << 4) + fr;
            bh[j] = *(const short8*)&Bs[0][bn][fq << 3];
            bm[j] = *(const short8*)&Bs[1][bn][fq << 3];
            bl[j] = *(const short8*)&Bs[2][bn][fq << 3];
        }
        #pragma unroll
        for (int i = 0; i < 2; ++i) {
            const int an = wm + (i << 4) + fr;
            short8 ah = *(const short8*)&As[0][an][fq << 3];
            short8 am = *(const short8*)&As[1][an][fq << 3];
            short8 al = *(const short8*)&As[2][an][fq << 3];
            #pragma unroll
            for (int j = 0; j < 4; ++j) {
                acc[i][j] = __builtin_amdgcn_mfma_f32_16x16x32_bf16(ah, bh[j], acc[i][j], 0, 0, 0);
                acc[i][j] = __builtin_amdgcn_mfma_f32_16x16x32_bf16(ah, bm[j], acc[i][j], 0, 0, 0);
                acc[i][j] = __builtin_amdgcn_mfma_f32_16x16x32_bf16(am, bh[j], acc[i][j], 0, 0, 0);
                acc[i][j] = __builtin_amdgcn_mfma_f32_16x16x32_bf16(ah, bl[j], acc[i][j], 0, 0, 0);
                acc[i][j] = __builtin_amdgcn_mfma_f32_16x16x32_bf16(al, bh[j], acc[i][j], 0, 0, 0);
                acc[i][j] = __builtin_amdgcn_mfma_f32_16x16x32_bf16(am, bm[j], acc[i][j], 0, 0, 0);
            }
        }

        if (s & 1) {
            #pragma unroll
            for (int i = 0; i < 2; ++i)
                #pragma unroll
                for (int j = 0; j < 4; ++j) {
                    #pragma unroll
                    for (int r = 0; r < 4; ++r) dacc[i][j][r] += (double)acc[i][j][r];
                    acc[i][j] = (f32x4)0.0f;
                }
        }
    }
    #pragma unroll
    for (int i = 0; i < 2; ++i)
        #pragma unroll
        for (int j = 0; j < 4; ++j)
            #pragma unroll
            for (int r = 0; r < 4; ++r) dacc[i][j][r] += (double)acc[i][j][r];

    // --- fused argmin epilogue ---
    __syncthreads();
    double* scb = (double*)&As[0][0][0];   // [128][2] scores
    int*    sib = (int*)(scb + 256);       // [128][2] indices

    #pragma unroll
    for (int i = 0; i < 2; ++i) {
        #pragma unroll
        for (int r = 0; r < 4; ++r) {
            double bs = 1e300; int bi = 0;
            #pragma unroll
            for (int j = 0; j < 4; ++j) {
                const int n = col0 + wn + (j << 4) + fr;
                const double s = c2[n] - 2.0 * dacc[i][j][r];
                if (s < bs) { bs = s; bi = n; }
            }
            #pragma unroll
            for (int msk = 1; msk < 16; msk <<= 1) {
                double os = __shfl_xor(bs, msk, 64);
                int    oi = __shfl_xor(bi, msk, 64);
                if (os < bs || (os == bs && oi < bi)) { bs = os; bi = oi; }
            }
            if (fr == 0) {
                const int lr = wm + (i << 4) + (fq << 2) + r;
                scb[lr * 2 + (wave & 1)] = bs;
                sib[lr * 2 + (wave & 1)] = bi;
            }
        }
    }
    __syncthreads();
    if (tid < 128) {
        double s0 = scb[tid * 2], s1 = scb[tid * 2 + 1];
        int    i0 = sib[tid * 2], i1 = sib[tid * 2 + 1];
        const bool t1 = (s1 < s0) || (s1 == s0 && i1 < i0);
        const size_t o = (size_t)(row0 + tid) * (KCODE / 128) + bx;
        psc[o] = t1 ? s1 : s0;
        pix[o] = t1 ? i1 : i0;
    }
}

// ---------------------------------------------------------------------------
// reduce partial argmins: [row][8] -> idx
// ---------------------------------------------------------------------------
__global__ __launch_bounds__(256)
void reduce8(const double* __restrict__ psc, const int* __restrict__ pix,
             int* __restrict__ idx_out)
{
    const int row = blockIdx.x * 256 + threadIdx.x;
    const double* ps = psc + (size_t)row * (KCODE / 128);
    const int*    pi = pix + (size_t)row * (KCODE / 128);
    double m = ps[0]; int mi = pi[0];
    #pragma unroll
    for (int t = 1; t < KCODE / 128; ++t) {
        double s = ps[t]; int c = pi[t];
        if (s < m || (s == m && c < mi)) { m = s; mi = c; }
    }
    idx_out[row] = mi;
}

// ---------------------------------------------------------------------------
// bf16 MFMA GEMM (decoder), triple-buffered DMA staging + counted vmcnt +
// XCD swizzle. A:[M][K], Bt:[N][K]. 128x128, BK=32, 256 thr, wave 64x64.
// LDS [3][128][32] per matrix (48 KB), slot swizzle as gemms.
// ---------------------------------------------------------------------------
template<int RELU, int OUTBF>
__global__ __launch_bounds__(256)
void gemmb2(const ushort* __restrict__ A, const ushort* __restrict__ Bt,
            const float* __restrict__ bias, void* __restrict__ C,
            int M, int N, int K, int gxlog)
{
    __shared__ __align__(16) short As[3][128][32];
    __shared__ __align__(16) short Bs[3][128][32];
    const int tid  = threadIdx.x;
    const int lane = tid & 63;
    const int wave = tid >> 6;                  // 0..3
    const int wm = (wave >> 1) << 6, wn = (wave & 1) << 6;
    const int fr = lane & 15;
    const int fq = lane >> 4;
    int bx, by;
    swz_xcd(gxlog, &bx, &by);
    const int row0 = by << 7, col0 = bx << 7;

    // staging: wave w covers rows [32w, 32w+32) as two 16-row chunks
    const int sr0 = (wave << 5) + (lane >> 2);
    const int sslot = lane & 3;
    const int kg0 = (sslot ^ ((sr0 >> 1) & 3)) << 3;
    const int sr1 = sr0 + 16;
    const int kg1 = (sslot ^ ((sr1 >> 1) & 3)) << 3;

    const ushort* Ag0 = A  + (size_t)(row0 + sr0) * K + kg0;
    const ushort* Ag1 = A  + (size_t)(row0 + sr1) * K + kg1;
    const ushort* Bg0 = Bt + (size_t)(col0 + sr0) * K + kg0;
    const ushort* Bg1 = Bt + (size_t)(col0 + sr1) * K + kg1;

    f32x4 acc[4][4];
    #pragma unroll
    for (int i = 0; i < 4; ++i)
        #pragma unroll
        for (int j = 0; j < 4; ++j) acc[i][j] = (f32x4)0.0f;

    auto stage = [&](int b, int kb) {
        gload16(Ag0 + kb, &As[b][wave << 5][0]);
        gload16(Ag1 + kb, &As[b][(wave << 5) + 16][0]);
        gload16(Bg0 + kb, &Bs[b][wave << 5][0]);
        gload16(Bg1 + kb, &Bs[b][(wave << 5) + 16][0]);
    };

    stage(0, 0);
    stage(1, 32);
    const int nsteps = K >> 5;
    int b = 0, sbuf = 2;
    for (int s = 0; s < nsteps; ++s) {
        if (s + 2 < nsteps) {
            stage(sbuf, (s + 2) << 5);
            sbuf = (sbuf == 2) ? 0 : sbuf + 1;
            asm volatile("s_waitcnt vmcnt(8)" ::: "memory");
        } else if (s + 1 < nsteps) {
            asm volatile("s_waitcnt vmcnt(4)" ::: "memory");
        } else {
            asm volatile("s_waitcnt vmcnt(0)" ::: "memory");
        }
        __builtin_amdgcn_s_barrier();
        __builtin_amdgcn_sched_barrier(0);

        short8 af[4], bf[4];
        #pragma unroll
        for (int i = 0; i < 4; ++i) {
            const int an = wm + (i << 4) + fr;
            af[i] = *(const short8*)&As[b][an][(fq ^ ((an >> 1) & 3)) << 3];
        }
        #pragma unroll
        for (int j = 0; j < 4; ++j) {
            const int bn = wn + (j << 4) + fr;
            bf[j] = *(const short8*)&Bs[b][bn][(fq ^ ((bn >> 1) & 3)) << 3];
        }
        #pragma unroll
        for (int i = 0; i < 4; ++i)
            #pragma unroll
            for (int j = 0; j < 4; ++j)
                acc[i][j] = __builtin_amdgcn_mfma_f32_16x16x32_bf16(
                                af[i], bf[j], acc[i][j], 0, 0, 0);

        b = (b == 2) ? 0 : b + 1;
        __builtin_amdgcn_sched_barrier(0);
        __builtin_amdgcn_s_barrier();
    }

    #pragma unroll
    for (int j = 0; j < 4; ++j) {
        const int n = col0 + wn + (j << 4) + fr;
        const float bv = bias[n];
        #pragma unroll
        for (int i = 0; i < 4; ++i) {
            const int mb = row0 + wm + (i << 4) + (fq << 2);
            #pragma unroll
            for (int r = 0; r < 4; ++r) {
                float v = acc[i][j][r] + bv;
                if (RELU) v = fmaxf(v, 0.0f);
                size_t o = (size_t)(mb + r) * N + n;
                if (OUTBF) ((bf16*)C)[o]  = __float2bfloat16(v);
                else       ((float*)C)[o] = v;
            }
        }
    }
}

// ---------------------------------------------------------------------------
// decoder weight transpose + f32->bf16 (unchanged)
// ---------------------------------------------------------------------------
__global__ __launch_bounds__(256)
void wtrans(const float* __restrict__ W, ushort* __restrict__ Wt, int K, int N)
{
    __shared__ float tile[64][65];
    const int tid = threadIdx.x;
    const int kb = blockIdx.y << 6, nb = blockIdx.x << 6;
    const int r = tid >> 4, c4 = (tid & 15) << 2;
    #pragma unroll
    for (int s = 0; s < 4; ++s) {
        float4 v = *(const float4*)(W + (size_t)(kb + r + (s << 4)) * N + nb + c4);
        tile[r + (s << 4)][c4 + 0] = v.x; tile[r + (s << 4)][c4 + 1] = v.y;
        tile[r + (s << 4)][c4 + 2] = v.z; tile[r + (s << 4)][c4 + 3] = v.w;
    }
    __syncthreads();
    #pragma unroll
    for (int s = 0; s < 4; ++s) {
        const int n = r + (s << 4);
        ushort u[4];
        #pragma unroll
        for (int l = 0; l < 4; ++l) {
            bf16 h = __float2bfloat16(tile[c4 + l][n]);
            u[l] = *(ushort*)&h;
        }
        *(ushort4*)(Wt + (size_t)(nb + n) * K + kb + c4) = make_ushort4(u[0], u[1], u[2], u[3]);
    }
}

// ---------------------------------------------------------------------------
// encoder weight transpose + 3-limb split: planes [N][K], stride N*K
// ---------------------------------------------------------------------------
__global__ __launch_bounds__(256)
void wsplit(const float* __restrict__ W, ushort* __restrict__ Wt, int K, int N)
{
    __shared__ float tile[64][65];
    const int tid = threadIdx.x;
    const int kb = blockIdx.y << 6, nb = blockIdx.x << 6;
    const int r = tid >> 4, c4 = (tid & 15) << 2;
    const size_t NK = (size_t)N * K;
    #pragma unroll
    for (int s = 0; s < 4; ++s) {
        float4 v = *(const float4*)(W + (size_t)(kb + r + (s << 4)) * N + nb + c4);
        tile[r + (s << 4)][c4 + 0] = v.x; tile[r + (s << 4)][c4 + 1] = v.y;
        tile[r + (s << 4)][c4 + 2] = v.z; tile[r + (s << 4)][c4 + 3] = v.w;
    }
    __syncthreads();
    #pragma unroll
    for (int s = 0; s < 4; ++s) {
        const int n = r + (s << 4);
        ushort h[4], m[4], l[4];
        #pragma unroll
        for (int e = 0; e < 4; ++e) split3(tile[c4 + e][n], &h[e], &m[e], &l[e]);
        const size_t o = (size_t)(nb + n) * K + kb + c4;
        *(ushort4*)(Wt + o)          = make_ushort4(h[0], h[1], h[2], h[3]);
        *(ushort4*)(Wt + NK + o)     = make_ushort4(m[0], m[1], m[2], m[3]);
        *(ushort4*)(Wt + 2 * NK + o) = make_ushort4(l[0], l[1], l[2], l[3]);
    }
}

// ---------------------------------------------------------------------------
// f32 row-major -> 3 bf16 limb planes, plane stride P (x and codebook)
// ---------------------------------------------------------------------------
__global__ __launch_bounds__(256)
void xsplit(const float* __restrict__ X, ushort* __restrict__ Xp, size_t P)
{
    const size_t i = ((size_t)blockIdx.x * 256 + threadIdx.x) << 2;
    float4 v = *(const float4*)(X + i);
    ushort h[4], m[4], l[4];
    split3(v.x, &h[0], &m[0], &l[0]);
    split3(v.y, &h[1], &m[1], &l[1]);
    split3(v.z, &h[2], &m[2], &l[2]);
    split3(v.w, &h[3], &m[3], &l[3]);
    *(ushort4*)(Xp + i)         = make_ushort4(h[0], h[1], h[2], h[3]);
    *(ushort4*)(Xp + P + i)     = make_ushort4(m[0], m[1], m[2], m[3]);
    *(ushort4*)(Xp + 2 * P + i) = make_ushort4(l[0], l[1], l[2], l[3]);
}

// ---------------------------------------------------------------------------
// codebook squared norms (f64)
// ---------------------------------------------------------------------------
__global__ __launch_bounds__(64)
void c2_k(const float* __restrict__ cb, double* __restrict__ c2)
{
    int code = blockIdx.x, l = threadIdx.x;
    float4 v = *(const float4*)(cb + (size_t)code * DCODE + (l << 2));
    double s = (double)v.x * v.x + (double)v.y * v.y
             + (double)v.z * v.z + (double)v.w * v.w;
    #pragma unroll
    for (int off = 32; off; off >>= 1) s += __shfl_down(s, off, 64);
    if (l == 0) c2[code] = s;
}

// ---------------------------------------------------------------------------
// gather + straight-through + loss partials + idx. 4 rows/block, no atomics.
// ---------------------------------------------------------------------------
__global__ __launch_bounds__(256)
void gather_k(const int* __restrict__ idx_in, const float* __restrict__ cb,
              const double* __restrict__ z, ushort* __restrict__ qstb,
              float* __restrict__ out_qst, float* __restrict__ out_idx,
              double* __restrict__ psum)
{
    const int tid  = threadIdx.x;
    const int row  = (blockIdx.x << 2) + (tid >> 6);
    const int lane = tid & 63;
    const int d    = lane << 2;
    const int idx  = idx_in[row];

    float4 qv = *(const float4*)(cb + (size_t)idx * DCODE + d);
    const double* zp = z + (size_t)row * DCODE + d;
    double2 z0 = *(const double2*)(zp);
    double2 z1 = *(const double2*)(zp + 2);

    double q[4] = {(double)qv.x, (double)qv.y, (double)qv.z, (double)qv.w};
    double zz[4] = {z0.x, z0.y, z1.x, z1.y};
    double qs[4];
    double s = 0.0;
    #pragma unroll
    for (int e = 0; e < 4; ++e) {
        double diff = q[e] - zz[e];
        qs[e] = zz[e] + diff;
        s += diff * diff;
    }
    *(float4*)(out_qst + (size_t)row * DCODE + d) =
        make_float4((float)qs[0], (float)qs[1], (float)qs[2], (float)qs[3]);
    ushort u[4];
    #pragma unroll
    for (int e = 0; e < 4; ++e) {
        bf16 h = __float2bfloat16((float)qs[e]);
        u[e] = *(ushort*)&h;
    }
    *(ushort4*)(qstb + (size_t)row * DCODE + d) = make_ushort4(u[0], u[1], u[2], u[3]);

    #pragma unroll
    for (int off = 32; off; off >>= 1) s += __shfl_down(s, off, 64);
    __shared__ double sred[4];
    if (lane == 0) {
        sred[tid >> 6] = s;
        out_idx[row] = (float)idx;
    }
    __syncthreads();
    if (tid == 0) psum[blockIdx.x] = sred[0] + sred[1] + sred[2] + sred[3];
}

// ---------------------------------------------------------------------------
// final loss reduce over BDIM/4 block partials
// ---------------------------------------------------------------------------
__global__ __launch_bounds__(256)
void loss_k(const double* __restrict__ psum, float* __restrict__ out_loss)
{
    const int tid = threadIdx.x;
    double s = 0.0;
    for (int i = tid; i < BDIM / 4; i += 256) s += psum[i];
    #pragma unroll
    for (int off = 32; off; off >>= 1) s += __shfl_down(s, off, 64);
    __shared__ double sred[4];
    if ((tid & 63) == 0) sred[tid >> 6] = s;
    __syncthreads();
    if (tid == 0)
        out_loss[0] = (float)(1.25 * (sred[0] + sred[1] + sred[2] + sred[3]) / 4194304.0);
}

// ===========================================================================
extern "C" void kernel_launch(void* const* d_in, const int* in_sizes, int n_in,
                              void* d_out, int out_size, void* d_ws, size_t ws_size,
                              hipStream_t stream)
{
    const float* x   = (const float*)d_in[0];
    const float* eW1 = (const float*)d_in[1];
    const float* eb1 = (const float*)d_in[2];
    const float* eW2 = (const float*)d_in[3];
    const float* eb2 = (const float*)d_in[4];
    const float* eW3 = (const float*)d_in[5];
    const float* eb3 = (const float*)d_in[6];
    const float* cbk = (const float*)d_in[7];
    const float* dW1 = (const float*)d_in[8];
    const float* db1 = (const float*)d_in[9];
    const float* dW2 = (const float*)d_in[10];
    const float* db2 = (const float*)d_in[11];
    const float* dW3 = (const float*)d_in[12];
    const float* db3 = (const float*)d_in[13];

    // --- sizes ---
    const size_t EPS1 = (size_t)3 * 2048 * 1024 * 2;
    const size_t EPS2 = (size_t)3 * 1024 * 2048 * 2;
    const size_t EPS3 = (size_t)3 * 256 * 1024 * 2;
    const size_t EPS  = EPS1 + EPS2 + EPS3;
    const size_t FIX_W1 = (size_t)1024 * 256 * 2;
    const size_t FIX_W2 = (size_t)2048 * 1024 * 2;
    const size_t FIX_W3 = (size_t)1024 * 2048 * 2;
    const size_t ZB   = (size_t)BDIM * DCODE * 8;
    const size_t ZPLB = (size_t)3 * BDIM * DCODE * 2;
    const size_t QSTB = (size_t)BDIM * DCODE * 2;
    const size_t IDXB = (size_t)BDIM * 4;
    const size_t NPT  = KCODE / 128;
    const size_t PSCB = (size_t)BDIM * NPT * 8;
    const size_t PIXB = (size_t)BDIM * NPT * 4;
    const size_t CBPB = (size_t)3 * KCODE * DCODE * 2;
    const size_t PSUM = (size_t)(BDIM / 4) * 8;

    const size_t PERSIST = FIX_W1 + FIX_W2 + FIX_W3 + ZB + ZPLB + QSTB + IDXB
                         + PSCB + PIXB + CBPB + PSUM + 8192 + 256;

    // per-row chunk region: xpl 6144 | h1pl 12288 | h2pl 6144
    int R = BDIM;
    while (R > 256 && PERSIST + EPS + (size_t)R * 24576 > ws_size) R >>= 1;
    const int nch = BDIM / R;

    char* ws = (char*)d_ws;
    size_t off = 0;
    ushort* eP1  = (ushort*)(ws + off); off += EPS1;
    ushort* eP2  = (ushort*)(ws + off); off += EPS2;
    ushort* eP3  = (ushort*)(ws + off); off += EPS3;
    ushort* xpl  = (ushort*)(ws + off); off += (size_t)R * 6144;
    ushort* h1pl = (ushort*)(ws + off); off += (size_t)R * 12288;
    ushort* h2pl = (ushort*)(ws + off); off += (size_t)R * 6144;
    ushort* dh1b = xpl;                   // phase-4 alias: R x 1024 bf16
    ushort* dh2b = h1pl;                  // phase-4 alias: R x 2048 bf16
    ushort* Wt1  = (ushort*)(ws + off); off += FIX_W1;
    ushort* Wt2  = (ushort*)(ws + off); off += FIX_W2;
    ushort* Wt3  = (ushort*)(ws + off); off += FIX_W3;
    double* zb   = (double*)(ws + off); off += ZB;
    ushort* zpl  = (ushort*)(ws + off); off += ZPLB;
    ushort* qstb = (ushort*)(ws + off); off += QSTB;
    int*    idxb = (int*)(ws + off);    off += IDXB;
    double* psc  = (double*)(ws + off); off += PSCB;
    int*    pix  = (int*)(ws + off);    off += PIXB;
    ushort* cbP  = (ushort*)(ws + off); off += CBPB;
    double* psum = (double*)(ws + off); off += PSUM;
    double* c2   = (double*)(ws + off); off += 8192;

    float* out      = (float*)d_out;
    float* out_rec  = out;
    float* out_qst  = out + (size_t)BDIM * DIN;
    float* out_loss = out_qst + (size_t)BDIM * DCODE;
    float* out_idx  = out_loss + 1;

    c2_k<<<KCODE, 64, 0, stream>>>(cbk, c2);
    wtrans<<<dim3(1024 / 64,  256 / 64), 256, 0, stream>>>(dW1, Wt1,  256, 1024);
    wtrans<<<dim3(2048 / 64, 1024 / 64), 256, 0, stream>>>(dW2, Wt2, 1024, 2048);
    wtrans<<<dim3(1024 / 64, 2048 / 64), 256, 0, stream>>>(dW3, Wt3, 2048, 1024);
    wsplit<<<dim3(2048 / 64, 1024 / 64), 256, 0, stream>>>(eW1, eP1, 1024, 2048);
    wsplit<<<dim3(1024 / 64, 2048 / 64), 256, 0, stream>>>(eW2, eP2, 2048, 1024);
    wsplit<<<dim3( 256 / 64, 1024 / 64), 256, 0, stream>>>(eW3, eP3, 1024,  256);
    xsplit<<<(KCODE * DCODE) / 1024, 256, 0, stream>>>(cbk, cbP, (size_t)KCODE * DCODE);

    const int rb = R / 128;   // row tiles per chunk

    // phase 1: encoder chunks -> zb (f64) + zpl (limb planes, fused)
    for (int c = 0; c < nch; ++c) {
        const float* xc = x + (size_t)c * R * DIN;
        double* zb_c  = zb + (size_t)c * R * DCODE;
        ushort* zpl_c = zpl + (size_t)c * R * DCODE;
        xsplit<<<R, 256, 0, stream>>>(xc, xpl, (size_t)R * DIN);
        gemms<1, 0><<<16 * rb, 512, 0, stream>>>(
            xpl, eP1, eb1, h1pl, nullptr, R, DH1, DIN,
            (size_t)R * DIN, (size_t)DH1 * DIN, (size_t)R * DH1, 4);
        gemms<1, 0><<<8 * rb, 512, 0, stream>>>(
            h1pl, eP2, eb2, h2pl, nullptr, R, DH2, DH1,
            (size_t)R * DH1, (size_t)DH2 * DH1, (size_t)R * DH2, 3);
        gemms<0, 3><<<2 * rb, 512, 0, stream>>>(
            h2pl, eP3, eb3, zb_c, zpl_c, R, DCODE, DH2,
            (size_t)R * DH2, (size_t)DCODE * DH2, (size_t)BDIM * DCODE, 1);
    }

    // phase 2: VQ on matrix cores, full batch
    distm<<<8 * (BDIM / 128), 512, 0, stream>>>(zpl, cbP, c2, psc, pix);
    reduce8<<<BDIM / 256, 256, 0, stream>>>(psc, pix, idxb);

    // phase 3: gather + loss partials, full batch
    gather_k<<<BDIM / 4, 256, 0, stream>>>(idxb, cbk, zb, qstb, out_qst, out_idx, psum);

    // phase 4: decoder chunks
    for (int c = 0; c < nch; ++c) {
        const ushort* qst_c = qstb + (size_t)c * R * DCODE;
        float* rec_c = out_rec + (size_t)c * R * DIN;
        gemmb2<1, 1><<<8 * rb, 256, 0, stream>>>(qst_c, Wt1, db1, dh1b, R, DH2, DCODE, 3);
        gemmb2<1, 1><<<16 * rb, 256, 0, stream>>>(dh1b, Wt2, db2, dh2b, R, DH1, DH2, 4);
        gemmb2<0, 0><<<8 * rb, 256, 0, stream>>>(dh2b, Wt3, db3, rec_c, R, DIN, DH1, 3);
    }

    loss_k<<<1, 256, 0, stream>>>(psum, out_loss);
}

// Round 6
// 1435.947 us; speedup vs baseline: 2.4081x; 1.0794x over previous
//
#include <hip/hip_runtime.h>
#include <hip/hip_bf16.h>
#include <stdint.h>

// ===========================================================================
// VQ-VAE forward, MI355X. Round 11: break the 2-phase lockstep via TLP.
// R10 = 1550us: gemms at 260us vs 100us MFMA floor; per-K-step cycle budget
// shows LDS pipe (1728cyc) and MFMA pipe (1861cyc) nearly equal but measured
// step time ~= their SUM (4875cyc): the 8-wave lockstep barrier forces all
// waves to read-then-MFMA in phase, so the pipes never overlap (documented
// 2-phase ceiling). This round: gemms -> 64x128 block, 4 waves of 32x64,
// depth-2, LDS 73.7KB => 2 INDEPENDENT blocks/CU whose barrier phases
// interleave (one block MFMAs while the other reads/stages). Unroll-by-2
// makes all LDS addresses static (less VALU); setprio(1) wraps the MFMA
// cluster (role diversity now exists across blocks). distm/gemmb2 untouched.
//
// Numerics unchanged (3-limb split-bf16, 6 products, f64 folds every 2
// K-steps; distances via limb MFMA + c2; loss from f64 z).
// Layout: inputs f32; out f32: rec[16384*1024] | qst[16384*256] | loss[1]
// | idx[16384].
// ===========================================================================

#define BDIM  16384
#define DIN   1024
#define DH1   2048
#define DH2   1024
#define DCODE 256
#define KCODE 1024

typedef __hip_bfloat16 bf16;
typedef __attribute__((ext_vector_type(8))) short short8;
typedef __attribute__((ext_vector_type(4))) float f32x4;

// ---------------------------------------------------------------------------
// async global->LDS, 16B per lane (wave-uniform LDS base + lane*16)
// ---------------------------------------------------------------------------
__device__ __forceinline__ void gload16(const void* g, void* l)
{
    __builtin_amdgcn_global_load_lds(
        (const __attribute__((address_space(1))) unsigned int*)g,
        (__attribute__((address_space(3))) unsigned int*)l, 16, 0, 0);
}

// ---------------------------------------------------------------------------
// chunked XCD swizzle: XCD j owns contiguous tile range. bijective iff
// nwg % 8 == 0 (all our grids); otherwise identity.
// ---------------------------------------------------------------------------
__device__ __forceinline__ void swz_xcd(int gxlog, int* bx, int* by)
{
    unsigned wg = blockIdx.x;
    const unsigned nwg = gridDim.x;
    if ((nwg & 7u) == 0u) wg = (wg & 7u) * (nwg >> 3) + (wg >> 3);
    *bx = wg & ((1u << gxlog) - 1u);
    *by = wg >> gxlog;
}

// ---------------------------------------------------------------------------
// 3-limb bf16 split: f = h + m + l up to ~2^-24 relative.
// ---------------------------------------------------------------------------
__device__ __forceinline__ void split3(float f, ushort* h, ushort* m, ushort* l)
{
    bf16 bh = __float2bfloat16(f);
    float r1 = f - __bfloat162float(bh);
    bf16 bm = __float2bfloat16(r1);
    float r2 = r1 - __bfloat162float(bm);
    bf16 bl = __float2bfloat16(r2);
    *h = *(ushort*)&bh; *m = *(ushort*)&bm; *l = *(ushort*)&bl;
}

// ---------------------------------------------------------------------------
// split-bf16 MFMA GEMM. 64x128 block, 4 waves (wave tile 32x64), BK=32,
// depth-2 DMA staging, 2 blocks/CU (LDS 73.7KB). Unrolled x2 over buffers
// (static LDS addresses), counted vmcnt(9), setprio around MFMA.
// A planes: [M][K] bf16 stride PA; Bt: [N][K] stride PB. Slot swizzle
// phys = logical ^ ((row>>1)&3) on global src AND fragment read.
// OUTK: 0 = 3 limb planes (stride PC); 2 = f64; 3 = f64 + limb planes (C2).
// ---------------------------------------------------------------------------
template<int RELU, int OUTK>
__global__ __launch_bounds__(256, 2)
void gemms(const ushort* __restrict__ Apl, const ushort* __restrict__ Bpl,
           const float* __restrict__ bias, void* __restrict__ C,
           void* __restrict__ C2,
           int M, int N, int K, size_t PA, size_t PB, size_t PC, int gxlog)
{
    __shared__ __align__(16) short As[2][3][64][32];    // [buf][plane][row][k]
    __shared__ __align__(16) short Bs[2][3][128][32];
    const int tid  = threadIdx.x;
    const int lane = tid & 63;
    const int wave = tid >> 6;                 // 0..3
    const int wm = (wave >> 1) << 5;           // {0,32}
    const int wn = (wave & 1) << 6;            // {0,64}
    const int fr = lane & 15, fq = lane >> 4;
    int bx, by;
    swz_xcd(gxlog, &bx, &by);
    const int row0 = by << 6, col0 = bx << 7;

    // staging: wave w -> A rows [16w,16w+16), B rows [32w,32w+32) (2 chunks)
    const int sr16  = lane >> 2;
    const int sslot = lane & 3;
    const int arow  = (wave << 4) + sr16;
    const int brow0 = (wave << 5) + sr16;
    const int brow1 = brow0 + 16;
    const int akg  = (sslot ^ ((arow  >> 1) & 3)) << 3;
    const int bkg0 = (sslot ^ ((brow0 >> 1) & 3)) << 3;
    const int bkg1 = (sslot ^ ((brow1 >> 1) & 3)) << 3;

    const ushort* AgT = Apl + (size_t)(row0 + arow)  * K + akg;
    const ushort* Bg0 = Bpl + (size_t)(col0 + brow0) * K + bkg0;
    const ushort* Bg1 = Bpl + (size_t)(col0 + brow1) * K + bkg1;

    f32x4  acc[2][4];
    double dacc[2][4][4];
    #pragma unroll
    for (int i = 0; i < 2; ++i)
        #pragma unroll
        for (int j = 0; j < 4; ++j) {
            acc[i][j] = (f32x4)0.0f;
            #pragma unroll
            for (int r = 0; r < 4; ++r) dacc[i][j][r] = 0.0;
        }

    auto stage = [&](int b, int kb) {   // 9 loads/wave
        #pragma unroll
        for (int p = 0; p < 3; ++p) {
            gload16(AgT + (size_t)p * PA + kb, &As[b][p][wave << 4][0]);
            gload16(Bg0 + (size_t)p * PB + kb, &Bs[b][p][wave << 5][0]);
            gload16(Bg1 + (size_t)p * PB + kb, &Bs[b][p][(wave << 5) + 16][0]);
        }
    };

    auto compute = [&](int b) {
        short8 bh[4], bm[4], bl[4];
        #pragma unroll
        for (int j = 0; j < 4; ++j) {
            const int bn = wn + (j << 4) + fr;
            const int bsl = (fq ^ ((bn >> 1) & 3)) << 3;
            bh[j] = *(const short8*)&Bs[b][0][bn][bsl];
            bm[j] = *(const short8*)&Bs[b][1][bn][bsl];
            bl[j] = *(const short8*)&Bs[b][2][bn][bsl];
        }
        __builtin_amdgcn_s_setprio(1);
        #pragma unroll
        for (int i = 0; i < 2; ++i) {
            const int an = wm + (i << 4) + fr;
            const int asl = (fq ^ ((an >> 1) & 3)) << 3;
            short8 ah = *(const short8*)&As[b][0][an][asl];
            short8 am = *(const short8*)&As[b][1][an][asl];
            short8 al = *(const short8*)&As[b][2][an][asl];
            #pragma unroll
            for (int j = 0; j < 4; ++j) {
                acc[i][j] = __builtin_amdgcn_mfma_f32_16x16x32_bf16(ah, bh[j], acc[i][j], 0, 0, 0);
                acc[i][j] = __builtin_amdgcn_mfma_f32_16x16x32_bf16(ah, bm[j], acc[i][j], 0, 0, 0);
                acc[i][j] = __builtin_amdgcn_mfma_f32_16x16x32_bf16(am, bh[j], acc[i][j], 0, 0, 0);
                acc[i][j] = __builtin_amdgcn_mfma_f32_16x16x32_bf16(ah, bl[j], acc[i][j], 0, 0, 0);
                acc[i][j] = __builtin_amdgcn_mfma_f32_16x16x32_bf16(al, bh[j], acc[i][j], 0, 0, 0);
                acc[i][j] = __builtin_amdgcn_mfma_f32_16x16x32_bf16(am, bm[j], acc[i][j], 0, 0, 0);
            }
        }
        __builtin_amdgcn_s_setprio(0);
    };

    stage(0, 0);
    const int nsteps = K >> 5;   // always even (K in {1024, 2048})
    for (int s = 0; s < nsteps; s += 2) {
        // --- even step: compute buf0, stage buf1 ---
        stage(1, (s + 1) << 5);
        asm volatile("s_waitcnt vmcnt(9)" ::: "memory");   // buf0 landed
        __builtin_amdgcn_s_barrier();
        __builtin_amdgcn_sched_barrier(0);
        compute(0);
        __builtin_amdgcn_sched_barrier(0);
        __builtin_amdgcn_s_barrier();                      // buf0 reads done
        // --- odd step: compute buf1, stage buf0 ---
        if (s + 2 < nsteps) {
            stage(0, (s + 2) << 5);
            asm volatile("s_waitcnt vmcnt(9)" ::: "memory");
        } else {
            asm volatile("s_waitcnt vmcnt(0)" ::: "memory");
        }
        __builtin_amdgcn_s_barrier();
        __builtin_amdgcn_sched_barrier(0);
        compute(1);
        // fold f32 acc into f64 shadow every 2 K-steps (64 K)
        #pragma unroll
        for (int i = 0; i < 2; ++i)
            #pragma unroll
            for (int j = 0; j < 4; ++j) {
                #pragma unroll
                for (int r = 0; r < 4; ++r) dacc[i][j][r] += (double)acc[i][j][r];
                acc[i][j] = (f32x4)0.0f;
            }
        __builtin_amdgcn_sched_barrier(0);
        __builtin_amdgcn_s_barrier();                      // buf1 reads done
    }

    // epilogue: D[m = fq*4 + r][n = fr] per 16x16 fragment (proven map)
    #pragma unroll
    for (int j = 0; j < 4; ++j) {
        const int n = col0 + wn + (j << 4) + fr;
        const double bv = (double)bias[n];
        #pragma unroll
        for (int i = 0; i < 2; ++i) {
            const int mb = row0 + wm + (i << 4) + (fq << 2);
            #pragma unroll
            for (int r = 0; r < 4; ++r) {
                double v = dacc[i][j][r] + bv;
                if (RELU) v = v > 0.0 ? v : 0.0;
                const size_t o = (size_t)(mb + r) * N + n;
                if (OUTK == 2 || OUTK == 3) ((double*)C)[o] = v;
                if (OUTK == 0 || OUTK == 3) {
                    ushort h, m, l;
                    split3((float)v, &h, &m, &l);
                    ushort* Cp = (ushort*)((OUTK == 0) ? C : C2);
                    Cp[o] = h; Cp[PC + o] = m; Cp[2 * PC + o] = l;
                }
            }
        }
    }
}

// ---------------------------------------------------------------------------
// split-bf16 MFMA distance + fused argmin (unchanged, proven).
// Zpl: [3][BDIM][DCODE]; Cpl: [3][KCODE][DCODE]. 1D grid, gx=8 (gxlog=3).
// ---------------------------------------------------------------------------
__global__ __launch_bounds__(512, 2)
void distm(const ushort* __restrict__ Zpl, const ushort* __restrict__ Cpl,
           const double* __restrict__ c2, double* __restrict__ psc,
           int* __restrict__ pix)
{
    __shared__ __align__(16) short As[3][128][40];
    __shared__ __align__(16) short Bs[3][128][40];
    const int tid  = threadIdx.x;
    const int lane = tid & 63;
    const int wave = tid >> 6;
    const int wm = (wave >> 1) << 5;
    const int wn = (wave & 1) << 6;
    const int fr = lane & 15, fq = lane >> 4;
    int bx, by;
    swz_xcd(3, &bx, &by);
    const int row0 = by << 7, col0 = bx << 7;
    const int sr = tid >> 2, sc = (tid & 3) << 3;
    const size_t PZ = (size_t)BDIM * DCODE;
    const size_t PC = (size_t)KCODE * DCODE;

    const ushort* Ag = Zpl + (size_t)(row0 + sr) * DCODE + sc;
    const ushort* Bg = Cpl + (size_t)(col0 + sr) * DCODE + sc;

    f32x4  acc[2][4];
    double dacc[2][4][4];
    #pragma unroll
    for (int i = 0; i < 2; ++i)
        #pragma unroll
        for (int j = 0; j < 4; ++j) {
            acc[i][j] = (f32x4)0.0f;
            #pragma unroll
            for (int r = 0; r < 4; ++r) dacc[i][j][r] = 0.0;
        }

    short8 sa[3], sb[3];
    #pragma unroll
    for (int p = 0; p < 3; ++p) {
        sa[p] = *(const short8*)(Ag + (size_t)p * PZ);
        sb[p] = *(const short8*)(Bg + (size_t)p * PC);
    }

    const int nsteps = DCODE >> 5;   // 8
    for (int s = 0; s < nsteps; ++s) {
        __syncthreads();
        #pragma unroll
        for (int p = 0; p < 3; ++p) {
            *(short8*)&As[p][sr][sc] = sa[p];
            *(short8*)&Bs[p][sr][sc] = sb[p];
        }
        __syncthreads();
        if (s + 1 < nsteps) {
            const int kb = (s + 1) << 5;
            #pragma unroll
            for (int p = 0; p < 3; ++p) {
                sa[p] = *(const short8*)(Ag + (size_t)p * PZ + kb);
                sb[p] = *(const short8*)(Bg + (size_t)p * PC + kb);
            }
        }

        short8 bh[4], bm[4], bl[4];
        #pragma unroll
        for (int j = 0; j < 4; ++j) {
            const int bn = wn + (j << 4) + fr;
            bh[j] = *(const short8*)&Bs[0][bn][fq << 3];
            bm[j] = *(const short8*)&Bs[1][bn][fq << 3];
            bl[j] = *(const short8*)&Bs[2][bn][fq << 3];
        }
        #pragma unroll
        for (int i = 0; i < 2; ++i) {
            const int an = wm + (i << 4) + fr;
            short8 ah = *(const short8*)&As[0][an][fq << 3];
            short8 am = *(const short8*)&As[1][an][fq << 3];
            short8 al = *(const short8*)&As[2][an][fq << 3];
            #pragma unroll
            for (int j = 0; j < 4; ++j) {
                acc[i][j] = __builtin_amdgcn_mfma_f32_16x16x32_bf16(ah, bh[j], acc[i][j], 0, 0, 0);
                acc[i][j] = __builtin_amdgcn_mfma_f32_16x16x32_bf16(ah, bm[j], acc[i][j], 0, 0, 0);
                acc[i][j] = __builtin_amdgcn_mfma_f32_16x16x32_bf16(am, bh[j], acc[i][j], 0, 0, 0);
                acc[i][j] = __builtin_amdgcn_mfma_f32_16x16x32_bf16(ah, bl[j], acc[i][j], 0, 0, 0);
                acc[i][j] = __builtin_amdgcn_mfma_f32_16x16x32_bf16(al, bh[j], acc[i][j], 0, 0, 0);
                acc[i][j] = __builtin_amdgcn_mfma_f32_16x16x32_bf16(am, bm[j], acc[i][j], 0, 0, 0);
            }
        }

        if (s & 1) {
            #pragma unroll
            for (int i = 0; i < 2; ++i)
                #pragma unroll
                for (int j = 0; j < 4; ++j) {
                    #pragma unroll
                    for (int r = 0; r < 4; ++r) dacc[i][j][r] += (double)acc[i][j][r];
                    acc[i][j] = (f32x4)0.0f;
                }
        }
    }
    #pragma unroll
    for (int i = 0; i < 2; ++i)
        #pragma unroll
        for (int j = 0; j < 4; ++j)
            #pragma unroll
            for (int r = 0; r < 4; ++r) dacc[i][j][r] += (double)acc[i][j][r];

    // --- fused argmin epilogue ---
    __syncthreads();
    double* scb = (double*)&As[0][0][0];   // [128][2] scores
    int*    sib = (int*)(scb + 256);       // [128][2] indices

    #pragma unroll
    for (int i = 0; i < 2; ++i) {
        #pragma unroll
        for (int r = 0; r < 4; ++r) {
            double bs = 1e300; int bi = 0;
            #pragma unroll
            for (int j = 0; j < 4; ++j) {
                const int n = col0 + wn + (j << 4) + fr;
                const double s = c2[n] - 2.0 * dacc[i][j][r];
                if (s < bs) { bs = s; bi = n; }
            }
            #pragma unroll
            for (int msk = 1; msk < 16; msk <<= 1) {
                double os = __shfl_xor(bs, msk, 64);
                int    oi = __shfl_xor(bi, msk, 64);
                if (os < bs || (os == bs && oi < bi)) { bs = os; bi = oi; }
            }
            if (fr == 0) {
                const int lr = wm + (i << 4) + (fq << 2) + r;
                scb[lr * 2 + (wave & 1)] = bs;
                sib[lr * 2 + (wave & 1)] = bi;
            }
        }
    }
    __syncthreads();
    if (tid < 128) {
        double s0 = scb[tid * 2], s1 = scb[tid * 2 + 1];
        int    i0 = sib[tid * 2], i1 = sib[tid * 2 + 1];
        const bool t1 = (s1 < s0) || (s1 == s0 && i1 < i0);
        const size_t o = (size_t)(row0 + tid) * (KCODE / 128) + bx;
        psc[o] = t1 ? s1 : s0;
        pix[o] = t1 ? i1 : i0;
    }
}

// ---------------------------------------------------------------------------
// reduce partial argmins: [row][8] -> idx
// ---------------------------------------------------------------------------
__global__ __launch_bounds__(256)
void reduce8(const double* __restrict__ psc, const int* __restrict__ pix,
             int* __restrict__ idx_out)
{
    const int row = blockIdx.x * 256 + threadIdx.x;
    const double* ps = psc + (size_t)row * (KCODE / 128);
    const int*    pi = pix + (size_t)row * (KCODE / 128);
    double m = ps[0]; int mi = pi[0];
    #pragma unroll
    for (int t = 1; t < KCODE / 128; ++t) {
        double s = ps[t]; int c = pi[t];
        if (s < m || (s == m && c < mi)) { m = s; mi = c; }
    }
    idx_out[row] = mi;
}

// ---------------------------------------------------------------------------
// bf16 MFMA GEMM (decoder), triple-buffered DMA staging + counted vmcnt +
// XCD swizzle. A:[M][K], Bt:[N][K]. 128x128, BK=32, 256 thr, wave 64x64.
// LDS [3][128][32] per matrix (48 KB), slot swizzle as gemms.
// ---------------------------------------------------------------------------
template<int RELU, int OUTBF>
__global__ __launch_bounds__(256)
void gemmb2(const ushort* __restrict__ A, const ushort* __restrict__ Bt,
            const float* __restrict__ bias, void* __restrict__ C,
            int M, int N, int K, int gxlog)
{
    __shared__ __align__(16) short As[3][128][32];
    __shared__ __align__(16) short Bs[3][128][32];
    const int tid  = threadIdx.x;
    const int lane = tid & 63;
    const int wave = tid >> 6;                  // 0..3
    const int wm = (wave >> 1) << 6, wn = (wave & 1) << 6;
    const int fr = lane & 15;
    const int fq = lane >> 4;
    int bx, by;
    swz_xcd(gxlog, &bx, &by);
    const int row0 = by << 7, col0 = bx << 7;

    // staging: wave w covers rows [32w, 32w+32) as two 16-row chunks
    const int sr0 = (wave << 5) + (lane >> 2);
    const int sslot = lane & 3;
    const int kg0 = (sslot ^ ((sr0 >> 1) & 3)) << 3;
    const int sr1 = sr0 + 16;
    const int kg1 = (sslot ^ ((sr1 >> 1) & 3)) << 3;

    const ushort* Ag0 = A  + (size_t)(row0 + sr0) * K + kg0;
    const ushort* Ag1 = A  + (size_t)(row0 + sr1) * K + kg1;
    const ushort* Bg0 = Bt + (size_t)(col0 + sr0) * K + kg0;
    const ushort* Bg1 = Bt + (size_t)(col0 + sr1) * K + kg1;

    f32x4 acc[4][4];
    #pragma unroll
    for (int i = 0; i < 4; ++i)
        #pragma unroll
        for (int j = 0; j < 4; ++j) acc[i][j] = (f32x4)0.0f;

    auto stage = [&](int b, int kb) {
        gload16(Ag0 + kb, &As[b][wave << 5][0]);
        gload16(Ag1 + kb, &As[b][(wave << 5) + 16][0]);
        gload16(Bg0 + kb, &Bs[b][wave << 5][0]);
        gload16(Bg1 + kb, &Bs[b][(wave << 5) + 16][0]);
    };

    stage(0, 0);
    stage(1, 32);
    const int nsteps = K >> 5;
    int b = 0, sbuf = 2;
    for (int s = 0; s < nsteps; ++s) {
        if (s + 2 < nsteps) {
            stage(sbuf, (s + 2) << 5);
            sbuf = (sbuf == 2) ? 0 : sbuf + 1;
            asm volatile("s_waitcnt vmcnt(8)" ::: "memory");
        } else if (s + 1 < nsteps) {
            asm volatile("s_waitcnt vmcnt(4)" ::: "memory");
        } else {
            asm volatile("s_waitcnt vmcnt(0)" ::: "memory");
        }
        __builtin_amdgcn_s_barrier();
        __builtin_amdgcn_sched_barrier(0);

        short8 af[4], bf[4];
        #pragma unroll
        for (int i = 0; i < 4; ++i) {
            const int an = wm + (i << 4) + fr;
            af[i] = *(const short8*)&As[b][an][(fq ^ ((an >> 1) & 3)) << 3];
        }
        #pragma unroll
        for (int j = 0; j < 4; ++j) {
            const int bn = wn + (j << 4) + fr;
            bf[j] = *(const short8*)&Bs[b][bn][(fq ^ ((bn >> 1) & 3)) << 3];
        }
        #pragma unroll
        for (int i = 0; i < 4; ++i)
            #pragma unroll
            for (int j = 0; j < 4; ++j)
                acc[i][j] = __builtin_amdgcn_mfma_f32_16x16x32_bf16(
                                af[i], bf[j], acc[i][j], 0, 0, 0);

        b = (b == 2) ? 0 : b + 1;
        __builtin_amdgcn_sched_barrier(0);
        __builtin_amdgcn_s_barrier();
    }

    #pragma unroll
    for (int j = 0; j < 4; ++j) {
        const int n = col0 + wn + (j << 4) + fr;
        const float bv = bias[n];
        #pragma unroll
        for (int i = 0; i < 4; ++i) {
            const int mb = row0 + wm + (i << 4) + (fq << 2);
            #pragma unroll
            for (int r = 0; r < 4; ++r) {
                float v = acc[i][j][r] + bv;
                if (RELU) v = fmaxf(v, 0.0f);
                size_t o = (size_t)(mb + r) * N + n;
                if (OUTBF) ((bf16*)C)[o]  = __float2bfloat16(v);
                else       ((float*)C)[o] = v;
            }
        }
    }
}

// ---------------------------------------------------------------------------
// decoder weight transpose + f32->bf16 (unchanged)
// ---------------------------------------------------------------------------
__global__ __launch_bounds__(256)
void wtrans(const float* __restrict__ W, ushort* __restrict__ Wt, int K, int N)
{
    __shared__ float tile[64][65];
    const int tid = threadIdx.x;
    const int kb = blockIdx.y << 6, nb = blockIdx.x << 6;
    const int r = tid >> 4, c4 = (tid & 15) << 2;
    #pragma unroll
    for (int s = 0; s < 4; ++s) {
        float4 v = *(const float4*)(W + (size_t)(kb + r + (s << 4)) * N + nb + c4);
        tile[r + (s << 4)][c4 + 0] = v.x; tile[r + (s << 4)][c4 + 1] = v.y;
        tile[r + (s << 4)][c4 + 2] = v.z; tile[r + (s << 4)][c4 + 3] = v.w;
    }
    __syncthreads();
    #pragma unroll
    for (int s = 0; s < 4; ++s) {
        const int n = r + (s << 4);
        ushort u[4];
        #pragma unroll
        for (int l = 0; l < 4; ++l) {
            bf16 h = __float2bfloat16(tile[c4 + l][n]);
            u[l] = *(ushort*)&h;
        }
        *(ushort4*)(Wt + (size_t)(nb + n) * K + kb + c4) = make_ushort4(u[0], u[1], u[2], u[3]);
    }
}

// ---------------------------------------------------------------------------
// encoder weight transpose + 3-limb split: planes [N][K], stride N*K
// ---------------------------------------------------------------------------
__global__ __launch_bounds__(256)
void wsplit(const float* __restrict__ W, ushort* __restrict__ Wt, int K, int N)
{
    __shared__ float tile[64][65];
    const int tid = threadIdx.x;
    const int kb = blockIdx.y << 6, nb = blockIdx.x << 6;
    const int r = tid >> 4, c4 = (tid & 15) << 2;
    const size_t NK = (size_t)N * K;
    #pragma unroll
    for (int s = 0; s < 4; ++s) {
        float4 v = *(const float4*)(W + (size_t)(kb + r + (s << 4)) * N + nb + c4);
        tile[r + (s << 4)][c4 + 0] = v.x; tile[r + (s << 4)][c4 + 1] = v.y;
        tile[r + (s << 4)][c4 + 2] = v.z; tile[r + (s << 4)][c4 + 3] = v.w;
    }
    __syncthreads();
    #pragma unroll
    for (int s = 0; s < 4; ++s) {
        const int n = r + (s << 4);
        ushort h[4], m[4], l[4];
        #pragma unroll
        for (int e = 0; e < 4; ++e) split3(tile[c4 + e][n], &h[e], &m[e], &l[e]);
        const size_t o = (size_t)(nb + n) * K + kb + c4;
        *(ushort4*)(Wt + o)          = make_ushort4(h[0], h[1], h[2], h[3]);
        *(ushort4*)(Wt + NK + o)     = make_ushort4(m[0], m[1], m[2], m[3]);
        *(ushort4*)(Wt + 2 * NK + o) = make_ushort4(l[0], l[1], l[2], l[3]);
    }
}

// ---------------------------------------------------------------------------
// f32 row-major -> 3 bf16 limb planes, plane stride P (x and codebook)
// ---------------------------------------------------------------------------
__global__ __launch_bounds__(256)
void xsplit(const float* __restrict__ X, ushort* __restrict__ Xp, size_t P)
{
    const size_t i = ((size_t)blockIdx.x * 256 + threadIdx.x) << 2;
    float4 v = *(const float4*)(X + i);
    ushort h[4], m[4], l[4];
    split3(v.x, &h[0], &m[0], &l[0]);
    split3(v.y, &h[1], &m[1], &l[1]);
    split3(v.z, &h[2], &m[2], &l[2]);
    split3(v.w, &h[3], &m[3], &l[3]);
    *(ushort4*)(Xp + i)         = make_ushort4(h[0], h[1], h[2], h[3]);
    *(ushort4*)(Xp + P + i)     = make_ushort4(m[0], m[1], m[2], m[3]);
    *(ushort4*)(Xp + 2 * P + i) = make_ushort4(l[0], l[1], l[2], l[3]);
}

// ---------------------------------------------------------------------------
// codebook squared norms (f64)
// ---------------------------------------------------------------------------
__global__ __launch_bounds__(64)
void c2_k(const float* __restrict__ cb, double* __restrict__ c2)
{
    int code = blockIdx.x, l = threadIdx.x;
    float4 v = *(const float4*)(cb + (size_t)code * DCODE + (l << 2));
    double s = (double)v.x * v.x + (double)v.y * v.y
             + (double)v.z * v.z + (double)v.w * v.w;
    #pragma unroll
    for (int off = 32; off; off >>= 1) s += __shfl_down(s, off, 64);
    if (l == 0) c2[code] = s;
}

// ---------------------------------------------------------------------------
// gather + straight-through + loss partials + idx. 4 rows/block, no atomics.
// ---------------------------------------------------------------------------
__global__ __launch_bounds__(256)
void gather_k(const int* __restrict__ idx_in, const float* __restrict__ cb,
              const double* __restrict__ z, ushort* __restrict__ qstb,
              float* __restrict__ out_qst, float* __restrict__ out_idx,
              double* __restrict__ psum)
{
    const int tid  = threadIdx.x;
    const int row  = (blockIdx.x << 2) + (tid >> 6);
    const int lane = tid & 63;
    const int d    = lane << 2;
    const int idx  = idx_in[row];

    float4 qv = *(const float4*)(cb + (size_t)idx * DCODE + d);
    const double* zp = z + (size_t)row * DCODE + d;
    double2 z0 = *(const double2*)(zp);
    double2 z1 = *(const double2*)(zp + 2);

    double q[4] = {(double)qv.x, (double)qv.y, (double)qv.z, (double)qv.w};
    double zz[4] = {z0.x, z0.y, z1.x, z1.y};
    double qs[4];
    double s = 0.0;
    #pragma unroll
    for (int e = 0; e < 4; ++e) {
        double diff = q[e] - zz[e];
        qs[e] = zz[e] + diff;
        s += diff * diff;
    }
    *(float4*)(out_qst + (size_t)row * DCODE + d) =
        make_float4((float)qs[0], (float)qs[1], (float)qs[2], (float)qs[3]);
    ushort u[4];
    #pragma unroll
    for (int e = 0; e < 4; ++e) {
        bf16 h = __float2bfloat16((float)qs[e]);
        u[e] = *(ushort*)&h;
    }
    *(ushort4*)(qstb + (size_t)row * DCODE + d) = make_ushort4(u[0], u[1], u[2], u[3]);

    #pragma unroll
    for (int off = 32; off; off >>= 1) s += __shfl_down(s, off, 64);
    __shared__ double sred[4];
    if (lane == 0) {
        sred[tid >> 6] = s;
        out_idx[row] = (float)idx;
    }
    __syncthreads();
    if (tid == 0) psum[blockIdx.x] = sred[0] + sred[1] + sred[2] + sred[3];
}

// ---------------------------------------------------------------------------
// final loss reduce over BDIM/4 block partials
// ---------------------------------------------------------------------------
__global__ __launch_bounds__(256)
void loss_k(const double* __restrict__ psum, float* __restrict__ out_loss)
{
    const int tid = threadIdx.x;
    double s = 0.0;
    for (int i = tid; i < BDIM / 4; i += 256) s += psum[i];
    #pragma unroll
    for (int off = 32; off; off >>= 1) s += __shfl_down(s, off, 64);
    __shared__ double sred[4];
    if ((tid & 63) == 0) sred[tid >> 6] = s;
    __syncthreads();
    if (tid == 0)
        out_loss[0] = (float)(1.25 * (sred[0] + sred[1] + sred[2] + sred[3]) / 4194304.0);
}

// ===========================================================================
extern "C" void kernel_launch(void* const* d_in, const int* in_sizes, int n_in,
                              void* d_out, int out_size, void* d_ws, size_t ws_size,
                              hipStream_t stream)
{
    const float* x   = (const float*)d_in[0];
    const float* eW1 = (const float*)d_in[1];
    const float* eb1 = (const float*)d_in[2];
    const float* eW2 = (const float*)d_in[3];
    const float* eb2 = (const float*)d_in[4];
    const float* eW3 = (const float*)d_in[5];
    const float* eb3 = (const float*)d_in[6];
    const float* cbk = (const float*)d_in[7];
    const float* dW1 = (const float*)d_in[8];
    const float* db1 = (const float*)d_in[9];
    const float* dW2 = (const float*)d_in[10];
    const float* db2 = (const float*)d_in[11];
    const float* dW3 = (const float*)d_in[12];
    const float* db3 = (const float*)d_in[13];

    // --- sizes ---
    const size_t EPS1 = (size_t)3 * 2048 * 1024 * 2;
    const size_t EPS2 = (size_t)3 * 1024 * 2048 * 2;
    const size_t EPS3 = (size_t)3 * 256 * 1024 * 2;
    const size_t EPS  = EPS1 + EPS2 + EPS3;
    const size_t FIX_W1 = (size_t)1024 * 256 * 2;
    const size_t FIX_W2 = (size_t)2048 * 1024 * 2;
    const size_t FIX_W3 = (size_t)1024 * 2048 * 2;
    const size_t ZB   = (size_t)BDIM * DCODE * 8;
    const size_t ZPLB = (size_t)3 * BDIM * DCODE * 2;
    const size_t QSTB = (size_t)BDIM * DCODE * 2;
    const size_t IDXB = (size_t)BDIM * 4;
    const size_t NPT  = KCODE / 128;
    const size_t PSCB = (size_t)BDIM * NPT * 8;
    const size_t PIXB = (size_t)BDIM * NPT * 4;
    const size_t CBPB = (size_t)3 * KCODE * DCODE * 2;
    const size_t PSUM = (size_t)(BDIM / 4) * 8;

    const size_t PERSIST = FIX_W1 + FIX_W2 + FIX_W3 + ZB + ZPLB + QSTB + IDXB
                         + PSCB + PIXB + CBPB + PSUM + 8192 + 256;

    // per-row chunk region: xpl 6144 | h1pl 12288 | h2pl 6144
    int R = BDIM;
    while (R > 256 && PERSIST + EPS + (size_t)R * 24576 > ws_size) R >>= 1;
    const int nch = BDIM / R;

    char* ws = (char*)d_ws;
    size_t off = 0;
    ushort* eP1  = (ushort*)(ws + off); off += EPS1;
    ushort* eP2  = (ushort*)(ws + off); off += EPS2;
    ushort* eP3  = (ushort*)(ws + off); off += EPS3;
    ushort* xpl  = (ushort*)(ws + off); off += (size_t)R * 6144;
    ushort* h1pl = (ushort*)(ws + off); off += (size_t)R * 12288;
    ushort* h2pl = (ushort*)(ws + off); off += (size_t)R * 6144;
    ushort* dh1b = xpl;                   // phase-4 alias: R x 1024 bf16
    ushort* dh2b = h1pl;                  // phase-4 alias: R x 2048 bf16
    ushort* Wt1  = (ushort*)(ws + off); off += FIX_W1;
    ushort* Wt2  = (ushort*)(ws + off); off += FIX_W2;
    ushort* Wt3  = (ushort*)(ws + off); off += FIX_W3;
    double* zb   = (double*)(ws + off); off += ZB;
    ushort* zpl  = (ushort*)(ws + off); off += ZPLB;
    ushort* qstb = (ushort*)(ws + off); off += QSTB;
    int*    idxb = (int*)(ws + off);    off += IDXB;
    double* psc  = (double*)(ws + off); off += PSCB;
    int*    pix  = (int*)(ws + off);    off += PIXB;
    ushort* cbP  = (ushort*)(ws + off); off += CBPB;
    double* psum = (double*)(ws + off); off += PSUM;
    double* c2   = (double*)(ws + off); off += 8192;

    float* out      = (float*)d_out;
    float* out_rec  = out;
    float* out_qst  = out + (size_t)BDIM * DIN;
    float* out_loss = out_qst + (size_t)BDIM * DCODE;
    float* out_idx  = out_loss + 1;

    c2_k<<<KCODE, 64, 0, stream>>>(cbk, c2);
    wtrans<<<dim3(1024 / 64,  256 / 64), 256, 0, stream>>>(dW1, Wt1,  256, 1024);
    wtrans<<<dim3(2048 / 64, 1024 / 64), 256, 0, stream>>>(dW2, Wt2, 1024, 2048);
    wtrans<<<dim3(1024 / 64, 2048 / 64), 256, 0, stream>>>(dW3, Wt3, 2048, 1024);
    wsplit<<<dim3(2048 / 64, 1024 / 64), 256, 0, stream>>>(eW1, eP1, 1024, 2048);
    wsplit<<<dim3(1024 / 64, 2048 / 64), 256, 0, stream>>>(eW2, eP2, 2048, 1024);
    wsplit<<<dim3( 256 / 64, 1024 / 64), 256, 0, stream>>>(eW3, eP3, 1024,  256);
    xsplit<<<(KCODE * DCODE) / 1024, 256, 0, stream>>>(cbk, cbP, (size_t)KCODE * DCODE);

    const int rb64 = R / 64;    // 64-row tiles per chunk (gemms)
    const int rb   = R / 128;   // 128-row tiles per chunk (gemmb2)

    // phase 1: encoder chunks -> zb (f64) + zpl (limb planes, fused)
    for (int c = 0; c < nch; ++c) {
        const float* xc = x + (size_t)c * R * DIN;
        double* zb_c  = zb + (size_t)c * R * DCODE;
        ushort* zpl_c = zpl + (size_t)c * R * DCODE;
        xsplit<<<R, 256, 0, stream>>>(xc, xpl, (size_t)R * DIN);
        gemms<1, 0><<<16 * rb64, 256, 0, stream>>>(
            xpl, eP1, eb1, h1pl, nullptr, R, DH1, DIN,
            (size_t)R * DIN, (size_t)DH1 * DIN, (size_t)R * DH1, 4);
        gemms<1, 0><<<8 * rb64, 256, 0, stream>>>(
            h1pl, eP2, eb2, h2pl, nullptr, R, DH2, DH1,
            (size_t)R * DH1, (size_t)DH2 * DH1, (size_t)R * DH2, 3);
        gemms<0, 3><<<2 * rb64, 256, 0, stream>>>(
            h2pl, eP3, eb3, zb_c, zpl_c, R, DCODE, DH2,
            (size_t)R * DH2, (size_t)DCODE * DH2, (size_t)BDIM * DCODE, 1);
    }

    // phase 2: VQ on matrix cores, full batch
    distm<<<8 * (BDIM / 128), 512, 0, stream>>>(zpl, cbP, c2, psc, pix);
    reduce8<<<BDIM / 256, 256, 0, stream>>>(psc, pix, idxb);

    // phase 3: gather + loss partials, full batch
    gather_k<<<BDIM / 4, 256, 0, stream>>>(idxb, cbk, zb, qstb, out_qst, out_idx, psum);

    // phase 4: decoder chunks
    for (int c = 0; c < nch; ++c) {
        const ushort* qst_c = qstb + (size_t)c * R * DCODE;
        float* rec_c = out_rec + (size_t)c * R * DIN;
        gemmb2<1, 1><<<8 * rb, 256, 0, stream>>>(qst_c, Wt1, db1, dh1b, R, DH2, DCODE, 3);
        gemmb2<1, 1><<<16 * rb, 256, 0, stream>>>(dh1b, Wt2, db2, dh2b, R, DH1, DH2, 4);
        gemmb2<0, 0><<<8 * rb, 256, 0, stream>>>(dh2b, Wt3, db3, rec_c, R, DIN, DH1, 3);
    }

    loss_k<<<1, 256, 0, stream>>>(psum, out_loss);
}